// Round 1
// baseline (1014.495 us; speedup 1.0000x reference)
//
#include <hip/hip_runtime.h>
#include <hip/hip_bf16.h>
#include <cstdint>
#include <cstddef>

#define NT 200000
#define NP 5000
#define FDIM 384
#define CDIM 128
#define EC 600000
#define EL 400000
#define NKEYS (NT + 2*NP)          // concatenated CSR segment count
#define NEDGE (2*EC + NT)          // concatenated edge count

typedef unsigned int uint;
typedef unsigned short ushort;
typedef __attribute__((ext_vector_type(8))) __bf16 bf16x8;
typedef __attribute__((ext_vector_type(4))) float f32x4;

union FragU { uint4 u; bf16x8 b; };

__device__ __forceinline__ ushort f2bf(float f){
  uint u = __float_as_uint(f);
  u = (u + 0x7fffu + ((u >> 16) & 1u)) >> 16;
  return (ushort)u;
}
__device__ __forceinline__ float bf2f(ushort h){
  return __uint_as_float(((uint)h) << 16);
}
// storage permutation: sigma(c) = (c&15)*8 + (c>>4); invs below
__device__ __forceinline__ int invs(int w){
  return ((w >> 2) & 1)*64 + (w & 3)*16 + (w >> 3);
}

// ---------------- fused CSR build ----------------
__global__ void k_hist3(const int* __restrict__ com0, const int* __restrict__ com1,
                        const int* __restrict__ sup1, int* __restrict__ counts){
  int i = blockIdx.x*256 + threadIdx.x;
  if (i < EC)            atomicAdd(&counts[com0[i]], 1);
  else if (i < 2*EC)     atomicAdd(&counts[NT + com1[i - EC]], 1);
  else if (i < NEDGE)    atomicAdd(&counts[NT + NP + sup1[i - 2*EC]], 1);
}

// local exclusive scan per 256-block + block totals
__global__ void k_scanA(const int* __restrict__ counts, int n,
                        int* __restrict__ rowptr, int* __restrict__ partials){
  __shared__ int s[256];
  int tid = threadIdx.x;
  int i = blockIdx.x*256 + tid;
  int v = (i < n) ? counts[i] : 0;
  s[tid] = v; __syncthreads();
  for (int off = 1; off < 256; off <<= 1){
    int t = (tid >= off) ? s[tid - off] : 0;
    __syncthreads();
    s[tid] += t;
    __syncthreads();
  }
  if (i < n) rowptr[i] = s[tid] - v;
  if (tid == 255) partials[blockIdx.x] = s[255];
}

__global__ void k_scanB(int* __restrict__ partials, int nP, int* __restrict__ total_out){
  __shared__ int s[1024];
  int carry = 0;
  for (int base = 0; base < nP; base += 1024){
    int i = base + threadIdx.x;
    int v = (i < nP) ? partials[i] : 0;
    s[threadIdx.x] = v; __syncthreads();
    for (int off = 1; off < 1024; off <<= 1){
      int t = (threadIdx.x >= off) ? s[threadIdx.x - off] : 0;
      __syncthreads();
      s[threadIdx.x] += t;
      __syncthreads();
    }
    if (i < nP) partials[i] = carry + s[threadIdx.x] - v;
    int chunk_total = s[1023];
    __syncthreads();
    carry += chunk_total;
  }
  if (threadIdx.x == 0 && total_out) *total_out = carry;
}

__global__ void k_scanC(int* __restrict__ rowptr, const int* __restrict__ pscan,
                        int n, int* __restrict__ cursor){
  int i = blockIdx.x*256 + threadIdx.x;
  if (i < n){
    int r = rowptr[i] + pscan[i >> 8];
    rowptr[i] = r;
    cursor[i] = r;
  }
}

__global__ void k_fill3(const int* __restrict__ com0, const int* __restrict__ com1,
                        const int* __restrict__ sup0, const int* __restrict__ sup1,
                        int* __restrict__ cursor, int* __restrict__ vals){
  int i = blockIdx.x*256 + threadIdx.x;
  int key, sv;
  if (i < EC)          { key = com0[i];                 sv = com1[i]; }
  else if (i < 2*EC)   { key = NT + com1[i - EC];       sv = com0[i - EC]; }
  else if (i < NEDGE)  { key = NT + NP + sup1[i - 2*EC]; sv = sup0[i - 2*EC]; }
  else return;
  int pos = atomicAdd(&cursor[key], 1);
  vals[pos] = sv;
}

// ---------------- prep: xp0 sigma-bf16 + WmFrag(natural) + W1aFrag(invs) + Wzb/WzcPerm ----------
__global__ void k_prep(const float* __restrict__ pe, const int* __restrict__ pid,
                       ushort* __restrict__ xp0,
                       const float* __restrict__ lin_W, ushort* __restrict__ WmFrag,
                       const float* __restrict__ cW1, ushort* __restrict__ W1aFrag,
                       float* __restrict__ WzbPerm, float* __restrict__ WzcPerm){
  int i = blockIdx.x*256 + threadIdx.x;
  if (i < NP*CDIM){                     // xp0[p][w] = bf16(pe[pid[p]][invs(w)])
    int p = i >> 7, w = i & 127;
    xp0[i] = f2bf(pe[(size_t)pid[p]*CDIM + invs(w)]);
    return;
  }
  i -= NP*CDIM;
  if (i < 384*128){                     // natural pack (A = fp32 natural)
    int j = i & 7, lane = (i >> 3) & 63, q = lane >> 4, nl = lane & 15, tl = i >> 9;
    int nt = tl & 7, kc = tl >> 3;
    int k = kc*32 + q*8 + j, n = nt*16 + nl;
    WmFrag[i] = f2bf(lin_W[(size_t)k*128 + n]);
    return;
  }
  i -= 384*128;
  if (i < 128*32){                      // invs pack (A = sigma-stored), N=32
    int j = i & 7, lane = (i >> 3) & 63, q = lane >> 4, nl = lane & 15, tl = i >> 9;
    int nt = tl & 1, kc = tl >> 1;
    int s = 32*kc + 8*q + j, n = nt*16 + nl;
    W1aFrag[i] = f2bf(cW1[(size_t)invs(s)*32 + n]);
    return;
  }
  i -= 128*32;
  if (i < 2*128*32){                    // row-permuted fp32 W for gemm32
    int m = i >> 12;                    // 0 = zpb block, 1 = zpc block
    int o = i & 4095;
    int s = o >> 5, n = o & 31;
    float v = cW1[(size_t)(128 + m*128 + invs(s))*32 + n];
    (m ? WzcPerm : WzbPerm)[o] = v;
  }
}

// ---------------- per-layer weight prep: WpFrag, Wl2Frag, Wl3Frag, WtFrag, bp, btp ----------------
__global__ void k_wprep(const float* __restrict__ gWl, const float* __restrict__ gbl,
                        const float* __restrict__ gWr, int layer,
                        ushort* __restrict__ WpFrag, ushort* __restrict__ Wl2Frag,
                        ushort* __restrict__ Wl3Frag, ushort* __restrict__ WtFrag,
                        float* __restrict__ bp, float* __restrict__ btp){
  int i = blockIdx.x*256 + threadIdx.x;
  const float* Wl_l = gWl + (size_t)layer*4*16384;
  const float* Wr_l = gWr + (size_t)layer*4*16384;
  const float* bl_l = gbl + (size_t)layer*4*128;
  if (i < 49152){                       // WpFrag: K=384, all blocks invs (A = [sig|sig|sig])
    int j = i & 7, lane = (i >> 3) & 63, q = lane >> 4, nl = lane & 15, tl = i >> 9;
    int nt = tl & 7, kc = tl >> 3;      // kc 0..11
    int s_row = 32*kc + 8*q + j;
    int b = s_row >> 7, w = s_row & 127;
    int r = invs(w), n = nt*16 + nl;
    float v;
    if (b == 0)      v = Wl_l[(size_t)r*128 + n];
    else if (b == 1) v = Wl_l[16384 + (size_t)r*128 + n];
    else             v = Wr_l[(size_t)r*128 + n] + Wr_l[16384 + (size_t)r*128 + n];
    WpFrag[i] = f2bf(v);
    return;
  }
  i -= 49152;
  if (i < 3*16384){                     // Wl2 / Wl3 / Wt frags (K=128, invs)
    int m = i >> 14;                    // 0,1,2
    int o = i & 16383;
    int j = o & 7, lane = (o >> 3) & 63, q = lane >> 4, nl = lane & 15, tl = o >> 9;
    int nt = tl & 7, kc = tl >> 3;      // kc 0..3
    int s = 32*kc + 8*q + j;
    int r = invs(s), n = nt*16 + nl;
    float v;
    if (m == 0)      v = Wl_l[2*16384 + (size_t)r*128 + n];
    else if (m == 1) v = Wl_l[3*16384 + (size_t)r*128 + n];
    else             v = Wr_l[2*16384 + (size_t)r*128 + n] + Wr_l[3*16384 + (size_t)r*128 + n];
    (m == 0 ? Wl2Frag : (m == 1 ? Wl3Frag : WtFrag))[o] = f2bf(v);
    return;
  }
  i -= 3*16384;
  if (i < 128){
    bp[i] = bl_l[i] + bl_l[128 + i];
    btp[(i & 15)*8 + (i >> 4)] = bl_l[2*128 + i] + bl_l[3*128 + i];   // sigma store
  }
}

// ---------------- segment sums: wave per prof; xt/xp sigma-bf16 in, apcat sigma-bf16 out --------
__global__ __launch_bounds__(256) void k_segsum(
    const uint* __restrict__ xt32, const uint* __restrict__ xp32,
    const int* __restrict__ mrp, const int* __restrict__ crp,
    const int* __restrict__ vall, uint* __restrict__ apcat){
  int p = blockIdx.x*4 + (threadIdx.x >> 6);
  if (p >= NP) return;
  int lane = threadIdx.x & 63;
  float s0a = 0.f, s0b = 0.f;
  {
    int j = mrp[p], je = mrp[p+1];
    for (; j + 4 <= je; j += 4){
      uint v0 = xt32[(size_t)vall[j]  *64 + lane];
      uint v1 = xt32[(size_t)vall[j+1]*64 + lane];
      uint v2 = xt32[(size_t)vall[j+2]*64 + lane];
      uint v3 = xt32[(size_t)vall[j+3]*64 + lane];
      s0a += (bf2f((ushort)(v0 & 0xffff)) + bf2f((ushort)(v1 & 0xffff)))
           + (bf2f((ushort)(v2 & 0xffff)) + bf2f((ushort)(v3 & 0xffff)));
      s0b += (bf2f((ushort)(v0 >> 16)) + bf2f((ushort)(v1 >> 16)))
           + (bf2f((ushort)(v2 >> 16)) + bf2f((ushort)(v3 >> 16)));
    }
    for (; j < je; ++j){
      uint v = xt32[(size_t)vall[j]*64 + lane];
      s0a += bf2f((ushort)(v & 0xffff));
      s0b += bf2f((ushort)(v >> 16));
    }
  }
  float s1a = 0.f, s1b = 0.f;
  {
    int j = crp[p], je = crp[p+1];
    for (; j + 4 <= je; j += 4){
      uint v0 = xt32[(size_t)vall[j]  *64 + lane];
      uint v1 = xt32[(size_t)vall[j+1]*64 + lane];
      uint v2 = xt32[(size_t)vall[j+2]*64 + lane];
      uint v3 = xt32[(size_t)vall[j+3]*64 + lane];
      s1a += (bf2f((ushort)(v0 & 0xffff)) + bf2f((ushort)(v1 & 0xffff)))
           + (bf2f((ushort)(v2 & 0xffff)) + bf2f((ushort)(v3 & 0xffff)));
      s1b += (bf2f((ushort)(v0 >> 16)) + bf2f((ushort)(v1 >> 16)))
           + (bf2f((ushort)(v2 >> 16)) + bf2f((ushort)(v3 >> 16)));
    }
    for (; j < je; ++j){
      uint v = xt32[(size_t)vall[j]*64 + lane];
      s1a += bf2f((ushort)(v & 0xffff));
      s1b += bf2f((ushort)(v >> 16));
    }
  }
  uint* row = apcat + (size_t)p*192;
  row[lane]       = (uint)f2bf(s0a) | ((uint)f2bf(s0b) << 16);
  row[64 + lane]  = (uint)f2bf(s1a) | ((uint)f2bf(s1b) << 16);
  row[128 + lane] = xp32[(size_t)p*64 + lane];
}

// ---------------- thesis MFMA GEMM ----------------
// GATH: fused neighbor aggregation in the epilogue — per output row, gather
//       mentor row from yp2 + com-CSR rows from yp3 (sigma layout, L2-resident
//       tables) + sigma bias btpS, added pre-ReLU.  Replaces the old k_agg +
//       aggp round-trip (saves ~102 MB HBM per layer).
// ZT:   skip xt store; round-trip tile through LDS (stride 136), emit
//       zt = tile @ W1a with zpb[mentor[row]] folded in (k_edge then needs
//       only 2 gathers per edge instead of 3 + a dependent hop).
template<int K, bool AF32, bool GATH, bool RELU, bool ZT>
__global__ __launch_bounds__(256) void k_mm(
    const void* __restrict__ Ain, int M,
    const ushort* __restrict__ Wfrag, const float* __restrict__ bias,
    ushort* __restrict__ Outp,
    const int* __restrict__ mentor, const int* __restrict__ rowptr,
    const int* __restrict__ vals,
    const ushort* __restrict__ yp2, const ushort* __restrict__ yp3,
    const float* __restrict__ btpS,
    const ushort* __restrict__ W1a, ushort* __restrict__ ztout,
    const ushort* __restrict__ zpb){
  constexpr int SMSZ = ZT ? 2176 : 1024;      // uint4 units (ZT: 34816 B tile overlay)
  __shared__ uint4 smem[SMSZ];
  uint4* As = smem;
  uint4* Bs = smem + 512;
  ushort* tile = (ushort*)smem;               // 128 x 136, used after K-loop only
  const int tid  = threadIdx.x;
  const int lane = tid & 63;
  const int wave = tid >> 6;
  const int wr   = wave >> 1, wc = wave & 1;
  const int m0   = blockIdx.x * 128;
  const float* Af = (const float*)Ain;
  const ushort* Ab = (const ushort*)Ain;

  f32x4 acc[4][4];
  #pragma unroll
  for (int i = 0; i < 4; ++i)
    #pragma unroll
    for (int j = 0; j < 4; ++j) acc[i][j] = (f32x4)(0.f);

  for (int kc = 0; kc < K/32; ++kc){
    if (AF32){
      const int rs = tid >> 2, qs = tid & 3;
      #pragma unroll
      for (int h = 0; h < 2; ++h){
        int rr = rs + 64*h;
        int grow = m0 + rr;
        uint4 payload = make_uint4(0,0,0,0);
        if (grow < M){
          const float* ap = Af + (size_t)grow*K + kc*32 + qs*8;
          float4 fa = *(const float4*)ap;
          float4 fb = *(const float4*)(ap + 4);
          payload.x = (uint)f2bf(fa.x) | ((uint)f2bf(fa.y) << 16);
          payload.y = (uint)f2bf(fa.z) | ((uint)f2bf(fa.w) << 16);
          payload.z = (uint)f2bf(fb.x) | ((uint)f2bf(fb.y) << 16);
          payload.w = (uint)f2bf(fb.z) | ((uint)f2bf(fb.w) << 16);
        }
        As[(rr >> 4)*64 + qs*16 + (rr & 15)] = payload;
      }
    } else {
      #pragma unroll
      for (int h = 0; h < 2; ++h){
        int e = tid + 256*h;
        int rr = e >> 2, q = e & 3;
        int grow = m0 + rr;
        uint4 payload = make_uint4(0,0,0,0);
        if (grow < M)
          payload = *(const uint4*)(Ab + (size_t)grow*K + (4*kc + q)*8);
        As[(rr >> 4)*64 + q*16 + (rr & 15)] = payload;
      }
    }
    const uint4* wsrc = (const uint4*)Wfrag + (size_t)kc*512;
    Bs[tid]       = wsrc[tid];
    Bs[tid + 256] = wsrc[tid + 256];
    __syncthreads();

    bf16x8 a[4], b[4];
    #pragma unroll
    for (int i = 0; i < 4; ++i){ FragU u; u.u = As[(wr*4 + i)*64 + lane]; a[i] = u.b; }
    #pragma unroll
    for (int j = 0; j < 4; ++j){ FragU u; u.u = Bs[(wc*4 + j)*64 + lane]; b[j] = u.b; }
    #pragma unroll
    for (int i = 0; i < 4; ++i)
      #pragma unroll
      for (int j = 0; j < 4; ++j)
        acc[i][j] = __builtin_amdgcn_mfma_f32_16x16x32_bf16(a[i], b[j], acc[i][j], 0, 0, 0);
    __syncthreads();
  }

  // --- epilogue ---
  const int nl = lane & 15;
  const int s0 = nl*8 + wc*4;
  float bv[4];
  if (GATH){
    float4 g = *(const float4*)(btpS + s0);     // sigma-layout bias, same for all rows
    bv[0] = g.x; bv[1] = g.y; bv[2] = g.z; bv[3] = g.w;
  } else {
    #pragma unroll
    for (int j = 0; j < 4; ++j) bv[j] = bias ? bias[wc*64 + j*16 + nl] : 0.f;
  }

  #pragma unroll
  for (int i = 0; i < 4; ++i){
    int rb = wr*64 + i*16 + (lane >> 4)*4;
    #pragma unroll
    for (int reg = 0; reg < 4; ++reg){
      int rr = rb + reg;
      int row = m0 + rr;
      if (row >= M) continue;
      float v0 = acc[i][0][reg] + bv[0];
      float v1 = acc[i][1][reg] + bv[1];
      float v2 = acc[i][2][reg] + bv[2];
      float v3 = acc[i][3][reg] + bv[3];
      if (GATH){
        int m = mentor[row];
        ushort4 y = *(const ushort4*)(yp2 + (size_t)m*CDIM + s0);
        v0 += bf2f(y.x); v1 += bf2f(y.y); v2 += bf2f(y.z); v3 += bf2f(y.w);
        int qe = rowptr[row + 1];
        for (int q = rowptr[row]; q < qe; ++q){
          ushort4 z = *(const ushort4*)(yp3 + (size_t)vals[q]*CDIM + s0);
          v0 += bf2f(z.x); v1 += bf2f(z.y); v2 += bf2f(z.z); v3 += bf2f(z.w);
        }
      }
      if (RELU){
        v0 = v0 > 0.f ? v0 : 0.f; v1 = v1 > 0.f ? v1 : 0.f;
        v2 = v2 > 0.f ? v2 : 0.f; v3 = v3 > 0.f ? v3 : 0.f;
      }
      ushort4 o;
      o.x = f2bf(v0); o.y = f2bf(v1); o.z = f2bf(v2); o.w = f2bf(v3);
      if (ZT) *(ushort4*)&tile[(size_t)rr*136 + s0] = o;
      else    *(ushort4*)(Outp + (size_t)row*CDIM + s0) = o;
    }
  }

  if (ZT){
    __syncthreads();
    const uint4* wf = (const uint4*)W1a;
    const int q = lane >> 4, mm = lane & 15;
    f32x4 acc2[2][2];
    #pragma unroll
    for (int a2 = 0; a2 < 2; ++a2)
      #pragma unroll
      for (int b2 = 0; b2 < 2; ++b2) acc2[a2][b2] = (f32x4)(0.f);
    #pragma unroll
    for (int kc = 0; kc < 4; ++kc){
      bf16x8 af[2];
      #pragma unroll
      for (int i2 = 0; i2 < 2; ++i2){
        FragU u;
        u.u = *(const uint4*)&tile[(size_t)(wave*32 + i2*16 + mm)*136 + (4*kc + q)*8];
        af[i2] = u.b;
      }
      #pragma unroll
      for (int nt = 0; nt < 2; ++nt){
        FragU u; u.u = wf[(kc*2 + nt)*64 + lane];
        #pragma unroll
        for (int i2 = 0; i2 < 2; ++i2)
          acc2[i2][nt] = __builtin_amdgcn_mfma_f32_16x16x32_bf16(af[i2], u.b, acc2[i2][nt], 0, 0, 0);
      }
    }
    #pragma unroll
    for (int i2 = 0; i2 < 2; ++i2){
      #pragma unroll
      for (int reg = 0; reg < 4; ++reg){
        int row = m0 + wave*32 + i2*16 + q*4 + reg;
        if (row >= M) continue;
        int m = mentor[row];   // fold zpb[mentor] into zt (fp32 pre-round)
        ztout[(size_t)row*32 + mm]      =
            f2bf(acc2[i2][0][reg] + bf2f(zpb[(size_t)m*32 + mm]));
        ztout[(size_t)row*32 + 16 + mm] =
            f2bf(acc2[i2][1][reg] + bf2f(zpb[(size_t)m*32 + 16 + mm]));
      }
    }
  }
}

// ---------------- prof MFMA GEMM: y = {xp-update(K=384), yp2, yp3} ----------------
__global__ __launch_bounds__(256) void k_mmp(
    const ushort* __restrict__ apcat, const ushort* __restrict__ xpold, int layer,
    const ushort* __restrict__ WpFrag, const ushort* __restrict__ Wl2Frag,
    const ushort* __restrict__ Wl3Frag, const float* __restrict__ bp,
    ushort* __restrict__ xpnew, ushort* __restrict__ yp2p, ushort* __restrict__ yp3p){
  const int y = blockIdx.y;
  const ushort* A; const ushort* Wf; const float* bias; ushort* Out;
  int nkc, rowlen; bool relu;
  if (y == 0){ A = apcat; rowlen = 384; nkc = 12; Wf = WpFrag; bias = bp;
               Out = xpnew; relu = (layer == 0); }
  else if (y == 1){ A = xpold; rowlen = 128; nkc = 4; Wf = Wl2Frag; bias = nullptr;
               Out = yp2p; relu = false; }
  else       { A = xpold; rowlen = 128; nkc = 4; Wf = Wl3Frag; bias = nullptr;
               Out = yp3p; relu = false; }

  __shared__ uint4 As[512];
  __shared__ uint4 Bs[512];
  const int tid  = threadIdx.x;
  const int lane = tid & 63;
  const int wave = tid >> 6;
  const int wr   = wave >> 1, wc = wave & 1;
  const int m0   = blockIdx.x * 128;

  f32x4 acc[4][4];
  #pragma unroll
  for (int i = 0; i < 4; ++i)
    #pragma unroll
    for (int j = 0; j < 4; ++j) acc[i][j] = (f32x4)(0.f);

  for (int kc = 0; kc < nkc; ++kc){
    #pragma unroll
    for (int h = 0; h < 2; ++h){
      int e = tid + 256*h;
      int rr = e >> 2, q = e & 3;
      int grow = m0 + rr;
      uint4 payload = make_uint4(0,0,0,0);
      if (grow < NP)
        payload = *(const uint4*)(A + (size_t)grow*rowlen + (4*kc + q)*8);
      As[(rr >> 4)*64 + q*16 + (rr & 15)] = payload;
    }
    const uint4* wsrc = (const uint4*)Wf + (size_t)kc*512;
    Bs[tid]       = wsrc[tid];
    Bs[tid + 256] = wsrc[tid + 256];
    __syncthreads();

    bf16x8 a[4], b[4];
    #pragma unroll
    for (int i = 0; i < 4; ++i){ FragU u; u.u = As[(wr*4 + i)*64 + lane]; a[i] = u.b; }
    #pragma unroll
    for (int j = 0; j < 4; ++j){ FragU u; u.u = Bs[(wc*4 + j)*64 + lane]; b[j] = u.b; }
    #pragma unroll
    for (int i = 0; i < 4; ++i)
      #pragma unroll
      for (int j = 0; j < 4; ++j)
        acc[i][j] = __builtin_amdgcn_mfma_f32_16x16x32_bf16(a[i], b[j], acc[i][j], 0, 0, 0);
    __syncthreads();
  }

  const int nl = lane & 15;
  float bv[4];
  #pragma unroll
  for (int j = 0; j < 4; ++j) bv[j] = bias ? bias[wc*64 + j*16 + nl] : 0.f;
  const int s0 = nl*8 + wc*4;

  #pragma unroll
  for (int i = 0; i < 4; ++i){
    int r0 = m0 + wr*64 + i*16 + (lane >> 4)*4;
    #pragma unroll
    for (int reg = 0; reg < 4; ++reg){
      int row = r0 + reg;
      if (row >= NP) continue;
      float v0 = acc[i][0][reg] + bv[0];
      float v1 = acc[i][1][reg] + bv[1];
      float v2 = acc[i][2][reg] + bv[2];
      float v3 = acc[i][3][reg] + bv[3];
      if (relu){
        v0 = v0 > 0.f ? v0 : 0.f; v1 = v1 > 0.f ? v1 : 0.f;
        v2 = v2 > 0.f ? v2 : 0.f; v3 = v3 > 0.f ? v3 : 0.f;
      }
      ushort4 o;
      o.x = f2bf(v0); o.y = f2bf(v1); o.z = f2bf(v2); o.w = f2bf(v3);
      *(ushort4*)(Out + (size_t)row*CDIM + s0) = o;
    }
  }
}

// ---------------- N=32 GEMM (prof zpb/zpc): A sigma-bf16, W row-permuted fp32 ----------------
// blockIdx.y==1 (zpc) additionally folds the classifier hidden bias b1.
__global__ __launch_bounds__(256) void k_gemm32(const ushort* __restrict__ A, int M,
                                                const float* __restrict__ W0,
                                                const float* __restrict__ W1,
                                                const float* __restrict__ b1,
                                                ushort* __restrict__ Out0,
                                                ushort* __restrict__ Out1){
  const float* W = blockIdx.y ? W1 : W0;
  ushort* Out = blockIdx.y ? Out1 : Out0;
  __shared__ float As[128*36];
  __shared__ float Ws[32*32];
  const int tid  = threadIdx.x;
  const int m0   = blockIdx.x*128;
  const int c4   = (tid & 7)*4;
  const int rowg = tid >> 3;
  float4 acc[4];
  #pragma unroll
  for (int j = 0; j < 4; ++j) acc[j] = make_float4(0.f,0.f,0.f,0.f);

  for (int k0 = 0; k0 < 128; k0 += 32){
    #pragma unroll
    for (int l = 0; l < 4; ++l){
      int q = tid + 256*l;
      int r = q >> 3, kf = q & 7;
      int row = m0 + r;
      float4 v = make_float4(0.f,0.f,0.f,0.f);
      if (row < M){
        ushort4 u = *(const ushort4*)(A + (size_t)row*CDIM + k0 + kf*4);
        v = make_float4(bf2f(u.x), bf2f(u.y), bf2f(u.z), bf2f(u.w));
      }
      *(float4*)&As[r*36 + kf*4] = v;
    }
    {
      int kk = tid >> 3, cf = tid & 7;
      *(float4*)&Ws[kk*32 + cf*4] = *(const float4*)(W + (size_t)(k0+kk)*32 + cf*4);
    }
    __syncthreads();
    #pragma unroll
    for (int k4 = 0; k4 < 8; ++k4){
      float4 w0 = *(const float4*)&Ws[(k4*4+0)*32 + c4];
      float4 w1 = *(const float4*)&Ws[(k4*4+1)*32 + c4];
      float4 w2 = *(const float4*)&Ws[(k4*4+2)*32 + c4];
      float4 w3 = *(const float4*)&Ws[(k4*4+3)*32 + c4];
      #pragma unroll
      for (int j = 0; j < 4; ++j){
        float4 a = *(const float4*)&As[(rowg + 32*j)*36 + k4*4];
        acc[j].x += a.x*w0.x + a.y*w1.x + a.z*w2.x + a.w*w3.x;
        acc[j].y += a.x*w0.y + a.y*w1.y + a.z*w2.y + a.w*w3.y;
        acc[j].z += a.x*w0.z + a.y*w1.z + a.z*w2.z + a.w*w3.z;
        acc[j].w += a.x*w0.w + a.y*w1.w + a.z*w2.w + a.w*w3.w;
      }
    }
    __syncthreads();
  }
  float4 bb = make_float4(0.f,0.f,0.f,0.f);
  if (blockIdx.y) bb = *(const float4*)(b1 + c4);
  #pragma unroll
  for (int j = 0; j < 4; ++j){
    int row = m0 + rowg + 32*j;
    if (row < M){
      ushort4 o;
      o.x = f2bf(acc[j].x + bb.x); o.y = f2bf(acc[j].y + bb.y);
      o.z = f2bf(acc[j].z + bb.z); o.w = f2bf(acc[j].w + bb.w);
      *(ushort4*)(Out + (size_t)row*32 + c4) = o;
    }
  }
}

// ---------------- edge classifier: zt2 already contains zpb[mentor]; zpc2 contains b1 ------------
__global__ __launch_bounds__(256) void k_edge(
    const int* __restrict__ el0, const int* __restrict__ el1,
    const ushort* __restrict__ zt2, const ushort* __restrict__ zpc2,
    const float* __restrict__ W2, const float* __restrict__ b2,
    float* __restrict__ out, int n){
  __shared__ float sW[32];
  if (threadIdx.x < 32) sW[threadIdx.x] = W2[threadIdx.x];
  __syncthreads();
  int e = blockIdx.x*256 + threadIdx.x;
  if (e >= n) return;
  int t = el0[e], p = el1[e];
  const uint4* zr = (const uint4*)(zt2  + (size_t)t*32);
  const uint4* cr = (const uint4*)(zpc2 + (size_t)p*32);
  float acc = 0.f;
  #pragma unroll
  for (int i = 0; i < 4; ++i){   // 4 uint4 = 32 bf16 hidden units
    uint4 ua = zr[i], uc = cr[i];
    const uint aw[4] = {ua.x, ua.y, ua.z, ua.w};
    const uint cw[4] = {uc.x, uc.y, uc.z, uc.w};
    #pragma unroll
    for (int k = 0; k < 4; ++k){
      int base = i*8 + k*2;
      float h0 = bf2f((ushort)(aw[k] & 0xffff)) + bf2f((ushort)(cw[k] & 0xffff));
      float h1 = bf2f((ushort)(aw[k] >> 16)) + bf2f((ushort)(cw[k] >> 16));
      h0 = h0 > 0.f ? h0 : 0.f;
      h1 = h1 > 0.f ? h1 : 0.f;
      acc = fmaf(h0, sW[base], acc);
      acc = fmaf(h1, sW[base + 1], acc);
    }
  }
  out[e] = acc + b2[0];
}

// ---------------- launch ----------------
extern "C" void kernel_launch(void* const* d_in, const int* in_sizes, int n_in,
                              void* d_out, int out_size, void* d_ws, size_t ws_size,
                              hipStream_t stream){
  const float* thesis_x = (const float*)d_in[0];
  const float* lin_W    = (const float*)d_in[1];
  const float* lin_b    = (const float*)d_in[2];
  const float* prof_emb = (const float*)d_in[3];
  const float* gWl      = (const float*)d_in[4];
  const float* gbl      = (const float*)d_in[5];
  const float* gWr      = (const float*)d_in[6];
  const float* cW1      = (const float*)d_in[7];
  const float* cb1      = (const float*)d_in[8];
  const float* cW2      = (const float*)d_in[9];
  const float* cb2      = (const float*)d_in[10];
  const int*   pid      = (const int*)d_in[11];
  const int*   sup0     = (const int*)d_in[12];
  const int*   sup1     = sup0 + NT;
  const int*   com0     = (const int*)d_in[13];
  const int*   com1     = com0 + EC;
  const int*   el0      = (const int*)d_in[14];
  const int*   el1      = el0 + EL;
  float* outp = (float*)d_out;

  char* base = (char*)d_ws;
  size_t off = 0;
  auto alloc = [&](size_t bytes)->void*{
    void* p = base + off;
    off += (bytes + 255) & ~(size_t)255;
    return p;
  };
  ushort* xt      = (ushort*)alloc((size_t)NT*CDIM*2);   // sigma-bf16
  ushort* zt      = (ushort*)alloc((size_t)NT*32*2);     // natural bf16 (incl. zpb[mentor])
  ushort* xp0     = (ushort*)alloc((size_t)NP*CDIM*2);   // sigma-bf16
  ushort* xp1     = (ushort*)alloc((size_t)NP*CDIM*2);
  ushort* apcat   = (ushort*)alloc((size_t)NP*384*2);    // [sig|sig|sig] bf16
  ushort* yp2p    = (ushort*)alloc((size_t)NP*CDIM*2);
  ushort* yp3p    = (ushort*)alloc((size_t)NP*CDIM*2);
  ushort* WmFrag  = (ushort*)alloc((size_t)384*128*2);
  ushort* W1aFrag = (ushort*)alloc((size_t)128*32*2);
  float*  WzbPerm = (float*)alloc((size_t)128*32*4);
  float*  WzcPerm = (float*)alloc((size_t)128*32*4);
  ushort* WpFrag  = (ushort*)alloc((size_t)2*384*128*2);
  ushort* Wl2Frag = (ushort*)alloc((size_t)2*128*128*2);
  ushort* Wl3Frag = (ushort*)alloc((size_t)2*128*128*2);
  ushort* WtFrag  = (ushort*)alloc((size_t)2*128*128*2);
  float*  bp      = (float*)alloc(2*512);
  float*  btp     = (float*)alloc(2*512);
  ushort* zpb     = (ushort*)alloc((size_t)NP*32*2);
  ushort* zpc     = (ushort*)alloc((size_t)NP*32*2);     // zpc2 = zpc + b1
  int* rp_all  = (int*)alloc((size_t)(NKEYS+1)*4);
  int* vals    = (int*)alloc((size_t)NEDGE*4);
  int* counts  = (int*)alloc((size_t)NKEYS*4);
  int* cursor  = (int*)alloc((size_t)NKEYS*4);
  int* partials= (int*)alloc(8192);

  auto cdiv = [](int a, int b){ return (a + b - 1)/b; };

  // ---- CSR build (6 dispatches) ----
  hipMemsetAsync(counts, 0, (size_t)NKEYS*4, stream);
  k_hist3<<<cdiv(NEDGE,256),256,0,stream>>>(com0, com1, sup1, counts);
  int nPb = cdiv(NKEYS,256);
  k_scanA<<<nPb,256,0,stream>>>(counts, NKEYS, rp_all, partials);
  k_scanB<<<1,1024,0,stream>>>(partials, nPb, rp_all + NKEYS);
  k_scanC<<<nPb,256,0,stream>>>(rp_all, partials, NKEYS, cursor);
  k_fill3<<<cdiv(NEDGE,256),256,0,stream>>>(com0, com1, sup0, sup1, cursor, vals);
  const int* rp_t = rp_all;               // com by thesis (vals = prof)
  const int* crp  = rp_all + NT;          // com by prof (vals = thesis)
  const int* mrp  = rp_all + NT + NP;     // sup by prof (vals = thesis)

  // ---- prep ----
  k_prep<<<cdiv(NP*CDIM + 384*128 + 128*32 + 2*128*32,256),256,0,stream>>>(
      prof_emb, pid, xp0, lin_W, WmFrag, cW1, W1aFrag, WzbPerm, WzcPerm);
  for (int l = 0; l < 2; ++l)
    k_wprep<<<cdiv(49152 + 3*16384 + 128,256),256,0,stream>>>(
        gWl, gbl, gWr, l,
        WpFrag + (size_t)l*49152, Wl2Frag + (size_t)l*16384,
        Wl3Frag + (size_t)l*16384, WtFrag + (size_t)l*16384,
        bp + l*128, btp + l*128);

  // xt = sigma-bf16(thesis_x @ lin_W + lin_b)
  k_mm<384,true,false,false,false><<<cdiv(NT,128),256,0,stream>>>(
      thesis_x, NT, WmFrag, lin_b, xt,
      nullptr, nullptr, nullptr, nullptr, nullptr, nullptr,
      nullptr, nullptr, nullptr);

  ushort* xpo = xp0; ushort* xpn = xp1;
  for (int l = 0; l < 2; ++l){
    k_segsum<<<cdiv(NP,4),256,0,stream>>>((const uint*)xt, (const uint*)xpo,
                                          mrp, crp, vals, (uint*)apcat);
    k_mmp<<<dim3(cdiv(NP,128),3),256,0,stream>>>(
        apcat, xpo, l, WpFrag + (size_t)l*49152, Wl2Frag + (size_t)l*16384,
        Wl3Frag + (size_t)l*16384, bp + l*128, xpn, yp2p, yp3p);
    if (l == 0){
      // layer 0: fused gather epilogue, ReLU, write xt in place
      k_mm<128,false,true,true,false><<<cdiv(NT,128),256,0,stream>>>(
          xt, NT, WtFrag, nullptr, xt,
          sup1, rp_t, vals, yp2p, yp3p, btp,
          nullptr, nullptr, nullptr);
    } else {
      // final xp is xpn; produce zpb / zpc2(+b1) BEFORE the last thesis GEMM
      k_gemm32<<<dim3(cdiv(NP,128),2),256,0,stream>>>(
          xpn, NP, WzbPerm, WzcPerm, cb1, zpb, zpc);
      // layer 1: fused gather, no ReLU, ZT path emits zt (+ zpb[mentor] fold)
      k_mm<128,false,true,false,true><<<cdiv(NT,128),256,0,stream>>>(
          xt, NT, WtFrag + 16384, nullptr, nullptr,
          sup1, rp_t, vals, yp2p, yp3p, btp + 128,
          W1aFrag, zt, zpb);
    }
    ushort* tmp = xpo; xpo = xpn; xpn = tmp;
  }

  k_edge<<<cdiv(EL,256),256,0,stream>>>(el0, el1, zt, zpc,
                                        cW2, cb2, outp, EL);
}

// Round 2
// 948.271 us; speedup vs baseline: 1.0698x; 1.0698x over previous
//
#include <hip/hip_runtime.h>
#include <hip/hip_bf16.h>
#include <cstdint>
#include <cstddef>

#define NT 200000
#define NP 5000
#define FDIM 384
#define CDIM 128
#define EC 600000
#define EL 400000
#define NKEYS (NT + 2*NP)          // concatenated CSR segment count
#define NEDGE (2*EC + NT)          // concatenated edge count

typedef unsigned int uint;
typedef unsigned short ushort;
typedef __attribute__((ext_vector_type(8))) __bf16 bf16x8;
typedef __attribute__((ext_vector_type(4))) float f32x4;

union FragU { uint4 u; bf16x8 b; };

__device__ __forceinline__ ushort f2bf(float f){
  uint u = __float_as_uint(f);
  u = (u + 0x7fffu + ((u >> 16) & 1u)) >> 16;
  return (ushort)u;
}
__device__ __forceinline__ float bf2f(ushort h){
  return __uint_as_float(((uint)h) << 16);
}
// storage permutation: sigma(c) = (c&15)*8 + (c>>4); invs below
__device__ __forceinline__ int invs(int w){
  return ((w >> 2) & 1)*64 + (w & 3)*16 + (w >> 3);
}

// ---------------- fused CSR build ----------------
__global__ void k_hist3(const int* __restrict__ com0, const int* __restrict__ com1,
                        const int* __restrict__ sup1, int* __restrict__ counts){
  int i = blockIdx.x*256 + threadIdx.x;
  if (i < EC)            atomicAdd(&counts[com0[i]], 1);
  else if (i < 2*EC)     atomicAdd(&counts[NT + com1[i - EC]], 1);
  else if (i < NEDGE)    atomicAdd(&counts[NT + NP + sup1[i - 2*EC]], 1);
}

// local exclusive scan per 256-block + block totals
__global__ void k_scanA(const int* __restrict__ counts, int n,
                        int* __restrict__ rowptr, int* __restrict__ partials){
  __shared__ int s[256];
  int tid = threadIdx.x;
  int i = blockIdx.x*256 + tid;
  int v = (i < n) ? counts[i] : 0;
  s[tid] = v; __syncthreads();
  for (int off = 1; off < 256; off <<= 1){
    int t = (tid >= off) ? s[tid - off] : 0;
    __syncthreads();
    s[tid] += t;
    __syncthreads();
  }
  if (i < n) rowptr[i] = s[tid] - v;
  if (tid == 255) partials[blockIdx.x] = s[255];
}

__global__ void k_scanB(int* __restrict__ partials, int nP, int* __restrict__ total_out){
  __shared__ int s[1024];
  int carry = 0;
  for (int base = 0; base < nP; base += 1024){
    int i = base + threadIdx.x;
    int v = (i < nP) ? partials[i] : 0;
    s[threadIdx.x] = v; __syncthreads();
    for (int off = 1; off < 1024; off <<= 1){
      int t = (threadIdx.x >= off) ? s[threadIdx.x - off] : 0;
      __syncthreads();
      s[threadIdx.x] += t;
      __syncthreads();
    }
    if (i < nP) partials[i] = carry + s[threadIdx.x] - v;
    int chunk_total = s[1023];
    __syncthreads();
    carry += chunk_total;
  }
  if (threadIdx.x == 0 && total_out) *total_out = carry;
}

__global__ void k_scanC(int* __restrict__ rowptr, const int* __restrict__ pscan,
                        int n, int* __restrict__ cursor){
  int i = blockIdx.x*256 + threadIdx.x;
  if (i < n){
    int r = rowptr[i] + pscan[i >> 8];
    rowptr[i] = r;
    cursor[i] = r;
  }
}

__global__ void k_fill3(const int* __restrict__ com0, const int* __restrict__ com1,
                        const int* __restrict__ sup0, const int* __restrict__ sup1,
                        int* __restrict__ cursor, int* __restrict__ vals){
  int i = blockIdx.x*256 + threadIdx.x;
  int key, sv;
  if (i < EC)          { key = com0[i];                 sv = com1[i]; }
  else if (i < 2*EC)   { key = NT + com1[i - EC];       sv = com0[i - EC]; }
  else if (i < NEDGE)  { key = NT + NP + sup1[i - 2*EC]; sv = sup0[i - 2*EC]; }
  else return;
  int pos = atomicAdd(&cursor[key], 1);
  vals[pos] = sv;
}

// ---------------- prep: xp0 sigma-bf16 + WmFrag(natural) + W1aFrag(invs) + Wzb/WzcPerm ----------
__global__ void k_prep(const float* __restrict__ pe, const int* __restrict__ pid,
                       ushort* __restrict__ xp0,
                       const float* __restrict__ lin_W, ushort* __restrict__ WmFrag,
                       const float* __restrict__ cW1, ushort* __restrict__ W1aFrag,
                       float* __restrict__ WzbPerm, float* __restrict__ WzcPerm){
  int i = blockIdx.x*256 + threadIdx.x;
  if (i < NP*CDIM){                     // xp0[p][w] = bf16(pe[pid[p]][invs(w)])
    int p = i >> 7, w = i & 127;
    xp0[i] = f2bf(pe[(size_t)pid[p]*CDIM + invs(w)]);
    return;
  }
  i -= NP*CDIM;
  if (i < 384*128){                     // natural pack (A = fp32 natural)
    int j = i & 7, lane = (i >> 3) & 63, q = lane >> 4, nl = lane & 15, tl = i >> 9;
    int nt = tl & 7, kc = tl >> 3;
    int k = kc*32 + q*8 + j, n = nt*16 + nl;
    WmFrag[i] = f2bf(lin_W[(size_t)k*128 + n]);
    return;
  }
  i -= 384*128;
  if (i < 128*32){                      // invs pack (A = sigma-stored), N=32
    int j = i & 7, lane = (i >> 3) & 63, q = lane >> 4, nl = lane & 15, tl = i >> 9;
    int nt = tl & 1, kc = tl >> 1;
    int s = 32*kc + 8*q + j, n = nt*16 + nl;
    W1aFrag[i] = f2bf(cW1[(size_t)invs(s)*32 + n]);
    return;
  }
  i -= 128*32;
  if (i < 2*128*32){                    // row-permuted fp32 W for gemm32
    int m = i >> 12;                    // 0 = zpb block, 1 = zpc block
    int o = i & 4095;
    int s = o >> 5, n = o & 31;
    float v = cW1[(size_t)(128 + m*128 + invs(s))*32 + n];
    (m ? WzcPerm : WzbPerm)[o] = v;
  }
}

// ---------------- per-layer weight prep: WpFrag, Wl2Frag, Wl3Frag, WtFrag, bp, btp ----------------
__global__ void k_wprep(const float* __restrict__ gWl, const float* __restrict__ gbl,
                        const float* __restrict__ gWr, int layer,
                        ushort* __restrict__ WpFrag, ushort* __restrict__ Wl2Frag,
                        ushort* __restrict__ Wl3Frag, ushort* __restrict__ WtFrag,
                        float* __restrict__ bp, float* __restrict__ btp){
  int i = blockIdx.x*256 + threadIdx.x;
  const float* Wl_l = gWl + (size_t)layer*4*16384;
  const float* Wr_l = gWr + (size_t)layer*4*16384;
  const float* bl_l = gbl + (size_t)layer*4*128;
  if (i < 49152){                       // WpFrag: K=384, all blocks invs (A = [sig|sig|sig])
    int j = i & 7, lane = (i >> 3) & 63, q = lane >> 4, nl = lane & 15, tl = i >> 9;
    int nt = tl & 7, kc = tl >> 3;      // kc 0..11
    int s_row = 32*kc + 8*q + j;
    int b = s_row >> 7, w = s_row & 127;
    int r = invs(w), n = nt*16 + nl;
    float v;
    if (b == 0)      v = Wl_l[(size_t)r*128 + n];
    else if (b == 1) v = Wl_l[16384 + (size_t)r*128 + n];
    else             v = Wr_l[(size_t)r*128 + n] + Wr_l[16384 + (size_t)r*128 + n];
    WpFrag[i] = f2bf(v);
    return;
  }
  i -= 49152;
  if (i < 3*16384){                     // Wl2 / Wl3 / Wt frags (K=128, invs)
    int m = i >> 14;                    // 0,1,2
    int o = i & 16383;
    int j = o & 7, lane = (o >> 3) & 63, q = lane >> 4, nl = lane & 15, tl = o >> 9;
    int nt = tl & 7, kc = tl >> 3;      // kc 0..3
    int s = 32*kc + 8*q + j;
    int r = invs(s), n = nt*16 + nl;
    float v;
    if (m == 0)      v = Wl_l[2*16384 + (size_t)r*128 + n];
    else if (m == 1) v = Wl_l[3*16384 + (size_t)r*128 + n];
    else             v = Wr_l[2*16384 + (size_t)r*128 + n] + Wr_l[3*16384 + (size_t)r*128 + n];
    (m == 0 ? Wl2Frag : (m == 1 ? Wl3Frag : WtFrag))[o] = f2bf(v);
    return;
  }
  i -= 3*16384;
  if (i < 128){
    bp[i] = bl_l[i] + bl_l[128 + i];
    btp[(i & 15)*8 + (i >> 4)] = bl_l[2*128 + i] + bl_l[3*128 + i];   // sigma store
  }
}

// ---------------- segment sums: wave per prof; xt/xp sigma-bf16 in, apcat sigma-bf16 out --------
__global__ __launch_bounds__(256) void k_segsum(
    const uint* __restrict__ xt32, const uint* __restrict__ xp32,
    const int* __restrict__ mrp, const int* __restrict__ crp,
    const int* __restrict__ vall, uint* __restrict__ apcat){
  int p = blockIdx.x*4 + (threadIdx.x >> 6);
  if (p >= NP) return;
  int lane = threadIdx.x & 63;
  float s0a = 0.f, s0b = 0.f;
  {
    int j = mrp[p], je = mrp[p+1];
    for (; j + 4 <= je; j += 4){
      uint v0 = xt32[(size_t)vall[j]  *64 + lane];
      uint v1 = xt32[(size_t)vall[j+1]*64 + lane];
      uint v2 = xt32[(size_t)vall[j+2]*64 + lane];
      uint v3 = xt32[(size_t)vall[j+3]*64 + lane];
      s0a += (bf2f((ushort)(v0 & 0xffff)) + bf2f((ushort)(v1 & 0xffff)))
           + (bf2f((ushort)(v2 & 0xffff)) + bf2f((ushort)(v3 & 0xffff)));
      s0b += (bf2f((ushort)(v0 >> 16)) + bf2f((ushort)(v1 >> 16)))
           + (bf2f((ushort)(v2 >> 16)) + bf2f((ushort)(v3 >> 16)));
    }
    for (; j < je; ++j){
      uint v = xt32[(size_t)vall[j]*64 + lane];
      s0a += bf2f((ushort)(v & 0xffff));
      s0b += bf2f((ushort)(v >> 16));
    }
  }
  float s1a = 0.f, s1b = 0.f;
  {
    int j = crp[p], je = crp[p+1];
    for (; j + 4 <= je; j += 4){
      uint v0 = xt32[(size_t)vall[j]  *64 + lane];
      uint v1 = xt32[(size_t)vall[j+1]*64 + lane];
      uint v2 = xt32[(size_t)vall[j+2]*64 + lane];
      uint v3 = xt32[(size_t)vall[j+3]*64 + lane];
      s1a += (bf2f((ushort)(v0 & 0xffff)) + bf2f((ushort)(v1 & 0xffff)))
           + (bf2f((ushort)(v2 & 0xffff)) + bf2f((ushort)(v3 & 0xffff)));
      s1b += (bf2f((ushort)(v0 >> 16)) + bf2f((ushort)(v1 >> 16)))
           + (bf2f((ushort)(v2 >> 16)) + bf2f((ushort)(v3 >> 16)));
    }
    for (; j < je; ++j){
      uint v = xt32[(size_t)vall[j]*64 + lane];
      s1a += bf2f((ushort)(v & 0xffff));
      s1b += bf2f((ushort)(v >> 16));
    }
  }
  uint* row = apcat + (size_t)p*192;
  row[lane]       = (uint)f2bf(s0a) | ((uint)f2bf(s0b) << 16);
  row[64 + lane]  = (uint)f2bf(s1a) | ((uint)f2bf(s1b) << 16);
  row[128 + lane] = xp32[(size_t)p*64 + lane];
}

// ---------------- edge aggregation (bf16 sigma tables) ----------------
__global__ __launch_bounds__(256) void k_agg(
    const int* __restrict__ mentor, const int* __restrict__ rowptr,
    const int* __restrict__ vals,
    const ushort* __restrict__ yp2p, const ushort* __restrict__ yp3p,
    const float* __restrict__ btp, ushort* __restrict__ aggp){
  int t = blockIdx.x*8 + (threadIdx.x >> 5);
  if (t >= NT) return;
  int i = threadIdx.x & 31;
  float4 s = *(const float4*)(btp + i*4);
  int m = mentor[t];
  ushort4 y = *(const ushort4*)(yp2p + (size_t)m*CDIM + i*4);
  s.x += bf2f(y.x); s.y += bf2f(y.y); s.z += bf2f(y.z); s.w += bf2f(y.w);
  int qb = rowptr[t], qe = rowptr[t+1];
  for (int q = qb; q < qe; ++q){
    ushort4 z = *(const ushort4*)(yp3p + (size_t)vals[q]*CDIM + i*4);
    s.x += bf2f(z.x); s.y += bf2f(z.y); s.z += bf2f(z.z); s.w += bf2f(z.w);
  }
  ushort4 o;
  o.x = f2bf(s.x); o.y = f2bf(s.y); o.z = f2bf(s.z); o.w = f2bf(s.w);
  *(ushort4*)(aggp + (size_t)t*CDIM + i*4) = o;
}

// ---------------- thesis MFMA GEMM ----------------
// EPI: add aggp (agg'd neighbor terms + bias, from k_agg) in epilogue.
// ZT:  skip xt store; round-trip tile through LDS (stride 136) and emit
//      zt = tile @ W1a with zpb[mentor[row]] folded in (k_edge then needs
//      only 2 independent gathers per edge instead of 3 + a dependent hop).
template<int K, bool AF32, bool EPI, bool RELU, bool ZT>
__global__ __launch_bounds__(256) void k_mm(
    const void* __restrict__ Ain, int M,
    const ushort* __restrict__ Wfrag, const float* __restrict__ bias,
    ushort* __restrict__ Outp, const ushort* __restrict__ aggp,
    const ushort* __restrict__ W1a, ushort* __restrict__ ztout,
    const int* __restrict__ mentor, const ushort* __restrict__ zpb){
  constexpr int SMSZ = ZT ? 2176 : 1024;      // uint4 units (ZT: 34816 B tile overlay)
  __shared__ uint4 smem[SMSZ];
  uint4* As = smem;
  uint4* Bs = smem + 512;
  ushort* tile = (ushort*)smem;               // 128 x 136, used after K-loop only
  const int tid  = threadIdx.x;
  const int lane = tid & 63;
  const int wave = tid >> 6;
  const int wr   = wave >> 1, wc = wave & 1;
  const int m0   = blockIdx.x * 128;
  const float* Af = (const float*)Ain;
  const ushort* Ab = (const ushort*)Ain;

  f32x4 acc[4][4];
  #pragma unroll
  for (int i = 0; i < 4; ++i)
    #pragma unroll
    for (int j = 0; j < 4; ++j) acc[i][j] = (f32x4)(0.f);

  for (int kc = 0; kc < K/32; ++kc){
    if (AF32){
      const int rs = tid >> 2, qs = tid & 3;
      #pragma unroll
      for (int h = 0; h < 2; ++h){
        int rr = rs + 64*h;
        int grow = m0 + rr;
        uint4 payload = make_uint4(0,0,0,0);
        if (grow < M){
          const float* ap = Af + (size_t)grow*K + kc*32 + qs*8;
          float4 fa = *(const float4*)ap;
          float4 fb = *(const float4*)(ap + 4);
          payload.x = (uint)f2bf(fa.x) | ((uint)f2bf(fa.y) << 16);
          payload.y = (uint)f2bf(fa.z) | ((uint)f2bf(fa.w) << 16);
          payload.z = (uint)f2bf(fb.x) | ((uint)f2bf(fb.y) << 16);
          payload.w = (uint)f2bf(fb.z) | ((uint)f2bf(fb.w) << 16);
        }
        As[(rr >> 4)*64 + qs*16 + (rr & 15)] = payload;
      }
    } else {
      #pragma unroll
      for (int h = 0; h < 2; ++h){
        int e = tid + 256*h;
        int rr = e >> 2, q = e & 3;
        int grow = m0 + rr;
        uint4 payload = make_uint4(0,0,0,0);
        if (grow < M)
          payload = *(const uint4*)(Ab + (size_t)grow*K + (4*kc + q)*8);
        As[(rr >> 4)*64 + q*16 + (rr & 15)] = payload;
      }
    }
    const uint4* wsrc = (const uint4*)Wfrag + (size_t)kc*512;
    Bs[tid]       = wsrc[tid];
    Bs[tid + 256] = wsrc[tid + 256];
    __syncthreads();

    bf16x8 a[4], b[4];
    #pragma unroll
    for (int i = 0; i < 4; ++i){ FragU u; u.u = As[(wr*4 + i)*64 + lane]; a[i] = u.b; }
    #pragma unroll
    for (int j = 0; j < 4; ++j){ FragU u; u.u = Bs[(wc*4 + j)*64 + lane]; b[j] = u.b; }
    #pragma unroll
    for (int i = 0; i < 4; ++i)
      #pragma unroll
      for (int j = 0; j < 4; ++j)
        acc[i][j] = __builtin_amdgcn_mfma_f32_16x16x32_bf16(a[i], b[j], acc[i][j], 0, 0, 0);
    __syncthreads();
  }

  // --- epilogue ---
  const int nl = lane & 15;
  float bv[4];
  #pragma unroll
  for (int j = 0; j < 4; ++j) bv[j] = bias ? bias[wc*64 + j*16 + nl] : 0.f;
  const int s0 = nl*8 + wc*4;

  #pragma unroll
  for (int i = 0; i < 4; ++i){
    int rb = wr*64 + i*16 + (lane >> 4)*4;
    #pragma unroll
    for (int reg = 0; reg < 4; ++reg){
      int rr = rb + reg;
      int row = m0 + rr;
      if (row >= M) continue;
      float v0 = acc[i][0][reg] + bv[0];
      float v1 = acc[i][1][reg] + bv[1];
      float v2 = acc[i][2][reg] + bv[2];
      float v3 = acc[i][3][reg] + bv[3];
      if (EPI){
        ushort4 av = *(const ushort4*)(aggp + (size_t)row*CDIM + s0);
        v0 += bf2f(av.x); v1 += bf2f(av.y); v2 += bf2f(av.z); v3 += bf2f(av.w);
      }
      if (RELU){
        v0 = v0 > 0.f ? v0 : 0.f; v1 = v1 > 0.f ? v1 : 0.f;
        v2 = v2 > 0.f ? v2 : 0.f; v3 = v3 > 0.f ? v3 : 0.f;
      }
      ushort4 o;
      o.x = f2bf(v0); o.y = f2bf(v1); o.z = f2bf(v2); o.w = f2bf(v3);
      if (ZT) *(ushort4*)&tile[(size_t)rr*136 + s0] = o;
      else    *(ushort4*)(Outp + (size_t)row*CDIM + s0) = o;
    }
  }

  if (ZT){
    __syncthreads();
    const uint4* wf = (const uint4*)W1a;
    const int q = lane >> 4, mm = lane & 15;
    f32x4 acc2[2][2];
    #pragma unroll
    for (int a2 = 0; a2 < 2; ++a2)
      #pragma unroll
      for (int b2 = 0; b2 < 2; ++b2) acc2[a2][b2] = (f32x4)(0.f);
    #pragma unroll
    for (int kc = 0; kc < 4; ++kc){
      bf16x8 af[2];
      #pragma unroll
      for (int i2 = 0; i2 < 2; ++i2){
        FragU u;
        u.u = *(const uint4*)&tile[(size_t)(wave*32 + i2*16 + mm)*136 + (4*kc + q)*8];
        af[i2] = u.b;
      }
      #pragma unroll
      for (int nt = 0; nt < 2; ++nt){
        FragU u; u.u = wf[(kc*2 + nt)*64 + lane];
        #pragma unroll
        for (int i2 = 0; i2 < 2; ++i2)
          acc2[i2][nt] = __builtin_amdgcn_mfma_f32_16x16x32_bf16(af[i2], u.b, acc2[i2][nt], 0, 0, 0);
      }
    }
    #pragma unroll
    for (int i2 = 0; i2 < 2; ++i2){
      #pragma unroll
      for (int reg = 0; reg < 4; ++reg){
        int row = m0 + wave*32 + i2*16 + q*4 + reg;
        if (row >= M) continue;
        int m = mentor[row];   // fold zpb[mentor] into zt (fp32 pre-round)
        ztout[(size_t)row*32 + mm]      =
            f2bf(acc2[i2][0][reg] + bf2f(zpb[(size_t)m*32 + mm]));
        ztout[(size_t)row*32 + 16 + mm] =
            f2bf(acc2[i2][1][reg] + bf2f(zpb[(size_t)m*32 + 16 + mm]));
      }
    }
  }
}

// ---------------- prof MFMA GEMM: y = {xp-update(K=384), yp2, yp3} ----------------
__global__ __launch_bounds__(256) void k_mmp(
    const ushort* __restrict__ apcat, const ushort* __restrict__ xpold, int layer,
    const ushort* __restrict__ WpFrag, const ushort* __restrict__ Wl2Frag,
    const ushort* __restrict__ Wl3Frag, const float* __restrict__ bp,
    ushort* __restrict__ xpnew, ushort* __restrict__ yp2p, ushort* __restrict__ yp3p){
  const int y = blockIdx.y;
  const ushort* A; const ushort* Wf; const float* bias; ushort* Out;
  int nkc, rowlen; bool relu;
  if (y == 0){ A = apcat; rowlen = 384; nkc = 12; Wf = WpFrag; bias = bp;
               Out = xpnew; relu = (layer == 0); }
  else if (y == 1){ A = xpold; rowlen = 128; nkc = 4; Wf = Wl2Frag; bias = nullptr;
               Out = yp2p; relu = false; }
  else       { A = xpold; rowlen = 128; nkc = 4; Wf = Wl3Frag; bias = nullptr;
               Out = yp3p; relu = false; }

  __shared__ uint4 As[512];
  __shared__ uint4 Bs[512];
  const int tid  = threadIdx.x;
  const int lane = tid & 63;
  const int wave = tid >> 6;
  const int wr   = wave >> 1, wc = wave & 1;
  const int m0   = blockIdx.x * 128;

  f32x4 acc[4][4];
  #pragma unroll
  for (int i = 0; i < 4; ++i)
    #pragma unroll
    for (int j = 0; j < 4; ++j) acc[i][j] = (f32x4)(0.f);

  for (int kc = 0; kc < nkc; ++kc){
    #pragma unroll
    for (int h = 0; h < 2; ++h){
      int e = tid + 256*h;
      int rr = e >> 2, q = e & 3;
      int grow = m0 + rr;
      uint4 payload = make_uint4(0,0,0,0);
      if (grow < NP)
        payload = *(const uint4*)(A + (size_t)grow*rowlen + (4*kc + q)*8);
      As[(rr >> 4)*64 + q*16 + (rr & 15)] = payload;
    }
    const uint4* wsrc = (const uint4*)Wf + (size_t)kc*512;
    Bs[tid]       = wsrc[tid];
    Bs[tid + 256] = wsrc[tid + 256];
    __syncthreads();

    bf16x8 a[4], b[4];
    #pragma unroll
    for (int i = 0; i < 4; ++i){ FragU u; u.u = As[(wr*4 + i)*64 + lane]; a[i] = u.b; }
    #pragma unroll
    for (int j = 0; j < 4; ++j){ FragU u; u.u = Bs[(wc*4 + j)*64 + lane]; b[j] = u.b; }
    #pragma unroll
    for (int i = 0; i < 4; ++i)
      #pragma unroll
      for (int j = 0; j < 4; ++j)
        acc[i][j] = __builtin_amdgcn_mfma_f32_16x16x32_bf16(a[i], b[j], acc[i][j], 0, 0, 0);
    __syncthreads();
  }

  const int nl = lane & 15;
  float bv[4];
  #pragma unroll
  for (int j = 0; j < 4; ++j) bv[j] = bias ? bias[wc*64 + j*16 + nl] : 0.f;
  const int s0 = nl*8 + wc*4;

  #pragma unroll
  for (int i = 0; i < 4; ++i){
    int r0 = m0 + wr*64 + i*16 + (lane >> 4)*4;
    #pragma unroll
    for (int reg = 0; reg < 4; ++reg){
      int row = r0 + reg;
      if (row >= NP) continue;
      float v0 = acc[i][0][reg] + bv[0];
      float v1 = acc[i][1][reg] + bv[1];
      float v2 = acc[i][2][reg] + bv[2];
      float v3 = acc[i][3][reg] + bv[3];
      if (relu){
        v0 = v0 > 0.f ? v0 : 0.f; v1 = v1 > 0.f ? v1 : 0.f;
        v2 = v2 > 0.f ? v2 : 0.f; v3 = v3 > 0.f ? v3 : 0.f;
      }
      ushort4 o;
      o.x = f2bf(v0); o.y = f2bf(v1); o.z = f2bf(v2); o.w = f2bf(v3);
      *(ushort4*)(Out + (size_t)row*CDIM + s0) = o;
    }
  }
}

// ---------------- N=32 GEMM (prof zpb/zpc): A sigma-bf16, W row-permuted fp32 ----------------
// blockIdx.y==1 (zpc) additionally folds the classifier hidden bias b1.
__global__ __launch_bounds__(256) void k_gemm32(const ushort* __restrict__ A, int M,
                                                const float* __restrict__ W0,
                                                const float* __restrict__ W1,
                                                const float* __restrict__ b1,
                                                ushort* __restrict__ Out0,
                                                ushort* __restrict__ Out1){
  const float* W = blockIdx.y ? W1 : W0;
  ushort* Out = blockIdx.y ? Out1 : Out0;
  __shared__ float As[128*36];
  __shared__ float Ws[32*32];
  const int tid  = threadIdx.x;
  const int m0   = blockIdx.x*128;
  const int c4   = (tid & 7)*4;
  const int rowg = tid >> 3;
  float4 acc[4];
  #pragma unroll
  for (int j = 0; j < 4; ++j) acc[j] = make_float4(0.f,0.f,0.f,0.f);

  for (int k0 = 0; k0 < 128; k0 += 32){
    #pragma unroll
    for (int l = 0; l < 4; ++l){
      int q = tid + 256*l;
      int r = q >> 3, kf = q & 7;
      int row = m0 + r;
      float4 v = make_float4(0.f,0.f,0.f,0.f);
      if (row < M){
        ushort4 u = *(const ushort4*)(A + (size_t)row*CDIM + k0 + kf*4);
        v = make_float4(bf2f(u.x), bf2f(u.y), bf2f(u.z), bf2f(u.w));
      }
      *(float4*)&As[r*36 + kf*4] = v;
    }
    {
      int kk = tid >> 3, cf = tid & 7;
      *(float4*)&Ws[kk*32 + cf*4] = *(const float4*)(W + (size_t)(k0+kk)*32 + cf*4);
    }
    __syncthreads();
    #pragma unroll
    for (int k4 = 0; k4 < 8; ++k4){
      float4 w0 = *(const float4*)&Ws[(k4*4+0)*32 + c4];
      float4 w1 = *(const float4*)&Ws[(k4*4+1)*32 + c4];
      float4 w2 = *(const float4*)&Ws[(k4*4+2)*32 + c4];
      float4 w3 = *(const float4*)&Ws[(k4*4+3)*32 + c4];
      #pragma unroll
      for (int j = 0; j < 4; ++j){
        float4 a = *(const float4*)&As[(rowg + 32*j)*36 + k4*4];
        acc[j].x += a.x*w0.x + a.y*w1.x + a.z*w2.x + a.w*w3.x;
        acc[j].y += a.x*w0.y + a.y*w1.y + a.z*w2.y + a.w*w3.y;
        acc[j].z += a.x*w0.z + a.y*w1.z + a.z*w2.z + a.w*w3.z;
        acc[j].w += a.x*w0.w + a.y*w1.w + a.z*w2.w + a.w*w3.w;
      }
    }
    __syncthreads();
  }
  float4 bb = make_float4(0.f,0.f,0.f,0.f);
  if (blockIdx.y) bb = *(const float4*)(b1 + c4);
  #pragma unroll
  for (int j = 0; j < 4; ++j){
    int row = m0 + rowg + 32*j;
    if (row < M){
      ushort4 o;
      o.x = f2bf(acc[j].x + bb.x); o.y = f2bf(acc[j].y + bb.y);
      o.z = f2bf(acc[j].z + bb.z); o.w = f2bf(acc[j].w + bb.w);
      *(ushort4*)(Out + (size_t)row*32 + c4) = o;
    }
  }
}

// ---------------- edge classifier: zt2 already contains zpb[mentor]; zpc2 contains b1 ------------
__global__ __launch_bounds__(256) void k_edge(
    const int* __restrict__ el0, const int* __restrict__ el1,
    const ushort* __restrict__ zt2, const ushort* __restrict__ zpc2,
    const float* __restrict__ W2, const float* __restrict__ b2,
    float* __restrict__ out, int n){
  __shared__ float sW[32];
  if (threadIdx.x < 32) sW[threadIdx.x] = W2[threadIdx.x];
  __syncthreads();
  int e = blockIdx.x*256 + threadIdx.x;
  if (e >= n) return;
  int t = el0[e], p = el1[e];
  const uint4* zr = (const uint4*)(zt2  + (size_t)t*32);
  const uint4* cr = (const uint4*)(zpc2 + (size_t)p*32);
  float acc = 0.f;
  #pragma unroll
  for (int i = 0; i < 4; ++i){   // 4 uint4 = 32 bf16 hidden units
    uint4 ua = zr[i], uc = cr[i];
    const uint aw[4] = {ua.x, ua.y, ua.z, ua.w};
    const uint cw[4] = {uc.x, uc.y, uc.z, uc.w};
    #pragma unroll
    for (int k = 0; k < 4; ++k){
      int base = i*8 + k*2;
      float h0 = bf2f((ushort)(aw[k] & 0xffff)) + bf2f((ushort)(cw[k] & 0xffff));
      float h1 = bf2f((ushort)(aw[k] >> 16)) + bf2f((ushort)(cw[k] >> 16));
      h0 = h0 > 0.f ? h0 : 0.f;
      h1 = h1 > 0.f ? h1 : 0.f;
      acc = fmaf(h0, sW[base], acc);
      acc = fmaf(h1, sW[base + 1], acc);
    }
  }
  out[e] = acc + b2[0];
}

// ---------------- launch ----------------
extern "C" void kernel_launch(void* const* d_in, const int* in_sizes, int n_in,
                              void* d_out, int out_size, void* d_ws, size_t ws_size,
                              hipStream_t stream){
  const float* thesis_x = (const float*)d_in[0];
  const float* lin_W    = (const float*)d_in[1];
  const float* lin_b    = (const float*)d_in[2];
  const float* prof_emb = (const float*)d_in[3];
  const float* gWl      = (const float*)d_in[4];
  const float* gbl      = (const float*)d_in[5];
  const float* gWr      = (const float*)d_in[6];
  const float* cW1      = (const float*)d_in[7];
  const float* cb1      = (const float*)d_in[8];
  const float* cW2      = (const float*)d_in[9];
  const float* cb2      = (const float*)d_in[10];
  const int*   pid      = (const int*)d_in[11];
  const int*   sup0     = (const int*)d_in[12];
  const int*   sup1     = sup0 + NT;
  const int*   com0     = (const int*)d_in[13];
  const int*   com1     = com0 + EC;
  const int*   el0      = (const int*)d_in[14];
  const int*   el1      = el0 + EL;
  float* outp = (float*)d_out;

  char* base = (char*)d_ws;
  size_t off = 0;
  auto alloc = [&](size_t bytes)->void*{
    void* p = base + off;
    off += (bytes + 255) & ~(size_t)255;
    return p;
  };
  ushort* xt      = (ushort*)alloc((size_t)NT*CDIM*2);   // sigma-bf16
  ushort* aggp    = (ushort*)alloc((size_t)NT*CDIM*2);   // sigma-bf16
  ushort* zt      = (ushort*)alloc((size_t)NT*32*2);     // natural bf16 (incl. zpb[mentor])
  ushort* xp0     = (ushort*)alloc((size_t)NP*CDIM*2);   // sigma-bf16
  ushort* xp1     = (ushort*)alloc((size_t)NP*CDIM*2);
  ushort* apcat   = (ushort*)alloc((size_t)NP*384*2);    // [sig|sig|sig] bf16
  ushort* yp2p    = (ushort*)alloc((size_t)NP*CDIM*2);
  ushort* yp3p    = (ushort*)alloc((size_t)NP*CDIM*2);
  ushort* WmFrag  = (ushort*)alloc((size_t)384*128*2);
  ushort* W1aFrag = (ushort*)alloc((size_t)128*32*2);
  float*  WzbPerm = (float*)alloc((size_t)128*32*4);
  float*  WzcPerm = (float*)alloc((size_t)128*32*4);
  ushort* WpFrag  = (ushort*)alloc((size_t)2*384*128*2);
  ushort* Wl2Frag = (ushort*)alloc((size_t)2*128*128*2);
  ushort* Wl3Frag = (ushort*)alloc((size_t)2*128*128*2);
  ushort* WtFrag  = (ushort*)alloc((size_t)2*128*128*2);
  float*  bp      = (float*)alloc(2*512);
  float*  btp     = (float*)alloc(2*512);
  ushort* zpb     = (ushort*)alloc((size_t)NP*32*2);
  ushort* zpc     = (ushort*)alloc((size_t)NP*32*2);     // zpc2 = zpc + b1
  int* rp_all  = (int*)alloc((size_t)(NKEYS+1)*4);
  int* vals    = (int*)alloc((size_t)NEDGE*4);
  int* counts  = (int*)alloc((size_t)NKEYS*4);
  int* cursor  = (int*)alloc((size_t)NKEYS*4);
  int* partials= (int*)alloc(8192);

  auto cdiv = [](int a, int b){ return (a + b - 1)/b; };

  // ---- CSR build (6 dispatches) ----
  hipMemsetAsync(counts, 0, (size_t)NKEYS*4, stream);
  k_hist3<<<cdiv(NEDGE,256),256,0,stream>>>(com0, com1, sup1, counts);
  int nPb = cdiv(NKEYS,256);
  k_scanA<<<nPb,256,0,stream>>>(counts, NKEYS, rp_all, partials);
  k_scanB<<<1,1024,0,stream>>>(partials, nPb, rp_all + NKEYS);
  k_scanC<<<nPb,256,0,stream>>>(rp_all, partials, NKEYS, cursor);
  k_fill3<<<cdiv(NEDGE,256),256,0,stream>>>(com0, com1, sup0, sup1, cursor, vals);
  const int* rp_t = rp_all;               // com by thesis (vals = prof)
  const int* crp  = rp_all + NT;          // com by prof (vals = thesis)
  const int* mrp  = rp_all + NT + NP;     // sup by prof (vals = thesis)

  // ---- prep ----
  k_prep<<<cdiv(NP*CDIM + 384*128 + 128*32 + 2*128*32,256),256,0,stream>>>(
      prof_emb, pid, xp0, lin_W, WmFrag, cW1, W1aFrag, WzbPerm, WzcPerm);
  for (int l = 0; l < 2; ++l)
    k_wprep<<<cdiv(49152 + 3*16384 + 128,256),256,0,stream>>>(
        gWl, gbl, gWr, l,
        WpFrag + (size_t)l*49152, Wl2Frag + (size_t)l*16384,
        Wl3Frag + (size_t)l*16384, WtFrag + (size_t)l*16384,
        bp + l*128, btp + l*128);

  // xt = sigma-bf16(thesis_x @ lin_W + lin_b)
  k_mm<384,true,false,false,false><<<cdiv(NT,128),256,0,stream>>>(
      thesis_x, NT, WmFrag, lin_b, xt, nullptr, nullptr, nullptr,
      nullptr, nullptr);

  ushort* xpo = xp0; ushort* xpn = xp1;
  for (int l = 0; l < 2; ++l){
    k_segsum<<<cdiv(NP,4),256,0,stream>>>((const uint*)xt, (const uint*)xpo,
                                          mrp, crp, vals, (uint*)apcat);
    k_mmp<<<dim3(cdiv(NP,128),3),256,0,stream>>>(
        apcat, xpo, l, WpFrag + (size_t)l*49152, Wl2Frag + (size_t)l*16384,
        Wl3Frag + (size_t)l*16384, bp + l*128, xpn, yp2p, yp3p);
    if (l == 1){
      // final xp is xpn; produce zpb / zpc2(+b1) before the ZT thesis GEMM
      k_gemm32<<<dim3(cdiv(NP,128),2),256,0,stream>>>(
          xpn, NP, WzbPerm, WzcPerm, cb1, zpb, zpc);
    }
    k_agg<<<cdiv(NT,8),256,0,stream>>>(sup1, rp_t, vals, yp2p, yp3p, btp + l*128, aggp);
    if (l == 0)
      k_mm<128,false,true,true,false><<<cdiv(NT,128),256,0,stream>>>(
          xt, NT, WtFrag, nullptr, xt, aggp, nullptr, nullptr,
          nullptr, nullptr);
    else
      k_mm<128,false,true,false,true><<<cdiv(NT,128),256,0,stream>>>(
          xt, NT, WtFrag + 16384, nullptr, nullptr, aggp, W1aFrag, zt,
          sup1, zpb);
    ushort* tmp = xpo; xpo = xpn; xpn = tmp;
  }

  k_edge<<<cdiv(EL,256),256,0,stream>>>(el0, el1, zt, zpc,
                                        cW2, cb2, outp, EL);
}

// Round 3
// 945.616 us; speedup vs baseline: 1.0728x; 1.0028x over previous
//
#include <hip/hip_runtime.h>
#include <hip/hip_bf16.h>
#include <cstdint>
#include <cstddef>

#define NT 200000
#define NP 5000
#define FDIM 384
#define CDIM 128
#define EC 600000
#define EL 400000
#define NKEYS (NT + 2*NP)          // concatenated CSR segment count
#define NEDGE (2*EC + NT)          // concatenated edge count

typedef unsigned int uint;
typedef unsigned short ushort;
typedef __attribute__((ext_vector_type(8))) __bf16 bf16x8;
typedef __attribute__((ext_vector_type(4))) float f32x4;

union FragU { uint4 u; bf16x8 b; };

__device__ __forceinline__ ushort f2bf(float f){
  uint u = __float_as_uint(f);
  u = (u + 0x7fffu + ((u >> 16) & 1u)) >> 16;
  return (ushort)u;
}
__device__ __forceinline__ float bf2f(ushort h){
  return __uint_as_float(((uint)h) << 16);
}
// storage permutation: sigma(c) = (c&15)*8 + (c>>4); invs below
__device__ __forceinline__ int invs(int w){
  return ((w >> 2) & 1)*64 + (w & 3)*16 + (w >> 3);
}

// ---------------- fused CSR build ----------------
__global__ void k_hist3(const int* __restrict__ com0, const int* __restrict__ com1,
                        const int* __restrict__ sup1, int* __restrict__ counts){
  int i = blockIdx.x*256 + threadIdx.x;
  if (i < EC)            atomicAdd(&counts[com0[i]], 1);
  else if (i < 2*EC)     atomicAdd(&counts[NT + com1[i - EC]], 1);
  else if (i < NEDGE)    atomicAdd(&counts[NT + NP + sup1[i - 2*EC]], 1);
}

// local exclusive scan per 256-block + block totals
__global__ void k_scanA(const int* __restrict__ counts, int n,
                        int* __restrict__ rowptr, int* __restrict__ partials){
  __shared__ int s[256];
  int tid = threadIdx.x;
  int i = blockIdx.x*256 + tid;
  int v = (i < n) ? counts[i] : 0;
  s[tid] = v; __syncthreads();
  for (int off = 1; off < 256; off <<= 1){
    int t = (tid >= off) ? s[tid - off] : 0;
    __syncthreads();
    s[tid] += t;
    __syncthreads();
  }
  if (i < n) rowptr[i] = s[tid] - v;
  if (tid == 255) partials[blockIdx.x] = s[255];
}

__global__ void k_scanB(int* __restrict__ partials, int nP, int* __restrict__ total_out){
  __shared__ int s[1024];
  int carry = 0;
  for (int base = 0; base < nP; base += 1024){
    int i = base + threadIdx.x;
    int v = (i < nP) ? partials[i] : 0;
    s[threadIdx.x] = v; __syncthreads();
    for (int off = 1; off < 1024; off <<= 1){
      int t = (threadIdx.x >= off) ? s[threadIdx.x - off] : 0;
      __syncthreads();
      s[threadIdx.x] += t;
      __syncthreads();
    }
    if (i < nP) partials[i] = carry + s[threadIdx.x] - v;
    int chunk_total = s[1023];
    __syncthreads();
    carry += chunk_total;
  }
  if (threadIdx.x == 0 && total_out) *total_out = carry;
}

__global__ void k_scanC(int* __restrict__ rowptr, const int* __restrict__ pscan,
                        int n, int* __restrict__ cursor){
  int i = blockIdx.x*256 + threadIdx.x;
  if (i < n){
    int r = rowptr[i] + pscan[i >> 8];
    rowptr[i] = r;
    cursor[i] = r;
  }
}

__global__ void k_fill3(const int* __restrict__ com0, const int* __restrict__ com1,
                        const int* __restrict__ sup0, const int* __restrict__ sup1,
                        int* __restrict__ cursor, int* __restrict__ vals){
  int i = blockIdx.x*256 + threadIdx.x;
  int key, sv;
  if (i < EC)          { key = com0[i];                 sv = com1[i]; }
  else if (i < 2*EC)   { key = NT + com1[i - EC];       sv = com0[i - EC]; }
  else if (i < NEDGE)  { key = NT + NP + sup1[i - 2*EC]; sv = sup0[i - 2*EC]; }
  else return;
  int pos = atomicAdd(&cursor[key], 1);
  vals[pos] = sv;
}

// ---------------- prep: xp0 sigma-bf16 + WmFrag(natural) + VzPerm + Wzb/WzcPerm ----------
__global__ void k_prep(const float* __restrict__ pe, const int* __restrict__ pid,
                       ushort* __restrict__ xp0,
                       const float* __restrict__ lin_W, ushort* __restrict__ WmFrag,
                       const float* __restrict__ cW1, float* __restrict__ VzPerm,
                       float* __restrict__ WzbPerm, float* __restrict__ WzcPerm){
  int i = blockIdx.x*256 + threadIdx.x;
  if (i < NP*CDIM){                     // xp0[p][w] = bf16(pe[pid[p]][invs(w)])
    int p = i >> 7, w = i & 127;
    xp0[i] = f2bf(pe[(size_t)pid[p]*CDIM + invs(w)]);
    return;
  }
  i -= NP*CDIM;
  if (i < 384*128){                     // natural pack (A = fp32 natural)
    int j = i & 7, lane = (i >> 3) & 63, q = lane >> 4, nl = lane & 15, tl = i >> 9;
    int nt = tl & 7, kc = tl >> 3;
    int k = kc*32 + q*8 + j, n = nt*16 + nl;
    WmFrag[i] = f2bf(lin_W[(size_t)k*128 + n]);
    return;
  }
  i -= 384*128;
  if (i < 128*32){                      // VzPerm: V rows invs-permuted, fp32
    int s = i >> 5, n = i & 31;
    VzPerm[i] = cW1[(size_t)invs(s)*32 + n];
    return;
  }
  i -= 128*32;
  if (i < 2*128*32){                    // row-permuted fp32 W for g32 (zpb/zpc blocks)
    int m = i >> 12;                    // 0 = zpb block, 1 = zpc block
    int o = i & 4095;
    int s = o >> 5, n = o & 31;
    float v = cW1[(size_t)(128 + m*128 + invs(s))*32 + n];
    (m ? WzcPerm : WzbPerm)[o] = v;
  }
}

// ---------------- per-layer weight prep: WpFrag, Wl2Frag, Wl3Frag, WtFrag, bp, btp ----------------
__global__ void k_wprep(const float* __restrict__ gWl, const float* __restrict__ gbl,
                        const float* __restrict__ gWr, int layer,
                        ushort* __restrict__ WpFrag, ushort* __restrict__ Wl2Frag,
                        ushort* __restrict__ Wl3Frag, ushort* __restrict__ WtFrag,
                        float* __restrict__ bp, float* __restrict__ btp){
  int i = blockIdx.x*256 + threadIdx.x;
  const float* Wl_l = gWl + (size_t)layer*4*16384;
  const float* Wr_l = gWr + (size_t)layer*4*16384;
  const float* bl_l = gbl + (size_t)layer*4*128;
  if (i < 49152){                       // WpFrag: K=384, all blocks invs (A = [sig|sig|sig])
    int j = i & 7, lane = (i >> 3) & 63, q = lane >> 4, nl = lane & 15, tl = i >> 9;
    int nt = tl & 7, kc = tl >> 3;      // kc 0..11
    int s_row = 32*kc + 8*q + j;
    int b = s_row >> 7, w = s_row & 127;
    int r = invs(w), n = nt*16 + nl;
    float v;
    if (b == 0)      v = Wl_l[(size_t)r*128 + n];
    else if (b == 1) v = Wl_l[16384 + (size_t)r*128 + n];
    else             v = Wr_l[(size_t)r*128 + n] + Wr_l[16384 + (size_t)r*128 + n];
    WpFrag[i] = f2bf(v);
    return;
  }
  i -= 49152;
  if (i < 3*16384){                     // Wl2 / Wl3 / Wt frags (K=128, invs)
    int m = i >> 14;                    // 0,1,2
    int o = i & 16383;
    int j = o & 7, lane = (o >> 3) & 63, q = lane >> 4, nl = lane & 15, tl = o >> 9;
    int nt = tl & 7, kc = tl >> 3;      // kc 0..3
    int s = 32*kc + 8*q + j;
    int r = invs(s), n = nt*16 + nl;
    float v;
    if (m == 0)      v = Wl_l[2*16384 + (size_t)r*128 + n];
    else if (m == 1) v = Wl_l[3*16384 + (size_t)r*128 + n];
    else             v = Wr_l[2*16384 + (size_t)r*128 + n] + Wr_l[3*16384 + (size_t)r*128 + n];
    (m == 0 ? Wl2Frag : (m == 1 ? Wl3Frag : WtFrag))[o] = f2bf(v);
    return;
  }
  i -= 3*16384;
  if (i < 128){
    bp[i] = bl_l[i] + bl_l[128 + i];
    btp[(i & 15)*8 + (i >> 4)] = bl_l[2*128 + i] + bl_l[3*128 + i];   // sigma store
  }
}

// ---------------- layer-1 weight fold: VtPerm = invs-perm(Wt1 @ V), btz = bt1 @ V -------------
// Wt1 = Wr[1][2] + Wr[1][3] (natural 128x128), V = cW1 rows 0..127 (128x32).
__global__ void k_fuse32(const float* __restrict__ gWr, const float* __restrict__ gbl,
                         const float* __restrict__ cW1,
                         float* __restrict__ VtPerm, float* __restrict__ btz){
  __shared__ float Vs[128*32];
  int tid = threadIdx.x;
  for (int i = tid; i < 4096; i += 256) Vs[i] = cW1[i];
  __syncthreads();
  const float* Wr2 = gWr + (size_t)4*16384 + 2*16384;
  const float* Wr3 = gWr + (size_t)4*16384 + 3*16384;
  int i = blockIdx.x*256 + tid;         // 16 blocks x 256 = 4096 outputs
  {
    int s = i >> 5, n = i & 31;
    int r = invs(s);
    float acc = 0.f;
    for (int c = 0; c < 128; ++c)
      acc += (Wr2[r*128 + c] + Wr3[r*128 + c]) * Vs[c*32 + n];
    VtPerm[i] = acc;
  }
  if (blockIdx.x == 0 && tid < 32){
    const float* b2 = gbl + 4*128 + 2*128;
    const float* b3 = gbl + 4*128 + 3*128;
    float acc = 0.f;
    for (int c = 0; c < 128; ++c)
      acc += (b2[c] + b3[c]) * Vs[c*32 + tid];
    btz[tid] = acc;
  }
}

// ---------------- segment sums: wave per prof; xt/xp sigma-bf16 in, apcat sigma-bf16 out --------
__global__ __launch_bounds__(256) void k_segsum(
    const uint* __restrict__ xt32, const uint* __restrict__ xp32,
    const int* __restrict__ mrp, const int* __restrict__ crp,
    const int* __restrict__ vall, uint* __restrict__ apcat){
  int p = blockIdx.x*4 + (threadIdx.x >> 6);
  if (p >= NP) return;
  int lane = threadIdx.x & 63;
  float s0a = 0.f, s0b = 0.f;
  {
    int j = mrp[p], je = mrp[p+1];
    for (; j + 4 <= je; j += 4){
      uint v0 = xt32[(size_t)vall[j]  *64 + lane];
      uint v1 = xt32[(size_t)vall[j+1]*64 + lane];
      uint v2 = xt32[(size_t)vall[j+2]*64 + lane];
      uint v3 = xt32[(size_t)vall[j+3]*64 + lane];
      s0a += (bf2f((ushort)(v0 & 0xffff)) + bf2f((ushort)(v1 & 0xffff)))
           + (bf2f((ushort)(v2 & 0xffff)) + bf2f((ushort)(v3 & 0xffff)));
      s0b += (bf2f((ushort)(v0 >> 16)) + bf2f((ushort)(v1 >> 16)))
           + (bf2f((ushort)(v2 >> 16)) + bf2f((ushort)(v3 >> 16)));
    }
    for (; j < je; ++j){
      uint v = xt32[(size_t)vall[j]*64 + lane];
      s0a += bf2f((ushort)(v & 0xffff));
      s0b += bf2f((ushort)(v >> 16));
    }
  }
  float s1a = 0.f, s1b = 0.f;
  {
    int j = crp[p], je = crp[p+1];
    for (; j + 4 <= je; j += 4){
      uint v0 = xt32[(size_t)vall[j]  *64 + lane];
      uint v1 = xt32[(size_t)vall[j+1]*64 + lane];
      uint v2 = xt32[(size_t)vall[j+2]*64 + lane];
      uint v3 = xt32[(size_t)vall[j+3]*64 + lane];
      s1a += (bf2f((ushort)(v0 & 0xffff)) + bf2f((ushort)(v1 & 0xffff)))
           + (bf2f((ushort)(v2 & 0xffff)) + bf2f((ushort)(v3 & 0xffff)));
      s1b += (bf2f((ushort)(v0 >> 16)) + bf2f((ushort)(v1 >> 16)))
           + (bf2f((ushort)(v2 >> 16)) + bf2f((ushort)(v3 >> 16)));
    }
    for (; j < je; ++j){
      uint v = xt32[(size_t)vall[j]*64 + lane];
      s1a += bf2f((ushort)(v & 0xffff));
      s1b += bf2f((ushort)(v >> 16));
    }
  }
  uint* row = apcat + (size_t)p*192;
  row[lane]       = (uint)f2bf(s0a) | ((uint)f2bf(s0b) << 16);
  row[64 + lane]  = (uint)f2bf(s1a) | ((uint)f2bf(s1b) << 16);
  row[128 + lane] = xp32[(size_t)p*64 + lane];
}

// ---------------- edge aggregation, 128-wide (layer 0 only) ----------------
__global__ __launch_bounds__(256) void k_agg(
    const int* __restrict__ mentor, const int* __restrict__ rowptr,
    const int* __restrict__ vals,
    const ushort* __restrict__ yp2p, const ushort* __restrict__ yp3p,
    const float* __restrict__ btp, ushort* __restrict__ aggp){
  int t = blockIdx.x*8 + (threadIdx.x >> 5);
  if (t >= NT) return;
  int i = threadIdx.x & 31;
  float4 s = *(const float4*)(btp + i*4);
  int m = mentor[t];
  ushort4 y = *(const ushort4*)(yp2p + (size_t)m*CDIM + i*4);
  s.x += bf2f(y.x); s.y += bf2f(y.y); s.z += bf2f(y.z); s.w += bf2f(y.w);
  int qb = rowptr[t], qe = rowptr[t+1];
  for (int q = qb; q < qe; ++q){
    ushort4 z = *(const ushort4*)(yp3p + (size_t)vals[q]*CDIM + i*4);
    s.x += bf2f(z.x); s.y += bf2f(z.y); s.z += bf2f(z.z); s.w += bf2f(z.w);
  }
  ushort4 o;
  o.x = f2bf(s.x); o.y = f2bf(s.y); o.z = f2bf(s.z); o.w = f2bf(s.w);
  *(ushort4*)(aggp + (size_t)t*CDIM + i*4) = o;
}

// ---------------- thesis MFMA GEMM (layer 0 + input projection) ----------------
// EPI: add aggp (agg'd neighbor terms + bias, from k_agg) in epilogue.
template<int K, bool AF32, bool EPI, bool RELU>
__global__ __launch_bounds__(256) void k_mm(
    const void* __restrict__ Ain, int M,
    const ushort* __restrict__ Wfrag, const float* __restrict__ bias,
    ushort* __restrict__ Outp, const ushort* __restrict__ aggp){
  __shared__ uint4 smem[1024];
  uint4* As = smem;
  uint4* Bs = smem + 512;
  const int tid  = threadIdx.x;
  const int lane = tid & 63;
  const int wave = tid >> 6;
  const int wr   = wave >> 1, wc = wave & 1;
  const int m0   = blockIdx.x * 128;
  const float* Af = (const float*)Ain;
  const ushort* Ab = (const ushort*)Ain;

  f32x4 acc[4][4];
  #pragma unroll
  for (int i = 0; i < 4; ++i)
    #pragma unroll
    for (int j = 0; j < 4; ++j) acc[i][j] = (f32x4)(0.f);

  for (int kc = 0; kc < K/32; ++kc){
    if (AF32){
      const int rs = tid >> 2, qs = tid & 3;
      #pragma unroll
      for (int h = 0; h < 2; ++h){
        int rr = rs + 64*h;
        int grow = m0 + rr;
        uint4 payload = make_uint4(0,0,0,0);
        if (grow < M){
          const float* ap = Af + (size_t)grow*K + kc*32 + qs*8;
          float4 fa = *(const float4*)ap;
          float4 fb = *(const float4*)(ap + 4);
          payload.x = (uint)f2bf(fa.x) | ((uint)f2bf(fa.y) << 16);
          payload.y = (uint)f2bf(fa.z) | ((uint)f2bf(fa.w) << 16);
          payload.z = (uint)f2bf(fb.x) | ((uint)f2bf(fb.y) << 16);
          payload.w = (uint)f2bf(fb.z) | ((uint)f2bf(fb.w) << 16);
        }
        As[(rr >> 4)*64 + qs*16 + (rr & 15)] = payload;
      }
    } else {
      #pragma unroll
      for (int h = 0; h < 2; ++h){
        int e = tid + 256*h;
        int rr = e >> 2, q = e & 3;
        int grow = m0 + rr;
        uint4 payload = make_uint4(0,0,0,0);
        if (grow < M)
          payload = *(const uint4*)(Ab + (size_t)grow*K + (4*kc + q)*8);
        As[(rr >> 4)*64 + q*16 + (rr & 15)] = payload;
      }
    }
    const uint4* wsrc = (const uint4*)Wfrag + (size_t)kc*512;
    Bs[tid]       = wsrc[tid];
    Bs[tid + 256] = wsrc[tid + 256];
    __syncthreads();

    bf16x8 a[4], b[4];
    #pragma unroll
    for (int i = 0; i < 4; ++i){ FragU u; u.u = As[(wr*4 + i)*64 + lane]; a[i] = u.b; }
    #pragma unroll
    for (int j = 0; j < 4; ++j){ FragU u; u.u = Bs[(wc*4 + j)*64 + lane]; b[j] = u.b; }
    #pragma unroll
    for (int i = 0; i < 4; ++i)
      #pragma unroll
      for (int j = 0; j < 4; ++j)
        acc[i][j] = __builtin_amdgcn_mfma_f32_16x16x32_bf16(a[i], b[j], acc[i][j], 0, 0, 0);
    __syncthreads();
  }

  // --- epilogue ---
  const int nl = lane & 15;
  float bv[4];
  #pragma unroll
  for (int j = 0; j < 4; ++j) bv[j] = bias ? bias[wc*64 + j*16 + nl] : 0.f;
  const int s0 = nl*8 + wc*4;

  #pragma unroll
  for (int i = 0; i < 4; ++i){
    int rb = wr*64 + i*16 + (lane >> 4)*4;
    #pragma unroll
    for (int reg = 0; reg < 4; ++reg){
      int rr = rb + reg;
      int row = m0 + rr;
      if (row >= M) continue;
      float v0 = acc[i][0][reg] + bv[0];
      float v1 = acc[i][1][reg] + bv[1];
      float v2 = acc[i][2][reg] + bv[2];
      float v3 = acc[i][3][reg] + bv[3];
      if (EPI){
        ushort4 av = *(const ushort4*)(aggp + (size_t)row*CDIM + s0);
        v0 += bf2f(av.x); v1 += bf2f(av.y); v2 += bf2f(av.z); v3 += bf2f(av.w);
      }
      if (RELU){
        v0 = v0 > 0.f ? v0 : 0.f; v1 = v1 > 0.f ? v1 : 0.f;
        v2 = v2 > 0.f ? v2 : 0.f; v3 = v3 > 0.f ? v3 : 0.f;
      }
      ushort4 o;
      o.x = f2bf(v0); o.y = f2bf(v1); o.z = f2bf(v2); o.w = f2bf(v3);
      *(ushort4*)(Outp + (size_t)row*CDIM + s0) = o;
    }
  }
}

// ---------------- prof MFMA GEMM: y = {xp-update(K=384), yp2, yp3} ----------------
__global__ __launch_bounds__(256) void k_mmp(
    const ushort* __restrict__ apcat, const ushort* __restrict__ xpold, int layer,
    const ushort* __restrict__ WpFrag, const ushort* __restrict__ Wl2Frag,
    const ushort* __restrict__ Wl3Frag, const float* __restrict__ bp,
    ushort* __restrict__ xpnew, ushort* __restrict__ yp2p, ushort* __restrict__ yp3p){
  const int y = blockIdx.y;
  const ushort* A; const ushort* Wf; const float* bias; ushort* Out;
  int nkc, rowlen; bool relu;
  if (y == 0){ A = apcat; rowlen = 384; nkc = 12; Wf = WpFrag; bias = bp;
               Out = xpnew; relu = (layer == 0); }
  else if (y == 1){ A = xpold; rowlen = 128; nkc = 4; Wf = Wl2Frag; bias = nullptr;
               Out = yp2p; relu = false; }
  else       { A = xpold; rowlen = 128; nkc = 4; Wf = Wl3Frag; bias = nullptr;
               Out = yp3p; relu = false; }

  __shared__ uint4 As[512];
  __shared__ uint4 Bs[512];
  const int tid  = threadIdx.x;
  const int lane = tid & 63;
  const int wave = tid >> 6;
  const int wr   = wave >> 1, wc = wave & 1;
  const int m0   = blockIdx.x * 128;

  f32x4 acc[4][4];
  #pragma unroll
  for (int i = 0; i < 4; ++i)
    #pragma unroll
    for (int j = 0; j < 4; ++j) acc[i][j] = (f32x4)(0.f);

  for (int kc = 0; kc < nkc; ++kc){
    #pragma unroll
    for (int h = 0; h < 2; ++h){
      int e = tid + 256*h;
      int rr = e >> 2, q = e & 3;
      int grow = m0 + rr;
      uint4 payload = make_uint4(0,0,0,0);
      if (grow < NP)
        payload = *(const uint4*)(A + (size_t)grow*rowlen + (4*kc + q)*8);
      As[(rr >> 4)*64 + q*16 + (rr & 15)] = payload;
    }
    const uint4* wsrc = (const uint4*)Wf + (size_t)kc*512;
    Bs[tid]       = wsrc[tid];
    Bs[tid + 256] = wsrc[tid + 256];
    __syncthreads();

    bf16x8 a[4], b[4];
    #pragma unroll
    for (int i = 0; i < 4; ++i){ FragU u; u.u = As[(wr*4 + i)*64 + lane]; a[i] = u.b; }
    #pragma unroll
    for (int j = 0; j < 4; ++j){ FragU u; u.u = Bs[(wc*4 + j)*64 + lane]; b[j] = u.b; }
    #pragma unroll
    for (int i = 0; i < 4; ++i)
      #pragma unroll
      for (int j = 0; j < 4; ++j)
        acc[i][j] = __builtin_amdgcn_mfma_f32_16x16x32_bf16(a[i], b[j], acc[i][j], 0, 0, 0);
    __syncthreads();
  }

  const int nl = lane & 15;
  float bv[4];
  #pragma unroll
  for (int j = 0; j < 4; ++j) bv[j] = bias ? bias[wc*64 + j*16 + nl] : 0.f;
  const int s0 = nl*8 + wc*4;

  #pragma unroll
  for (int i = 0; i < 4; ++i){
    int r0 = m0 + wr*64 + i*16 + (lane >> 4)*4;
    #pragma unroll
    for (int reg = 0; reg < 4; ++reg){
      int row = r0 + reg;
      if (row >= NP) continue;
      float v0 = acc[i][0][reg] + bv[0];
      float v1 = acc[i][1][reg] + bv[1];
      float v2 = acc[i][2][reg] + bv[2];
      float v3 = acc[i][3][reg] + bv[3];
      if (relu){
        v0 = v0 > 0.f ? v0 : 0.f; v1 = v1 > 0.f ? v1 : 0.f;
        v2 = v2 > 0.f ? v2 : 0.f; v3 = v3 > 0.f ? v3 : 0.f;
      }
      ushort4 o;
      o.x = f2bf(v0); o.y = f2bf(v1); o.z = f2bf(v2); o.w = f2bf(v3);
      *(ushort4*)(Out + (size_t)row*CDIM + s0) = o;
    }
  }
}

// ---------------- shared N=32 GEMM pass: A sigma-bf16, W invs-row-permuted fp32 ----------------
__device__ __forceinline__ void g32_pass(const ushort* __restrict__ A, int M, int m0,
                                         const float* __restrict__ W,
                                         float* As, float* Ws, float4 acc[4]){
  const int tid  = threadIdx.x;
  const int c4   = (tid & 7)*4;
  const int rowg = tid >> 3;
  for (int k0 = 0; k0 < 128; k0 += 32){
    #pragma unroll
    for (int l = 0; l < 4; ++l){
      int q = tid + 256*l;
      int r = q >> 3, kf = q & 7;
      int row = m0 + r;
      float4 v = make_float4(0.f,0.f,0.f,0.f);
      if (row < M){
        ushort4 u = *(const ushort4*)(A + (size_t)row*CDIM + k0 + kf*4);
        v = make_float4(bf2f(u.x), bf2f(u.y), bf2f(u.z), bf2f(u.w));
      }
      *(float4*)&As[r*36 + kf*4] = v;
    }
    {
      int kk = tid >> 3, cf = tid & 7;
      *(float4*)&Ws[kk*32 + cf*4] = *(const float4*)(W + (size_t)(k0+kk)*32 + cf*4);
    }
    __syncthreads();
    #pragma unroll
    for (int k4 = 0; k4 < 8; ++k4){
      float4 w0 = *(const float4*)&Ws[(k4*4+0)*32 + c4];
      float4 w1 = *(const float4*)&Ws[(k4*4+1)*32 + c4];
      float4 w2 = *(const float4*)&Ws[(k4*4+2)*32 + c4];
      float4 w3 = *(const float4*)&Ws[(k4*4+3)*32 + c4];
      #pragma unroll
      for (int j = 0; j < 4; ++j){
        float4 a = *(const float4*)&As[(rowg + 32*j)*36 + k4*4];
        acc[j].x += a.x*w0.x + a.y*w1.x + a.z*w2.x + a.w*w3.x;
        acc[j].y += a.x*w0.y + a.y*w1.y + a.z*w2.y + a.w*w3.y;
        acc[j].z += a.x*w0.z + a.y*w1.z + a.z*w2.z + a.w*w3.z;
        acc[j].w += a.x*w0.w + a.y*w1.w + a.z*w2.w + a.w*w3.w;
      }
    }
    __syncthreads();
  }
}

// ---------------- prof-side N=32 outputs ----------------
// y=0: zpc2 = xp2 @ Wzc + b1
// y=1: y2z  = yp2p @ V + xp2 @ Wzb + btz   (mentor-side table incl. zpb + bt1@V)
// y=2: y3z  = yp3p @ V
__global__ __launch_bounds__(256) void k_g32prof(
    const ushort* __restrict__ xp2, const ushort* __restrict__ yp2p,
    const ushort* __restrict__ yp3p,
    const float* __restrict__ WzcPerm, const float* __restrict__ WzbPerm,
    const float* __restrict__ VzPerm,
    const float* __restrict__ b1, const float* __restrict__ btz,
    ushort* __restrict__ zpc2, ushort* __restrict__ y2z, ushort* __restrict__ y3z){
  __shared__ float As[128*36];
  __shared__ float Ws[32*32];
  const int y = blockIdx.y;
  const int m0 = blockIdx.x*128;
  const ushort* A0; const float* W0; const ushort* A1 = nullptr; const float* W1 = nullptr;
  const float* bias = nullptr; ushort* Out;
  if (y == 0){ A0 = xp2;  W0 = WzcPerm; bias = b1;  Out = zpc2; }
  else if (y == 1){ A0 = yp2p; W0 = VzPerm; A1 = xp2; W1 = WzbPerm; bias = btz; Out = y2z; }
  else { A0 = yp3p; W0 = VzPerm; Out = y3z; }

  float4 acc[4];
  #pragma unroll
  for (int j = 0; j < 4; ++j) acc[j] = make_float4(0.f,0.f,0.f,0.f);
  g32_pass(A0, NP, m0, W0, As, Ws, acc);
  if (A1) g32_pass(A1, NP, m0, W1, As, Ws, acc);

  const int c4   = (threadIdx.x & 7)*4;
  const int rowg = threadIdx.x >> 3;
  float4 bb = make_float4(0.f,0.f,0.f,0.f);
  if (bias) bb = *(const float4*)(bias + c4);
  #pragma unroll
  for (int j = 0; j < 4; ++j){
    int row = m0 + rowg + 32*j;
    if (row < NP){
      ushort4 o;
      o.x = f2bf(acc[j].x + bb.x); o.y = f2bf(acc[j].y + bb.y);
      o.z = f2bf(acc[j].z + bb.z); o.w = f2bf(acc[j].w + bb.w);
      *(ushort4*)(Out + (size_t)row*32 + c4) = o;
    }
  }
}

// ---------------- thesis N=32 GEMM: zt0 = xt1 @ VtPerm ----------------
__global__ __launch_bounds__(256) void k_g32t(const ushort* __restrict__ xt,
                                              const float* __restrict__ VtPerm,
                                              ushort* __restrict__ zt0){
  __shared__ float As[128*36];
  __shared__ float Ws[32*32];
  const int m0 = blockIdx.x*128;
  float4 acc[4];
  #pragma unroll
  for (int j = 0; j < 4; ++j) acc[j] = make_float4(0.f,0.f,0.f,0.f);
  g32_pass(xt, NT, m0, VtPerm, As, Ws, acc);
  const int c4   = (threadIdx.x & 7)*4;
  const int rowg = threadIdx.x >> 3;
  #pragma unroll
  for (int j = 0; j < 4; ++j){
    int row = m0 + rowg + 32*j;
    if (row < NT){
      ushort4 o;
      o.x = f2bf(acc[j].x); o.y = f2bf(acc[j].y);
      o.z = f2bf(acc[j].z); o.w = f2bf(acc[j].w);
      *(ushort4*)(zt0 + (size_t)row*32 + c4) = o;
    }
  }
}

// ---------------- 32-wide edge aggregation: zt = zt0 + y2z[mentor] + sum y3z[com] ------------
__global__ __launch_bounds__(256) void k_aggz(
    const int* __restrict__ mentor, const int* __restrict__ rowptr,
    const int* __restrict__ vals,
    const uint* __restrict__ zt0, const uint* __restrict__ y2z,
    const uint* __restrict__ y3z, uint* __restrict__ ztout){
  int t = blockIdx.x*16 + (threadIdx.x >> 4);
  if (t >= NT) return;
  int i = threadIdx.x & 15;
  uint v = zt0[(size_t)t*16 + i];
  float a = bf2f((ushort)(v & 0xffff));
  float b = bf2f((ushort)(v >> 16));
  int m = mentor[t];
  uint u = y2z[(size_t)m*16 + i];
  a += bf2f((ushort)(u & 0xffff));
  b += bf2f((ushort)(u >> 16));
  int qb = rowptr[t], qe = rowptr[t+1];
  for (int q = qb; q < qe; ++q){
    uint w = y3z[(size_t)vals[q]*16 + i];
    a += bf2f((ushort)(w & 0xffff));
    b += bf2f((ushort)(w >> 16));
  }
  ztout[(size_t)t*16 + i] = (uint)f2bf(a) | ((uint)f2bf(b) << 16);
}

// ---------------- edge classifier: zt already contains mentor-side terms; zpc2 contains b1 -------
__global__ __launch_bounds__(256) void k_edge(
    const int* __restrict__ el0, const int* __restrict__ el1,
    const ushort* __restrict__ zt2, const ushort* __restrict__ zpc2,
    const float* __restrict__ W2, const float* __restrict__ b2,
    float* __restrict__ out, int n){
  __shared__ float sW[32];
  if (threadIdx.x < 32) sW[threadIdx.x] = W2[threadIdx.x];
  __syncthreads();
  int e = blockIdx.x*256 + threadIdx.x;
  if (e >= n) return;
  int t = el0[e], p = el1[e];
  const uint4* zr = (const uint4*)(zt2  + (size_t)t*32);
  const uint4* cr = (const uint4*)(zpc2 + (size_t)p*32);
  float acc = 0.f;
  #pragma unroll
  for (int i = 0; i < 4; ++i){   // 4 uint4 = 32 bf16 hidden units
    uint4 ua = zr[i], uc = cr[i];
    const uint aw[4] = {ua.x, ua.y, ua.z, ua.w};
    const uint cw[4] = {uc.x, uc.y, uc.z, uc.w};
    #pragma unroll
    for (int k = 0; k < 4; ++k){
      int base = i*8 + k*2;
      float h0 = bf2f((ushort)(aw[k] & 0xffff)) + bf2f((ushort)(cw[k] & 0xffff));
      float h1 = bf2f((ushort)(aw[k] >> 16)) + bf2f((ushort)(cw[k] >> 16));
      h0 = h0 > 0.f ? h0 : 0.f;
      h1 = h1 > 0.f ? h1 : 0.f;
      acc = fmaf(h0, sW[base], acc);
      acc = fmaf(h1, sW[base + 1], acc);
    }
  }
  out[e] = acc + b2[0];
}

// ---------------- launch ----------------
extern "C" void kernel_launch(void* const* d_in, const int* in_sizes, int n_in,
                              void* d_out, int out_size, void* d_ws, size_t ws_size,
                              hipStream_t stream){
  const float* thesis_x = (const float*)d_in[0];
  const float* lin_W    = (const float*)d_in[1];
  const float* lin_b    = (const float*)d_in[2];
  const float* prof_emb = (const float*)d_in[3];
  const float* gWl      = (const float*)d_in[4];
  const float* gbl      = (const float*)d_in[5];
  const float* gWr      = (const float*)d_in[6];
  const float* cW1      = (const float*)d_in[7];
  const float* cb1      = (const float*)d_in[8];
  const float* cW2      = (const float*)d_in[9];
  const float* cb2      = (const float*)d_in[10];
  const int*   pid      = (const int*)d_in[11];
  const int*   sup0     = (const int*)d_in[12];
  const int*   sup1     = sup0 + NT;
  const int*   com0     = (const int*)d_in[13];
  const int*   com1     = com0 + EC;
  const int*   el0      = (const int*)d_in[14];
  const int*   el1      = el0 + EL;
  float* outp = (float*)d_out;

  char* base = (char*)d_ws;
  size_t off = 0;
  auto alloc = [&](size_t bytes)->void*{
    void* p = base + off;
    off += (bytes + 255) & ~(size_t)255;
    return p;
  };
  ushort* xt      = (ushort*)alloc((size_t)NT*CDIM*2);   // sigma-bf16
  ushort* aggp    = (ushort*)alloc((size_t)NT*CDIM*2);   // sigma-bf16 (layer 0)
  ushort* zt      = (ushort*)alloc((size_t)NT*32*2);     // natural bf16 (final, incl. mentor terms)
  ushort* zt0     = (ushort*)alloc((size_t)NT*32*2);     // natural bf16 (xt1 @ Vt)
  ushort* xp0     = (ushort*)alloc((size_t)NP*CDIM*2);   // sigma-bf16
  ushort* xp1     = (ushort*)alloc((size_t)NP*CDIM*2);
  ushort* apcat   = (ushort*)alloc((size_t)NP*384*2);    // [sig|sig|sig] bf16
  ushort* yp2p    = (ushort*)alloc((size_t)NP*CDIM*2);
  ushort* yp3p    = (ushort*)alloc((size_t)NP*CDIM*2);
  ushort* WmFrag  = (ushort*)alloc((size_t)384*128*2);
  float*  VzPerm  = (float*)alloc((size_t)128*32*4);
  float*  VtPerm  = (float*)alloc((size_t)128*32*4);
  float*  btz     = (float*)alloc(512);
  float*  WzbPerm = (float*)alloc((size_t)128*32*4);
  float*  WzcPerm = (float*)alloc((size_t)128*32*4);
  ushort* WpFrag  = (ushort*)alloc((size_t)2*384*128*2);
  ushort* Wl2Frag = (ushort*)alloc((size_t)2*128*128*2);
  ushort* Wl3Frag = (ushort*)alloc((size_t)2*128*128*2);
  ushort* WtFrag  = (ushort*)alloc((size_t)2*128*128*2);
  float*  bp      = (float*)alloc(2*512);
  float*  btp     = (float*)alloc(2*512);
  ushort* zpc     = (ushort*)alloc((size_t)NP*32*2);     // zpc2 = zpc + b1
  ushort* y2z     = (ushort*)alloc((size_t)NP*32*2);
  ushort* y3z     = (ushort*)alloc((size_t)NP*32*2);
  int* rp_all  = (int*)alloc((size_t)(NKEYS+1)*4);
  int* vals    = (int*)alloc((size_t)NEDGE*4);
  int* counts  = (int*)alloc((size_t)NKEYS*4);
  int* cursor  = (int*)alloc((size_t)NKEYS*4);
  int* partials= (int*)alloc(8192);

  auto cdiv = [](int a, int b){ return (a + b - 1)/b; };

  // ---- CSR build (6 dispatches) ----
  hipMemsetAsync(counts, 0, (size_t)NKEYS*4, stream);
  k_hist3<<<cdiv(NEDGE,256),256,0,stream>>>(com0, com1, sup1, counts);
  int nPb = cdiv(NKEYS,256);
  k_scanA<<<nPb,256,0,stream>>>(counts, NKEYS, rp_all, partials);
  k_scanB<<<1,1024,0,stream>>>(partials, nPb, rp_all + NKEYS);
  k_scanC<<<nPb,256,0,stream>>>(rp_all, partials, NKEYS, cursor);
  k_fill3<<<cdiv(NEDGE,256),256,0,stream>>>(com0, com1, sup0, sup1, cursor, vals);
  const int* rp_t = rp_all;               // com by thesis (vals = prof)
  const int* crp  = rp_all + NT;          // com by prof (vals = thesis)
  const int* mrp  = rp_all + NT + NP;     // sup by prof (vals = thesis)

  // ---- prep ----
  k_prep<<<cdiv(NP*CDIM + 384*128 + 128*32 + 2*128*32,256),256,0,stream>>>(
      prof_emb, pid, xp0, lin_W, WmFrag, cW1, VzPerm, WzbPerm, WzcPerm);
  for (int l = 0; l < 2; ++l)
    k_wprep<<<cdiv(49152 + 3*16384 + 128,256),256,0,stream>>>(
        gWl, gbl, gWr, l,
        WpFrag + (size_t)l*49152, Wl2Frag + (size_t)l*16384,
        Wl3Frag + (size_t)l*16384, WtFrag + (size_t)l*16384,
        bp + l*128, btp + l*128);
  k_fuse32<<<16,256,0,stream>>>(gWr, gbl, cW1, VtPerm, btz);

  // xt = sigma-bf16(thesis_x @ lin_W + lin_b)
  k_mm<384,true,false,false><<<cdiv(NT,128),256,0,stream>>>(
      thesis_x, NT, WmFrag, lin_b, xt, nullptr);

  // ---- layer 0 ----
  k_segsum<<<cdiv(NP,4),256,0,stream>>>((const uint*)xt, (const uint*)xp0,
                                        mrp, crp, vals, (uint*)apcat);
  k_mmp<<<dim3(cdiv(NP,128),3),256,0,stream>>>(
      apcat, xp0, 0, WpFrag, Wl2Frag, Wl3Frag, bp, xp1, yp2p, yp3p);
  k_agg<<<cdiv(NT,8),256,0,stream>>>(sup1, rp_t, vals, yp2p, yp3p, btp, aggp);
  k_mm<128,false,true,true><<<cdiv(NT,128),256,0,stream>>>(
      xt, NT, WtFrag, nullptr, xt, aggp);

  // ---- layer 1 (prof side full-width; thesis side compressed to N=32) ----
  k_segsum<<<cdiv(NP,4),256,0,stream>>>((const uint*)xt, (const uint*)xp1,
                                        mrp, crp, vals, (uint*)apcat);
  k_mmp<<<dim3(cdiv(NP,128),3),256,0,stream>>>(
      apcat, xp1, 1, WpFrag + 49152, Wl2Frag + 16384,
      Wl3Frag + 16384, bp + 128, xp0, yp2p, yp3p);   // xp0 reused as xp2
  k_g32prof<<<dim3(cdiv(NP,128),3),256,0,stream>>>(
      xp0, yp2p, yp3p, WzcPerm, WzbPerm, VzPerm, cb1, btz, zpc, y2z, y3z);
  k_g32t<<<cdiv(NT,128),256,0,stream>>>(xt, VtPerm, zt0);
  k_aggz<<<cdiv(NT,16),256,0,stream>>>(sup1, rp_t, vals,
                                       (const uint*)zt0, (const uint*)y2z,
                                       (const uint*)y3z, (uint*)zt);

  k_edge<<<cdiv(EL,256),256,0,stream>>>(el0, el1, zt, zpc,
                                        cW2, cb2, outp, EL);
}

// Round 4
// 893.762 us; speedup vs baseline: 1.1351x; 1.0580x over previous
//
#include <hip/hip_runtime.h>
#include <hip/hip_bf16.h>
#include <cstdint>
#include <cstddef>

#define NT 200000
#define NP 5000
#define FDIM 384
#define CDIM 128
#define EC 600000
#define EL 400000
#define NKEYS (NT + 2*NP)          // concatenated CSR segment count
#define NEDGE (2*EC + NT)          // concatenated edge count

typedef unsigned int uint;
typedef unsigned short ushort;
typedef __attribute__((ext_vector_type(8))) __bf16 bf16x8;
typedef __attribute__((ext_vector_type(4))) float f32x4;

union FragU { uint4 u; bf16x8 b; };

__device__ __forceinline__ ushort f2bf(float f){
  uint u = __float_as_uint(f);
  u = (u + 0x7fffu + ((u >> 16) & 1u)) >> 16;
  return (ushort)u;
}
__device__ __forceinline__ float bf2f(ushort h){
  return __uint_as_float(((uint)h) << 16);
}
// storage permutation: sigma(c) = (c&15)*8 + (c>>4); invs below
__device__ __forceinline__ int invs(int w){
  return ((w >> 2) & 1)*64 + (w & 3)*16 + (w >> 3);
}

// ---------------- fused CSR build ----------------
__global__ void k_hist3(const int* __restrict__ com0, const int* __restrict__ com1,
                        const int* __restrict__ sup1, int* __restrict__ counts){
  int i = blockIdx.x*256 + threadIdx.x;
  if (i < EC)            atomicAdd(&counts[com0[i]], 1);
  else if (i < 2*EC)     atomicAdd(&counts[NT + com1[i - EC]], 1);
  else if (i < NEDGE)    atomicAdd(&counts[NT + NP + sup1[i - 2*EC]], 1);
}

// local exclusive scan per 256-block + block totals
__global__ void k_scanA(const int* __restrict__ counts, int n,
                        int* __restrict__ rowptr, int* __restrict__ partials){
  __shared__ int s[256];
  int tid = threadIdx.x;
  int i = blockIdx.x*256 + tid;
  int v = (i < n) ? counts[i] : 0;
  s[tid] = v; __syncthreads();
  for (int off = 1; off < 256; off <<= 1){
    int t = (tid >= off) ? s[tid - off] : 0;
    __syncthreads();
    s[tid] += t;
    __syncthreads();
  }
  if (i < n) rowptr[i] = s[tid] - v;
  if (tid == 255) partials[blockIdx.x] = s[255];
}

__global__ void k_scanB(int* __restrict__ partials, int nP, int* __restrict__ total_out){
  __shared__ int s[1024];
  int carry = 0;
  for (int base = 0; base < nP; base += 1024){
    int i = base + threadIdx.x;
    int v = (i < nP) ? partials[i] : 0;
    s[threadIdx.x] = v; __syncthreads();
    for (int off = 1; off < 1024; off <<= 1){
      int t = (threadIdx.x >= off) ? s[threadIdx.x - off] : 0;
      __syncthreads();
      s[threadIdx.x] += t;
      __syncthreads();
    }
    if (i < nP) partials[i] = carry + s[threadIdx.x] - v;
    int chunk_total = s[1023];
    __syncthreads();
    carry += chunk_total;
  }
  if (threadIdx.x == 0 && total_out) *total_out = carry;
}

__global__ void k_scanC(int* __restrict__ rowptr, const int* __restrict__ pscan,
                        int n, int* __restrict__ cursor){
  int i = blockIdx.x*256 + threadIdx.x;
  if (i < n){
    int r = rowptr[i] + pscan[i >> 8];
    rowptr[i] = r;
    cursor[i] = r;
  }
}

__global__ void k_fill3(const int* __restrict__ com0, const int* __restrict__ com1,
                        const int* __restrict__ sup0, const int* __restrict__ sup1,
                        int* __restrict__ cursor, int* __restrict__ vals){
  int i = blockIdx.x*256 + threadIdx.x;
  int key, sv;
  if (i < EC)          { key = com0[i];                 sv = com1[i]; }
  else if (i < 2*EC)   { key = NT + com1[i - EC];       sv = com0[i - EC]; }
  else if (i < NEDGE)  { key = NT + NP + sup1[i - 2*EC]; sv = sup0[i - 2*EC]; }
  else return;
  int pos = atomicAdd(&cursor[key], 1);
  vals[pos] = sv;
}

// ---------------- per-layer weight prep element (from old k_wprep) ----------------
__device__ __forceinline__ void wprep_elem(int o, int layer,
    const float* __restrict__ gWl, const float* __restrict__ gbl,
    const float* __restrict__ gWr,
    ushort* __restrict__ WpFrag, ushort* __restrict__ Wl2Frag,
    ushort* __restrict__ Wl3Frag, ushort* __restrict__ WtFrag,
    float* __restrict__ bp, float* __restrict__ btp){
  const float* Wl_l = gWl + (size_t)layer*4*16384;
  const float* Wr_l = gWr + (size_t)layer*4*16384;
  const float* bl_l = gbl + (size_t)layer*4*128;
  if (o < 49152){                       // WpFrag: K=384, all blocks invs
    int j = o & 7, lane = (o >> 3) & 63, q = lane >> 4, nl = lane & 15, tl = o >> 9;
    int nt = tl & 7, kc = tl >> 3;
    int s_row = 32*kc + 8*q + j;
    int b = s_row >> 7, w = s_row & 127;
    int r = invs(w), n = nt*16 + nl;
    float v;
    if (b == 0)      v = Wl_l[(size_t)r*128 + n];
    else if (b == 1) v = Wl_l[16384 + (size_t)r*128 + n];
    else             v = Wr_l[(size_t)r*128 + n] + Wr_l[16384 + (size_t)r*128 + n];
    WpFrag[(size_t)layer*49152 + o] = f2bf(v);
    return;
  }
  o -= 49152;
  if (o < 3*16384){                     // Wl2 / Wl3 / Wt frags (K=128, invs)
    int m = o >> 14;
    int oo = o & 16383;
    int j = oo & 7, lane = (oo >> 3) & 63, q = lane >> 4, nl = lane & 15, tl = oo >> 9;
    int nt = tl & 7, kc = tl >> 3;
    int s = 32*kc + 8*q + j;
    int r = invs(s), n = nt*16 + nl;
    float v;
    if (m == 0)      v = Wl_l[2*16384 + (size_t)r*128 + n];
    else if (m == 1) v = Wl_l[3*16384 + (size_t)r*128 + n];
    else             v = Wr_l[2*16384 + (size_t)r*128 + n] + Wr_l[3*16384 + (size_t)r*128 + n];
    ushort* dst = (m == 0 ? Wl2Frag : (m == 1 ? Wl3Frag : WtFrag));
    dst[(size_t)layer*16384 + oo] = f2bf(v);
    return;
  }
  o -= 3*16384;
  if (o < 128){
    bp[layer*128 + o] = bl_l[o] + bl_l[128 + o];
    btp[layer*128 + (o & 15)*8 + (o >> 4)] = bl_l[2*128 + o] + bl_l[3*128 + o];
  }
}

// ---------------- fused prep: counts zero + xp0 + frags + g32 weights + layer-1 folds ---------
// elementwise segment sizes
#define PS0 NKEYS            // zero counts
#define PS1 (NP*CDIM)        // xp0
#define PS2 (384*128)        // WmFrag
#define PS3 (2*128*32)       // Wzb/WzcPerm
#define PS4 98432            // wprep layer 0
#define PS5 98432            // wprep layer 1
#define PE_TOTAL (PS0+PS1+PS2+PS3+PS4+PS5)

__global__ __launch_bounds__(256) void k_prepall(
    const float* __restrict__ pe, const int* __restrict__ pid,
    ushort* __restrict__ xp0,
    const float* __restrict__ lin_W, ushort* __restrict__ WmFrag,
    const float* __restrict__ cW1,
    float* __restrict__ WzbPerm, float* __restrict__ WzcPerm,
    const float* __restrict__ gWl, const float* __restrict__ gbl,
    const float* __restrict__ gWr,
    ushort* __restrict__ WpFrag, ushort* __restrict__ Wl2Frag,
    ushort* __restrict__ Wl3Frag, ushort* __restrict__ WtFrag,
    float* __restrict__ bp, float* __restrict__ btp,
    ushort* __restrict__ VtFrag, float* __restrict__ W2V,
    float* __restrict__ W3V, float* __restrict__ btz,
    int* __restrict__ counts, int nEblocks){
  __shared__ float Vs[4096];
  const int tid = threadIdx.x;
  int fb = blockIdx.x - nEblocks;
  if (fb >= 0){
    // ---- fold blocks: 48 blocks, each 256 outputs of a 128x32 = W @ V product ----
    for (int i = tid; i < 4096; i += 256) Vs[i] = cW1[i];   // V = cW1 rows 0..127
    __syncthreads();
    int which = fb >> 4;                 // 0: VtFrag, 1: W2V, 2: W3V
    int o = (fb & 15)*256 + tid;         // 0..4095
    if (which == 0){
      // MFMA frag layout (K=128, N=32), value = Vt_nat[invs(s)][n],
      // Vt = (Wr[1][2] + Wr[1][3]) @ V
      int j = o & 7, lane = (o >> 3) & 63, q = lane >> 4, nl = lane & 15, tl = o >> 9;
      int nt = tl & 1, kc = tl >> 1;
      int s = 32*kc + 8*q + j, n = nt*16 + nl;
      int r = invs(s);
      const float* Wr2 = gWr + (size_t)6*16384;
      const float* Wr3 = gWr + (size_t)7*16384;
      float acc = 0.f;
      for (int c = 0; c < 128; ++c)
        acc += (Wr2[r*128 + c] + Wr3[r*128 + c]) * Vs[c*32 + n];
      VtFrag[o] = f2bf(acc);
    } else {
      // g32 layout: [s][n], rows invs-permuted; W2V = Wl[1][2]@V, W3V = Wl[1][3]@V
      int s = o >> 5, n = o & 31;
      int r = invs(s);
      const float* W = gWl + (size_t)(which == 1 ? 6 : 7)*16384;
      float acc = 0.f;
      for (int c = 0; c < 128; ++c)
        acc += W[r*128 + c] * Vs[c*32 + n];
      (which == 1 ? W2V : W3V)[o] = acc;
    }
    if (fb == 0 && tid < 32){            // btz = (bl[1][2]+bl[1][3]) @ V
      const float* b2 = gbl + 6*128;
      const float* b3 = gbl + 7*128;
      float acc = 0.f;
      for (int c = 0; c < 128; ++c)
        acc += (b2[c] + b3[c]) * Vs[c*32 + tid];
      btz[tid] = acc;
    }
    return;
  }
  // ---- elementwise blocks ----
  int i = blockIdx.x*256 + tid;
  if (i < PS0){ counts[i] = 0; return; }
  i -= PS0;
  if (i < PS1){                          // xp0[p][w] = bf16(pe[pid[p]][invs(w)])
    int p = i >> 7, w = i & 127;
    xp0[i] = f2bf(pe[(size_t)pid[p]*CDIM + invs(w)]);
    return;
  }
  i -= PS1;
  if (i < PS2){                          // WmFrag natural pack (A = fp32 natural)
    int j = i & 7, lane = (i >> 3) & 63, q = lane >> 4, nl = lane & 15, tl = i >> 9;
    int nt = tl & 7, kc = tl >> 3;
    int k = kc*32 + q*8 + j, n = nt*16 + nl;
    WmFrag[i] = f2bf(lin_W[(size_t)k*128 + n]);
    return;
  }
  i -= PS2;
  if (i < PS3){                          // row-permuted fp32 W for g32 (zpb/zpc blocks)
    int m = i >> 12;
    int o = i & 4095;
    int s = o >> 5, n = o & 31;
    float v = cW1[(size_t)(128 + m*128 + invs(s))*32 + n];
    (m ? WzcPerm : WzbPerm)[o] = v;
    return;
  }
  i -= PS3;
  if (i < PS4){
    wprep_elem(i, 0, gWl, gbl, gWr, WpFrag, Wl2Frag, Wl3Frag, WtFrag, bp, btp);
    return;
  }
  i -= PS4;
  if (i < PS5)
    wprep_elem(i, 1, gWl, gbl, gWr, WpFrag, Wl2Frag, Wl3Frag, WtFrag, bp, btp);
}

// ---------------- segment sums: 2 waves per prof (sup / com split), unroll 8 ----------------
__global__ __launch_bounds__(256) void k_segsum(
    const uint* __restrict__ xt32, const uint* __restrict__ xp32,
    const int* __restrict__ mrp, const int* __restrict__ crp,
    const int* __restrict__ vall, uint* __restrict__ apcat){
  int wid = threadIdx.x >> 6;
  int p = blockIdx.x*2 + (wid >> 1);
  if (p >= NP) return;
  int lane = threadIdx.x & 63;
  const bool is_sup = (wid & 1) == 0;
  const int* rp = is_sup ? mrp : crp;
  int j = rp[p], je = rp[p+1];
  float sa = 0.f, sb = 0.f;
  for (; j + 8 <= je; j += 8){
    uint v0 = xt32[(size_t)vall[j]  *64 + lane];
    uint v1 = xt32[(size_t)vall[j+1]*64 + lane];
    uint v2 = xt32[(size_t)vall[j+2]*64 + lane];
    uint v3 = xt32[(size_t)vall[j+3]*64 + lane];
    uint v4 = xt32[(size_t)vall[j+4]*64 + lane];
    uint v5 = xt32[(size_t)vall[j+5]*64 + lane];
    uint v6 = xt32[(size_t)vall[j+6]*64 + lane];
    uint v7 = xt32[(size_t)vall[j+7]*64 + lane];
    sa += ((bf2f((ushort)(v0 & 0xffff)) + bf2f((ushort)(v1 & 0xffff)))
         + (bf2f((ushort)(v2 & 0xffff)) + bf2f((ushort)(v3 & 0xffff))))
        + ((bf2f((ushort)(v4 & 0xffff)) + bf2f((ushort)(v5 & 0xffff)))
         + (bf2f((ushort)(v6 & 0xffff)) + bf2f((ushort)(v7 & 0xffff))));
    sb += ((bf2f((ushort)(v0 >> 16)) + bf2f((ushort)(v1 >> 16)))
         + (bf2f((ushort)(v2 >> 16)) + bf2f((ushort)(v3 >> 16))))
        + ((bf2f((ushort)(v4 >> 16)) + bf2f((ushort)(v5 >> 16)))
         + (bf2f((ushort)(v6 >> 16)) + bf2f((ushort)(v7 >> 16))));
  }
  for (; j < je; ++j){
    uint v = xt32[(size_t)vall[j]*64 + lane];
    sa += bf2f((ushort)(v & 0xffff));
    sb += bf2f((ushort)(v >> 16));
  }
  uint* row = apcat + (size_t)p*192;
  uint packed = (uint)f2bf(sa) | ((uint)f2bf(sb) << 16);
  if (is_sup){
    row[lane]       = packed;
    row[128 + lane] = xp32[(size_t)p*64 + lane];
  } else {
    row[64 + lane]  = packed;
  }
}

// ---------------- edge aggregation, 128-wide (layer 0 only) ----------------
__global__ __launch_bounds__(256) void k_agg(
    const int* __restrict__ mentor, const int* __restrict__ rowptr,
    const int* __restrict__ vals,
    const ushort* __restrict__ yp2p, const ushort* __restrict__ yp3p,
    const float* __restrict__ btp, ushort* __restrict__ aggp){
  int t = blockIdx.x*8 + (threadIdx.x >> 5);
  if (t >= NT) return;
  int i = threadIdx.x & 31;
  float4 s = *(const float4*)(btp + i*4);
  int m = mentor[t];
  ushort4 y = *(const ushort4*)(yp2p + (size_t)m*CDIM + i*4);
  s.x += bf2f(y.x); s.y += bf2f(y.y); s.z += bf2f(y.z); s.w += bf2f(y.w);
  int qb = rowptr[t], qe = rowptr[t+1];
  for (int q = qb; q < qe; ++q){
    ushort4 z = *(const ushort4*)(yp3p + (size_t)vals[q]*CDIM + i*4);
    s.x += bf2f(z.x); s.y += bf2f(z.y); s.z += bf2f(z.z); s.w += bf2f(z.w);
  }
  ushort4 o;
  o.x = f2bf(s.x); o.y = f2bf(s.y); o.z = f2bf(s.z); o.w = f2bf(s.w);
  *(ushort4*)(aggp + (size_t)t*CDIM + i*4) = o;
}

// ---------------- thesis MFMA GEMM ----------------
// EPI: add aggp (agg'd neighbor terms + bias, from k_agg) in epilogue.
// ZT:  ALSO write result tile to LDS (stride 136) and emit zt0 = tile @ W1a
//      (in addition to the normal Outp store).
template<int K, bool AF32, bool EPI, bool RELU, bool ZT>
__global__ __launch_bounds__(256) void k_mm(
    const void* __restrict__ Ain, int M,
    const ushort* __restrict__ Wfrag, const float* __restrict__ bias,
    ushort* __restrict__ Outp, const ushort* __restrict__ aggp,
    const ushort* __restrict__ W1a, ushort* __restrict__ ztout){
  constexpr int SMSZ = ZT ? 2176 : 1024;      // uint4 units (ZT: 34816 B tile overlay)
  __shared__ uint4 smem[SMSZ];
  uint4* As = smem;
  uint4* Bs = smem + 512;
  ushort* tile = (ushort*)smem;               // 128 x 136, used after K-loop only
  const int tid  = threadIdx.x;
  const int lane = tid & 63;
  const int wave = tid >> 6;
  const int wr   = wave >> 1, wc = wave & 1;
  const int m0   = blockIdx.x * 128;
  const float* Af = (const float*)Ain;
  const ushort* Ab = (const ushort*)Ain;

  f32x4 acc[4][4];
  #pragma unroll
  for (int i = 0; i < 4; ++i)
    #pragma unroll
    for (int j = 0; j < 4; ++j) acc[i][j] = (f32x4)(0.f);

  for (int kc = 0; kc < K/32; ++kc){
    if (AF32){
      const int rs = tid >> 2, qs = tid & 3;
      #pragma unroll
      for (int h = 0; h < 2; ++h){
        int rr = rs + 64*h;
        int grow = m0 + rr;
        uint4 payload = make_uint4(0,0,0,0);
        if (grow < M){
          const float* ap = Af + (size_t)grow*K + kc*32 + qs*8;
          float4 fa = *(const float4*)ap;
          float4 fb = *(const float4*)(ap + 4);
          payload.x = (uint)f2bf(fa.x) | ((uint)f2bf(fa.y) << 16);
          payload.y = (uint)f2bf(fa.z) | ((uint)f2bf(fa.w) << 16);
          payload.z = (uint)f2bf(fb.x) | ((uint)f2bf(fb.y) << 16);
          payload.w = (uint)f2bf(fb.z) | ((uint)f2bf(fb.w) << 16);
        }
        As[(rr >> 4)*64 + qs*16 + (rr & 15)] = payload;
      }
    } else {
      #pragma unroll
      for (int h = 0; h < 2; ++h){
        int e = tid + 256*h;
        int rr = e >> 2, q = e & 3;
        int grow = m0 + rr;
        uint4 payload = make_uint4(0,0,0,0);
        if (grow < M)
          payload = *(const uint4*)(Ab + (size_t)grow*K + (4*kc + q)*8);
        As[(rr >> 4)*64 + q*16 + (rr & 15)] = payload;
      }
    }
    const uint4* wsrc = (const uint4*)Wfrag + (size_t)kc*512;
    Bs[tid]       = wsrc[tid];
    Bs[tid + 256] = wsrc[tid + 256];
    __syncthreads();

    bf16x8 a[4], b[4];
    #pragma unroll
    for (int i = 0; i < 4; ++i){ FragU u; u.u = As[(wr*4 + i)*64 + lane]; a[i] = u.b; }
    #pragma unroll
    for (int j = 0; j < 4; ++j){ FragU u; u.u = Bs[(wc*4 + j)*64 + lane]; b[j] = u.b; }
    #pragma unroll
    for (int i = 0; i < 4; ++i)
      #pragma unroll
      for (int j = 0; j < 4; ++j)
        acc[i][j] = __builtin_amdgcn_mfma_f32_16x16x32_bf16(a[i], b[j], acc[i][j], 0, 0, 0);
    __syncthreads();
  }

  // --- epilogue ---
  const int nl = lane & 15;
  float bv[4];
  #pragma unroll
  for (int j = 0; j < 4; ++j) bv[j] = bias ? bias[wc*64 + j*16 + nl] : 0.f;
  const int s0 = nl*8 + wc*4;

  #pragma unroll
  for (int i = 0; i < 4; ++i){
    int rb = wr*64 + i*16 + (lane >> 4)*4;
    #pragma unroll
    for (int reg = 0; reg < 4; ++reg){
      int rr = rb + reg;
      int row = m0 + rr;
      if (row >= M) continue;
      float v0 = acc[i][0][reg] + bv[0];
      float v1 = acc[i][1][reg] + bv[1];
      float v2 = acc[i][2][reg] + bv[2];
      float v3 = acc[i][3][reg] + bv[3];
      if (EPI){
        ushort4 av = *(const ushort4*)(aggp + (size_t)row*CDIM + s0);
        v0 += bf2f(av.x); v1 += bf2f(av.y); v2 += bf2f(av.z); v3 += bf2f(av.w);
      }
      if (RELU){
        v0 = v0 > 0.f ? v0 : 0.f; v1 = v1 > 0.f ? v1 : 0.f;
        v2 = v2 > 0.f ? v2 : 0.f; v3 = v3 > 0.f ? v3 : 0.f;
      }
      ushort4 o;
      o.x = f2bf(v0); o.y = f2bf(v1); o.z = f2bf(v2); o.w = f2bf(v3);
      if (ZT) *(ushort4*)&tile[(size_t)rr*136 + s0] = o;
      *(ushort4*)(Outp + (size_t)row*CDIM + s0) = o;
    }
  }

  if (ZT){
    __syncthreads();
    const uint4* wf = (const uint4*)W1a;
    const int q = lane >> 4, mm = lane & 15;
    f32x4 acc2[2][2];
    #pragma unroll
    for (int a2 = 0; a2 < 2; ++a2)
      #pragma unroll
      for (int b2 = 0; b2 < 2; ++b2) acc2[a2][b2] = (f32x4)(0.f);
    #pragma unroll
    for (int kc = 0; kc < 4; ++kc){
      bf16x8 af[2];
      #pragma unroll
      for (int i2 = 0; i2 < 2; ++i2){
        FragU u;
        u.u = *(const uint4*)&tile[(size_t)(wave*32 + i2*16 + mm)*136 + (4*kc + q)*8];
        af[i2] = u.b;
      }
      #pragma unroll
      for (int nt = 0; nt < 2; ++nt){
        FragU u; u.u = wf[(kc*2 + nt)*64 + lane];
        #pragma unroll
        for (int i2 = 0; i2 < 2; ++i2)
          acc2[i2][nt] = __builtin_amdgcn_mfma_f32_16x16x32_bf16(af[i2], u.b, acc2[i2][nt], 0, 0, 0);
      }
    }
    #pragma unroll
    for (int i2 = 0; i2 < 2; ++i2){
      #pragma unroll
      for (int reg = 0; reg < 4; ++reg){
        int row = m0 + wave*32 + i2*16 + q*4 + reg;
        if (row >= M) continue;
        ztout[(size_t)row*32 + mm]      = f2bf(acc2[i2][0][reg]);
        ztout[(size_t)row*32 + 16 + mm] = f2bf(acc2[i2][1][reg]);
      }
    }
  }
}

// ---------------- prof MFMA GEMM: y = {xp-update(K=384), yp2, yp3} ----------------
__global__ __launch_bounds__(256) void k_mmp(
    const ushort* __restrict__ apcat, const ushort* __restrict__ xpold, int layer,
    const ushort* __restrict__ WpFrag, const ushort* __restrict__ Wl2Frag,
    const ushort* __restrict__ Wl3Frag, const float* __restrict__ bp,
    ushort* __restrict__ xpnew, ushort* __restrict__ yp2p, ushort* __restrict__ yp3p){
  const int y = blockIdx.y;
  const ushort* A; const ushort* Wf; const float* bias; ushort* Out;
  int nkc, rowlen; bool relu;
  if (y == 0){ A = apcat; rowlen = 384; nkc = 12; Wf = WpFrag; bias = bp;
               Out = xpnew; relu = (layer == 0); }
  else if (y == 1){ A = xpold; rowlen = 128; nkc = 4; Wf = Wl2Frag; bias = nullptr;
               Out = yp2p; relu = false; }
  else       { A = xpold; rowlen = 128; nkc = 4; Wf = Wl3Frag; bias = nullptr;
               Out = yp3p; relu = false; }

  __shared__ uint4 As[512];
  __shared__ uint4 Bs[512];
  const int tid  = threadIdx.x;
  const int lane = tid & 63;
  const int wave = tid >> 6;
  const int wr   = wave >> 1, wc = wave & 1;
  const int m0   = blockIdx.x * 128;

  f32x4 acc[4][4];
  #pragma unroll
  for (int i = 0; i < 4; ++i)
    #pragma unroll
    for (int j = 0; j < 4; ++j) acc[i][j] = (f32x4)(0.f);

  for (int kc = 0; kc < nkc; ++kc){
    #pragma unroll
    for (int h = 0; h < 2; ++h){
      int e = tid + 256*h;
      int rr = e >> 2, q = e & 3;
      int grow = m0 + rr;
      uint4 payload = make_uint4(0,0,0,0);
      if (grow < NP)
        payload = *(const uint4*)(A + (size_t)grow*rowlen + (4*kc + q)*8);
      As[(rr >> 4)*64 + q*16 + (rr & 15)] = payload;
    }
    const uint4* wsrc = (const uint4*)Wf + (size_t)kc*512;
    Bs[tid]       = wsrc[tid];
    Bs[tid + 256] = wsrc[tid + 256];
    __syncthreads();

    bf16x8 a[4], b[4];
    #pragma unroll
    for (int i = 0; i < 4; ++i){ FragU u; u.u = As[(wr*4 + i)*64 + lane]; a[i] = u.b; }
    #pragma unroll
    for (int j = 0; j < 4; ++j){ FragU u; u.u = Bs[(wc*4 + j)*64 + lane]; b[j] = u.b; }
    #pragma unroll
    for (int i = 0; i < 4; ++i)
      #pragma unroll
      for (int j = 0; j < 4; ++j)
        acc[i][j] = __builtin_amdgcn_mfma_f32_16x16x32_bf16(a[i], b[j], acc[i][j], 0, 0, 0);
    __syncthreads();
  }

  const int nl = lane & 15;
  float bv[4];
  #pragma unroll
  for (int j = 0; j < 4; ++j) bv[j] = bias ? bias[wc*64 + j*16 + nl] : 0.f;
  const int s0 = nl*8 + wc*4;

  #pragma unroll
  for (int i = 0; i < 4; ++i){
    int r0 = m0 + wr*64 + i*16 + (lane >> 4)*4;
    #pragma unroll
    for (int reg = 0; reg < 4; ++reg){
      int row = r0 + reg;
      if (row >= NP) continue;
      float v0 = acc[i][0][reg] + bv[0];
      float v1 = acc[i][1][reg] + bv[1];
      float v2 = acc[i][2][reg] + bv[2];
      float v3 = acc[i][3][reg] + bv[3];
      if (relu){
        v0 = v0 > 0.f ? v0 : 0.f; v1 = v1 > 0.f ? v1 : 0.f;
        v2 = v2 > 0.f ? v2 : 0.f; v3 = v3 > 0.f ? v3 : 0.f;
      }
      ushort4 o;
      o.x = f2bf(v0); o.y = f2bf(v1); o.z = f2bf(v2); o.w = f2bf(v3);
      *(ushort4*)(Out + (size_t)row*CDIM + s0) = o;
    }
  }
}

// ---------------- shared N=32 GEMM pass: A sigma-bf16, W invs-row-permuted fp32 ----------------
__device__ __forceinline__ void g32_pass(const ushort* __restrict__ A, int M, int m0,
                                         const float* __restrict__ W,
                                         float* As, float* Ws, float4 acc[4]){
  const int tid  = threadIdx.x;
  const int c4   = (tid & 7)*4;
  const int rowg = tid >> 3;
  for (int k0 = 0; k0 < 128; k0 += 32){
    #pragma unroll
    for (int l = 0; l < 4; ++l){
      int q = tid + 256*l;
      int r = q >> 3, kf = q & 7;
      int row = m0 + r;
      float4 v = make_float4(0.f,0.f,0.f,0.f);
      if (row < M){
        ushort4 u = *(const ushort4*)(A + (size_t)row*CDIM + k0 + kf*4);
        v = make_float4(bf2f(u.x), bf2f(u.y), bf2f(u.z), bf2f(u.w));
      }
      *(float4*)&As[r*36 + kf*4] = v;
    }
    {
      int kk = tid >> 3, cf = tid & 7;
      *(float4*)&Ws[kk*32 + cf*4] = *(const float4*)(W + (size_t)(k0+kk)*32 + cf*4);
    }
    __syncthreads();
    #pragma unroll
    for (int k4 = 0; k4 < 8; ++k4){
      float4 w0 = *(const float4*)&Ws[(k4*4+0)*32 + c4];
      float4 w1 = *(const float4*)&Ws[(k4*4+1)*32 + c4];
      float4 w2 = *(const float4*)&Ws[(k4*4+2)*32 + c4];
      float4 w3 = *(const float4*)&Ws[(k4*4+3)*32 + c4];
      #pragma unroll
      for (int j = 0; j < 4; ++j){
        float4 a = *(const float4*)&As[(rowg + 32*j)*36 + k4*4];
        acc[j].x += a.x*w0.x + a.y*w1.x + a.z*w2.x + a.w*w3.x;
        acc[j].y += a.x*w0.y + a.y*w1.y + a.z*w2.y + a.w*w3.y;
        acc[j].z += a.x*w0.z + a.y*w1.z + a.z*w2.z + a.w*w3.z;
        acc[j].w += a.x*w0.w + a.y*w1.w + a.z*w2.w + a.w*w3.w;
      }
    }
    __syncthreads();
  }
}

// ---------------- prof-side N=32 outputs (layer-1, folded) ----------------
// y=0: zpc2 = xp2 @ Wzc + b1
// y=1: y2z  = xp1 @ (Wl2_1@V) + xp2 @ Wzb + btz   (mentor-side table incl. zpb + bt1@V)
// y=2: y3z  = xp1 @ (Wl3_1@V)
__global__ __launch_bounds__(256) void k_g32prof(
    const ushort* __restrict__ xp2, const ushort* __restrict__ xp1,
    const float* __restrict__ WzcPerm, const float* __restrict__ WzbPerm,
    const float* __restrict__ W2V, const float* __restrict__ W3V,
    const float* __restrict__ b1, const float* __restrict__ btz,
    ushort* __restrict__ zpc2, ushort* __restrict__ y2z, ushort* __restrict__ y3z){
  __shared__ float As[128*36];
  __shared__ float Ws[32*32];
  const int y = blockIdx.y;
  const int m0 = blockIdx.x*128;
  const ushort* A0; const float* W0; const ushort* A1 = nullptr; const float* W1 = nullptr;
  const float* bias = nullptr; ushort* Out;
  if (y == 0){ A0 = xp2; W0 = WzcPerm; bias = b1;  Out = zpc2; }
  else if (y == 1){ A0 = xp1; W0 = W2V; A1 = xp2; W1 = WzbPerm; bias = btz; Out = y2z; }
  else { A0 = xp1; W0 = W3V; Out = y3z; }

  float4 acc[4];
  #pragma unroll
  for (int j = 0; j < 4; ++j) acc[j] = make_float4(0.f,0.f,0.f,0.f);
  g32_pass(A0, NP, m0, W0, As, Ws, acc);
  if (A1) g32_pass(A1, NP, m0, W1, As, Ws, acc);

  const int c4   = (threadIdx.x & 7)*4;
  const int rowg = threadIdx.x >> 3;
  float4 bb = make_float4(0.f,0.f,0.f,0.f);
  if (bias) bb = *(const float4*)(bias + c4);
  #pragma unroll
  for (int j = 0; j < 4; ++j){
    int row = m0 + rowg + 32*j;
    if (row < NP){
      ushort4 o;
      o.x = f2bf(acc[j].x + bb.x); o.y = f2bf(acc[j].y + bb.y);
      o.z = f2bf(acc[j].z + bb.z); o.w = f2bf(acc[j].w + bb.w);
      *(ushort4*)(Out + (size_t)row*32 + c4) = o;
    }
  }
}

// ---------------- 32-wide edge aggregation: zt = zt0 + y2z[mentor] + sum y3z[com] ------------
__global__ __launch_bounds__(256) void k_aggz(
    const int* __restrict__ mentor, const int* __restrict__ rowptr,
    const int* __restrict__ vals,
    const uint* __restrict__ zt0, const uint* __restrict__ y2z,
    const uint* __restrict__ y3z, uint* __restrict__ ztout){
  int t = blockIdx.x*16 + (threadIdx.x >> 4);
  if (t >= NT) return;
  int i = threadIdx.x & 15;
  uint v = zt0[(size_t)t*16 + i];
  float a = bf2f((ushort)(v & 0xffff));
  float b = bf2f((ushort)(v >> 16));
  int m = mentor[t];
  uint u = y2z[(size_t)m*16 + i];
  a += bf2f((ushort)(u & 0xffff));
  b += bf2f((ushort)(u >> 16));
  int qb = rowptr[t], qe = rowptr[t+1];
  for (int q = qb; q < qe; ++q){
    uint w = y3z[(size_t)vals[q]*16 + i];
    a += bf2f((ushort)(w & 0xffff));
    b += bf2f((ushort)(w >> 16));
  }
  ztout[(size_t)t*16 + i] = (uint)f2bf(a) | ((uint)f2bf(b) << 16);
}

// ---------------- edge classifier: zt already contains mentor-side terms; zpc2 contains b1 -------
__global__ __launch_bounds__(256) void k_edge(
    const int* __restrict__ el0, const int* __restrict__ el1,
    const ushort* __restrict__ zt2, const ushort* __restrict__ zpc2,
    const float* __restrict__ W2, const float* __restrict__ b2,
    float* __restrict__ out, int n){
  __shared__ float sW[32];
  if (threadIdx.x < 32) sW[threadIdx.x] = W2[threadIdx.x];
  __syncthreads();
  int e = blockIdx.x*256 + threadIdx.x;
  if (e >= n) return;
  int t = el0[e], p = el1[e];
  const uint4* zr = (const uint4*)(zt2  + (size_t)t*32);
  const uint4* cr = (const uint4*)(zpc2 + (size_t)p*32);
  float acc = 0.f;
  #pragma unroll
  for (int i = 0; i < 4; ++i){   // 4 uint4 = 32 bf16 hidden units
    uint4 ua = zr[i], uc = cr[i];
    const uint aw[4] = {ua.x, ua.y, ua.z, ua.w};
    const uint cw[4] = {uc.x, uc.y, uc.z, uc.w};
    #pragma unroll
    for (int k = 0; k < 4; ++k){
      int base = i*8 + k*2;
      float h0 = bf2f((ushort)(aw[k] & 0xffff)) + bf2f((ushort)(cw[k] & 0xffff));
      float h1 = bf2f((ushort)(aw[k] >> 16)) + bf2f((ushort)(cw[k] >> 16));
      h0 = h0 > 0.f ? h0 : 0.f;
      h1 = h1 > 0.f ? h1 : 0.f;
      acc = fmaf(h0, sW[base], acc);
      acc = fmaf(h1, sW[base + 1], acc);
    }
  }
  out[e] = acc + b2[0];
}

// ---------------- launch ----------------
extern "C" void kernel_launch(void* const* d_in, const int* in_sizes, int n_in,
                              void* d_out, int out_size, void* d_ws, size_t ws_size,
                              hipStream_t stream){
  const float* thesis_x = (const float*)d_in[0];
  const float* lin_W    = (const float*)d_in[1];
  const float* lin_b    = (const float*)d_in[2];
  const float* prof_emb = (const float*)d_in[3];
  const float* gWl      = (const float*)d_in[4];
  const float* gbl      = (const float*)d_in[5];
  const float* gWr      = (const float*)d_in[6];
  const float* cW1      = (const float*)d_in[7];
  const float* cb1      = (const float*)d_in[8];
  const float* cW2      = (const float*)d_in[9];
  const float* cb2      = (const float*)d_in[10];
  const int*   pid      = (const int*)d_in[11];
  const int*   sup0     = (const int*)d_in[12];
  const int*   sup1     = sup0 + NT;
  const int*   com0     = (const int*)d_in[13];
  const int*   com1     = com0 + EC;
  const int*   el0      = (const int*)d_in[14];
  const int*   el1      = el0 + EL;
  float* outp = (float*)d_out;

  char* base = (char*)d_ws;
  size_t off = 0;
  auto alloc = [&](size_t bytes)->void*{
    void* p = base + off;
    off += (bytes + 255) & ~(size_t)255;
    return p;
  };
  ushort* xt      = (ushort*)alloc((size_t)NT*CDIM*2);   // sigma-bf16
  ushort* aggp    = (ushort*)alloc((size_t)NT*CDIM*2);   // sigma-bf16 (layer 0)
  ushort* zt      = (ushort*)alloc((size_t)NT*32*2);     // natural bf16 (final)
  ushort* zt0     = (ushort*)alloc((size_t)NT*32*2);     // natural bf16 (xt1 @ Vt, from ZT epi)
  ushort* xp0     = (ushort*)alloc((size_t)NP*CDIM*2);   // sigma-bf16
  ushort* xp1     = (ushort*)alloc((size_t)NP*CDIM*2);
  ushort* apcat   = (ushort*)alloc((size_t)NP*384*2);    // [sig|sig|sig] bf16
  ushort* yp2p    = (ushort*)alloc((size_t)NP*CDIM*2);
  ushort* yp3p    = (ushort*)alloc((size_t)NP*CDIM*2);
  ushort* WmFrag  = (ushort*)alloc((size_t)384*128*2);
  ushort* VtFrag  = (ushort*)alloc((size_t)128*32*2);    // bf16 frag of (Wr12+Wr13)@V
  float*  W2V     = (float*)alloc((size_t)128*32*4);     // invs-perm (Wl12@V)
  float*  W3V     = (float*)alloc((size_t)128*32*4);     // invs-perm (Wl13@V)
  float*  btz     = (float*)alloc(512);
  float*  WzbPerm = (float*)alloc((size_t)128*32*4);
  float*  WzcPerm = (float*)alloc((size_t)128*32*4);
  ushort* WpFrag  = (ushort*)alloc((size_t)2*384*128*2);
  ushort* Wl2Frag = (ushort*)alloc((size_t)2*128*128*2);
  ushort* Wl3Frag = (ushort*)alloc((size_t)2*128*128*2);
  ushort* WtFrag  = (ushort*)alloc((size_t)2*128*128*2);
  float*  bp      = (float*)alloc(2*512);
  float*  btp     = (float*)alloc(2*512);
  ushort* zpc     = (ushort*)alloc((size_t)NP*32*2);     // zpc2 = zpc + b1
  ushort* y2z     = (ushort*)alloc((size_t)NP*32*2);
  ushort* y3z     = (ushort*)alloc((size_t)NP*32*2);
  int* rp_all  = (int*)alloc((size_t)(NKEYS+1)*4);
  int* vals    = (int*)alloc((size_t)NEDGE*4);
  int* counts  = (int*)alloc((size_t)NKEYS*4);
  int* cursor  = (int*)alloc((size_t)NKEYS*4);
  int* partials= (int*)alloc(8192);

  auto cdiv = [](int a, int b){ return (a + b - 1)/b; };

  // ---- fused prep (also zeroes counts; replaces memset+prep+wprep*2+fuse32) ----
  const int nEblocks = cdiv(PE_TOTAL, 256);
  k_prepall<<<nEblocks + 48, 256, 0, stream>>>(
      prof_emb, pid, xp0, lin_W, WmFrag, cW1, WzbPerm, WzcPerm,
      gWl, gbl, gWr, WpFrag, Wl2Frag, Wl3Frag, WtFrag, bp, btp,
      VtFrag, W2V, W3V, btz, counts, nEblocks);

  // ---- CSR build ----
  k_hist3<<<cdiv(NEDGE,256),256,0,stream>>>(com0, com1, sup1, counts);
  int nPb = cdiv(NKEYS,256);
  k_scanA<<<nPb,256,0,stream>>>(counts, NKEYS, rp_all, partials);
  k_scanB<<<1,1024,0,stream>>>(partials, nPb, rp_all + NKEYS);
  k_scanC<<<nPb,256,0,stream>>>(rp_all, partials, NKEYS, cursor);
  k_fill3<<<cdiv(NEDGE,256),256,0,stream>>>(com0, com1, sup0, sup1, cursor, vals);
  const int* rp_t = rp_all;               // com by thesis (vals = prof)
  const int* crp  = rp_all + NT;          // com by prof (vals = thesis)
  const int* mrp  = rp_all + NT + NP;     // sup by prof (vals = thesis)

  // xt = sigma-bf16(thesis_x @ lin_W + lin_b)
  k_mm<384,true,false,false,false><<<cdiv(NT,128),256,0,stream>>>(
      thesis_x, NT, WmFrag, lin_b, xt, nullptr, nullptr, nullptr);

  // ---- layer 0 ----
  k_segsum<<<cdiv(NP,2),256,0,stream>>>((const uint*)xt, (const uint*)xp0,
                                        mrp, crp, vals, (uint*)apcat);
  k_mmp<<<dim3(cdiv(NP,128),3),256,0,stream>>>(
      apcat, xp0, 0, WpFrag, Wl2Frag, Wl3Frag, bp, xp1, yp2p, yp3p);
  k_agg<<<cdiv(NT,8),256,0,stream>>>(sup1, rp_t, vals, yp2p, yp3p, btp, aggp);
  // xt1 (in-place, ReLU) + zt0 = xt1 @ Vt via fused ZT epilogue
  k_mm<128,false,true,true,true><<<cdiv(NT,128),256,0,stream>>>(
      xt, NT, WtFrag, nullptr, xt, aggp, VtFrag, zt0);

  // ---- layer 1 (prof side; thesis side fully folded to N=32) ----
  k_segsum<<<cdiv(NP,2),256,0,stream>>>((const uint*)xt, (const uint*)xp1,
                                        mrp, crp, vals, (uint*)apcat);
  k_mmp<<<dim3(cdiv(NP,128),1),256,0,stream>>>(     // only y=0: xp2
      apcat, xp1, 1, WpFrag + 49152, Wl2Frag + 16384,
      Wl3Frag + 16384, bp + 128, xp0, yp2p, yp3p);  // xp0 reused as xp2
  k_g32prof<<<dim3(cdiv(NP,128),3),256,0,stream>>>(
      xp0, xp1, WzcPerm, WzbPerm, W2V, W3V, cb1, btz, zpc, y2z, y3z);
  k_aggz<<<cdiv(NT,16),256,0,stream>>>(sup1, rp_t, vals,
                                       (const uint*)zt0, (const uint*)y2z,
                                       (const uint*)y3z, (uint*)zt);

  k_edge<<<cdiv(EL,256),256,0,stream>>>(el0, el1, zt, zpc,
                                        cW2, cb2, outp, EL);
}

// Round 5
// 886.115 us; speedup vs baseline: 1.1449x; 1.0086x over previous
//
#include <hip/hip_runtime.h>
#include <hip/hip_bf16.h>
#include <cstdint>
#include <cstddef>

#define NT 200000
#define NP 5000
#define FDIM 384
#define CDIM 128
#define EC 600000
#define EL 400000
#define NKEYS (NT + 2*NP)          // concatenated CSR segment count
#define NEDGE (2*EC + NT)          // concatenated edge count

typedef unsigned int uint;
typedef unsigned short ushort;
typedef __attribute__((ext_vector_type(8))) __bf16 bf16x8;
typedef __attribute__((ext_vector_type(4))) float f32x4;

union FragU { uint4 u; bf16x8 b; };

__device__ __forceinline__ ushort f2bf(float f){
  uint u = __float_as_uint(f);
  u = (u + 0x7fffu + ((u >> 16) & 1u)) >> 16;
  return (ushort)u;
}
__device__ __forceinline__ float bf2f(ushort h){
  return __uint_as_float(((uint)h) << 16);
}
// storage permutation: sigma(c) = (c&15)*8 + (c>>4); invs below
__device__ __forceinline__ int invs(int w){
  return ((w >> 2) & 1)*64 + (w & 3)*16 + (w >> 3);
}

// ---------------- fused CSR build ----------------
__global__ void k_hist3(const int* __restrict__ com0, const int* __restrict__ com1,
                        const int* __restrict__ sup1, int* __restrict__ counts){
  int i = blockIdx.x*256 + threadIdx.x;
  if (i < EC)            atomicAdd(&counts[com0[i]], 1);
  else if (i < 2*EC)     atomicAdd(&counts[NT + com1[i - EC]], 1);
  else if (i < NEDGE)    atomicAdd(&counts[NT + NP + sup1[i - 2*EC]], 1);
}

// local exclusive scan per 256-block + block totals
__global__ void k_scanA(const int* __restrict__ counts, int n,
                        int* __restrict__ rowptr, int* __restrict__ partials){
  __shared__ int s[256];
  int tid = threadIdx.x;
  int i = blockIdx.x*256 + tid;
  int v = (i < n) ? counts[i] : 0;
  s[tid] = v; __syncthreads();
  for (int off = 1; off < 256; off <<= 1){
    int t = (tid >= off) ? s[tid - off] : 0;
    __syncthreads();
    s[tid] += t;
    __syncthreads();
  }
  if (i < n) rowptr[i] = s[tid] - v;
  if (tid == 255) partials[blockIdx.x] = s[255];
}

__global__ void k_scanB(int* __restrict__ partials, int nP, int* __restrict__ total_out){
  __shared__ int s[1024];
  int carry = 0;
  for (int base = 0; base < nP; base += 1024){
    int i = base + threadIdx.x;
    int v = (i < nP) ? partials[i] : 0;
    s[threadIdx.x] = v; __syncthreads();
    for (int off = 1; off < 1024; off <<= 1){
      int t = (threadIdx.x >= off) ? s[threadIdx.x - off] : 0;
      __syncthreads();
      s[threadIdx.x] += t;
      __syncthreads();
    }
    if (i < nP) partials[i] = carry + s[threadIdx.x] - v;
    int chunk_total = s[1023];
    __syncthreads();
    carry += chunk_total;
  }
  if (threadIdx.x == 0 && total_out) *total_out = carry;
}

__global__ void k_scanC(int* __restrict__ rowptr, const int* __restrict__ pscan,
                        int n, int* __restrict__ cursor){
  int i = blockIdx.x*256 + threadIdx.x;
  if (i < n){
    int r = rowptr[i] + pscan[i >> 8];
    rowptr[i] = r;
    cursor[i] = r;
  }
}

__global__ void k_fill3(const int* __restrict__ com0, const int* __restrict__ com1,
                        const int* __restrict__ sup0, const int* __restrict__ sup1,
                        int* __restrict__ cursor, int* __restrict__ vals){
  int i = blockIdx.x*256 + threadIdx.x;
  int key, sv;
  if (i < EC)          { key = com0[i];                 sv = com1[i]; }
  else if (i < 2*EC)   { key = NT + com1[i - EC];       sv = com0[i - EC]; }
  else if (i < NEDGE)  { key = NT + NP + sup1[i - 2*EC]; sv = sup0[i - 2*EC]; }
  else return;
  int pos = atomicAdd(&cursor[key], 1);
  vals[pos] = sv;
}

// ---------------- layer-0 weight prep element ----------------
__device__ __forceinline__ void wprep_elem(int o,
    const float* __restrict__ gWl, const float* __restrict__ gbl,
    const float* __restrict__ gWr,
    ushort* __restrict__ WpFrag, ushort* __restrict__ Wl2Frag,
    ushort* __restrict__ Wl3Frag, ushort* __restrict__ WtFrag,
    float* __restrict__ bp, float* __restrict__ btp){
  if (o < 49152){                       // WpFrag: K=384, all blocks invs
    int j = o & 7, lane = (o >> 3) & 63, q = lane >> 4, nl = lane & 15, tl = o >> 9;
    int nt = tl & 7, kc = tl >> 3;
    int s_row = 32*kc + 8*q + j;
    int b = s_row >> 7, w = s_row & 127;
    int r = invs(w), n = nt*16 + nl;
    float v;
    if (b == 0)      v = gWl[(size_t)r*128 + n];
    else if (b == 1) v = gWl[16384 + (size_t)r*128 + n];
    else             v = gWr[(size_t)r*128 + n] + gWr[16384 + (size_t)r*128 + n];
    WpFrag[o] = f2bf(v);
    return;
  }
  o -= 49152;
  if (o < 3*16384){                     // Wl2 / Wl3 / Wt frags (K=128, invs)
    int m = o >> 14;
    int oo = o & 16383;
    int j = oo & 7, lane = (oo >> 3) & 63, q = lane >> 4, nl = lane & 15, tl = oo >> 9;
    int nt = tl & 7, kc = tl >> 3;
    int s = 32*kc + 8*q + j;
    int r = invs(s), n = nt*16 + nl;
    float v;
    if (m == 0)      v = gWl[2*16384 + (size_t)r*128 + n];
    else if (m == 1) v = gWl[3*16384 + (size_t)r*128 + n];
    else             v = gWr[2*16384 + (size_t)r*128 + n] + gWr[3*16384 + (size_t)r*128 + n];
    (m == 0 ? Wl2Frag : (m == 1 ? Wl3Frag : WtFrag))[oo] = f2bf(v);
    return;
  }
  o -= 3*16384;
  if (o < 128){
    bp[o] = gbl[o] + gbl[128 + o];
    btp[(o & 15)*8 + (o >> 4)] = gbl[2*128 + o] + gbl[3*128 + o];   // sigma store
  }
}

// ---------------- fused prep: counts zero + xp0 + layer-0 frags + layer-1 folds --------------
// elementwise segment sizes
#define PS0 NKEYS            // zero counts
#define PS1 (NP*CDIM)        // xp0
#define PS2 (384*128)        // WmFrag
#define PS4 98432            // wprep layer 0
#define PE_TOTAL (PS0+PS1+PS2+PS4)
// fold blocks: VtFrag 16, W2V 16, W3V 16, WpzbPerm 48, WpzcPerm 48 = 144
#define NFOLD 144

__global__ __launch_bounds__(256) void k_prepall(
    const float* __restrict__ pe, const int* __restrict__ pid,
    ushort* __restrict__ xp0,
    const float* __restrict__ lin_W, ushort* __restrict__ WmFrag,
    const float* __restrict__ cW1, const float* __restrict__ cb1,
    const float* __restrict__ gWl, const float* __restrict__ gbl,
    const float* __restrict__ gWr,
    ushort* __restrict__ WpFrag, ushort* __restrict__ Wl2Frag,
    ushort* __restrict__ Wl3Frag, ushort* __restrict__ WtFrag,
    float* __restrict__ bp, float* __restrict__ btp,
    ushort* __restrict__ VtFrag, float* __restrict__ W2V,
    float* __restrict__ W3V,
    float* __restrict__ WpzbPerm, float* __restrict__ WpzcPerm,
    float* __restrict__ bpzb, float* __restrict__ bpzc,
    int* __restrict__ counts, int nEblocks){
  __shared__ float Vs[4096];
  const int tid = threadIdx.x;
  int fb = blockIdx.x - nEblocks;
  if (fb >= 0){
    // ---- fold blocks ----
    int ftype, o;
    if (fb < 16)      { ftype = 0; o = fb*256 + tid; }        // VtFrag
    else if (fb < 32) { ftype = 1; o = (fb-16)*256 + tid; }   // W2V
    else if (fb < 48) { ftype = 2; o = (fb-32)*256 + tid; }   // W3V
    else if (fb < 96) { ftype = 3; o = (fb-48)*256 + tid; }   // WpzbPerm
    else              { ftype = 4; o = (fb-96)*256 + tid; }   // WpzcPerm
    // stage the relevant 128x32 slice of cW1: V / Wzb / Wzc
    const float* slice = cW1 + (ftype == 3 ? 128*32 : (ftype == 4 ? 256*32 : 0));
    for (int i = tid; i < 4096; i += 256) Vs[i] = slice[i];
    __syncthreads();
    if (ftype == 0){
      // MFMA frag layout (K=128, N=32): Vt = (Wr1[2]+Wr1[3]) @ V, rows invs
      int j = o & 7, lane = (o >> 3) & 63, q = lane >> 4, nl = lane & 15, tl = o >> 9;
      int nt = tl & 1, kc = tl >> 1;
      int s = 32*kc + 8*q + j, n = nt*16 + nl;
      int r = invs(s);
      const float* Wr2 = gWr + (size_t)6*16384;
      const float* Wr3 = gWr + (size_t)7*16384;
      float acc = 0.f;
      for (int c = 0; c < 128; ++c)
        acc += (Wr2[r*128 + c] + Wr3[r*128 + c]) * Vs[c*32 + n];
      VtFrag[o] = f2bf(acc);
    } else if (ftype <= 2){
      // g32 layout [s][n], rows invs; W2V = Wl1[2]@V, W3V = Wl1[3]@V
      int s = o >> 5, n = o & 31;
      int r = invs(s);
      const float* W = gWl + (size_t)(ftype == 1 ? 6 : 7)*16384;
      float acc = 0.f;
      for (int c = 0; c < 128; ++c)
        acc += W[r*128 + c] * Vs[c*32 + n];
      (ftype == 1 ? W2V : W3V)[o] = acc;
    } else {
      // Wpz{b,c}Perm[s][n], s in [0,384): apcat-block-aware invs rows of
      // Wp1_combined = [Wl1[0]; Wl1[1]; Wr1[0]+Wr1[1]] times (Wzb | Wzc)
      int s = o >> 5, n = o & 31;
      int b = s >> 7, w = s & 127;
      int r = invs(w);
      float acc = 0.f;
      if (b == 0){
        const float* W = gWl + (size_t)4*16384 + (size_t)r*128;
        for (int c = 0; c < 128; ++c) acc += W[c] * Vs[c*32 + n];
      } else if (b == 1){
        const float* W = gWl + (size_t)5*16384 + (size_t)r*128;
        for (int c = 0; c < 128; ++c) acc += W[c] * Vs[c*32 + n];
      } else {
        const float* Wa = gWr + (size_t)4*16384 + (size_t)r*128;
        const float* Wb = gWr + (size_t)5*16384 + (size_t)r*128;
        for (int c = 0; c < 128; ++c) acc += (Wa[c] + Wb[c]) * Vs[c*32 + n];
      }
      (ftype == 3 ? WpzbPerm : WpzcPerm)[o] = acc;
      // bias folds (one block per type)
      if ((fb == 48 || fb == 96) && tid < 32){
        int nn = tid;
        const float* b0 = gbl + 4*128;   // bl1[0]
        const float* b1l = gbl + 5*128;  // bl1[1]
        float a2 = 0.f;
        for (int c = 0; c < 128; ++c) a2 += (b0[c] + b1l[c]) * Vs[c*32 + nn];
        if (fb == 48){
          // + (bl1[2]+bl1[3]) @ V   (V read from global; Vs holds Wzb here)
          const float* b2 = gbl + 6*128;
          const float* b3 = gbl + 7*128;
          for (int c = 0; c < 128; ++c) a2 += (b2[c] + b3[c]) * cW1[c*32 + nn];
          bpzb[nn] = a2;
        } else {
          bpzc[nn] = a2 + cb1[nn];
        }
      }
    }
    return;
  }
  // ---- elementwise blocks ----
  int i = blockIdx.x*256 + tid;
  if (i < PS0){ counts[i] = 0; return; }
  i -= PS0;
  if (i < PS1){                          // xp0[p][w] = bf16(pe[pid[p]][invs(w)])
    int p = i >> 7, w = i & 127;
    xp0[i] = f2bf(pe[(size_t)pid[p]*CDIM + invs(w)]);
    return;
  }
  i -= PS1;
  if (i < PS2){                          // WmFrag natural pack (A = fp32 natural)
    int j = i & 7, lane = (i >> 3) & 63, q = lane >> 4, nl = lane & 15, tl = i >> 9;
    int nt = tl & 7, kc = tl >> 3;
    int k = kc*32 + q*8 + j, n = nt*16 + nl;
    WmFrag[i] = f2bf(lin_W[(size_t)k*128 + n]);
    return;
  }
  i -= PS2;
  if (i < PS4)
    wprep_elem(i, gWl, gbl, gWr, WpFrag, Wl2Frag, Wl3Frag, WtFrag, bp, btp);
}

// ---------------- segment sums: 1 block per prof; wave0 = sup, waves1-3 = com thirds ----------
__global__ __launch_bounds__(256) void k_segsum(
    const uint* __restrict__ xt32, const uint* __restrict__ xp32,
    const int* __restrict__ mrp, const int* __restrict__ crp,
    const int* __restrict__ vall, uint* __restrict__ apcat){
  __shared__ float part[3][64][2];
  int p = blockIdx.x;
  int wid = threadIdx.x >> 6;
  int lane = threadIdx.x & 63;
  uint* row = apcat + (size_t)p*192;
  float sa = 0.f, sb = 0.f;
  int j, je;
  if (wid == 0){ j = mrp[p]; je = mrp[p+1]; }
  else {
    int base = crp[p], end = crp[p+1];
    int n = end - base, chunk = (n + 2)/3;
    j = base + (wid-1)*chunk;
    je = j + chunk; if (je > end) je = end;
  }
  for (; j + 8 <= je; j += 8){
    uint v0 = xt32[(size_t)vall[j]  *64 + lane];
    uint v1 = xt32[(size_t)vall[j+1]*64 + lane];
    uint v2 = xt32[(size_t)vall[j+2]*64 + lane];
    uint v3 = xt32[(size_t)vall[j+3]*64 + lane];
    uint v4 = xt32[(size_t)vall[j+4]*64 + lane];
    uint v5 = xt32[(size_t)vall[j+5]*64 + lane];
    uint v6 = xt32[(size_t)vall[j+6]*64 + lane];
    uint v7 = xt32[(size_t)vall[j+7]*64 + lane];
    sa += ((bf2f((ushort)(v0 & 0xffff)) + bf2f((ushort)(v1 & 0xffff)))
         + (bf2f((ushort)(v2 & 0xffff)) + bf2f((ushort)(v3 & 0xffff))))
        + ((bf2f((ushort)(v4 & 0xffff)) + bf2f((ushort)(v5 & 0xffff)))
         + (bf2f((ushort)(v6 & 0xffff)) + bf2f((ushort)(v7 & 0xffff))));
    sb += ((bf2f((ushort)(v0 >> 16)) + bf2f((ushort)(v1 >> 16)))
         + (bf2f((ushort)(v2 >> 16)) + bf2f((ushort)(v3 >> 16))))
        + ((bf2f((ushort)(v4 >> 16)) + bf2f((ushort)(v5 >> 16)))
         + (bf2f((ushort)(v6 >> 16)) + bf2f((ushort)(v7 >> 16))));
  }
  for (; j < je; ++j){
    uint v = xt32[(size_t)vall[j]*64 + lane];
    sa += bf2f((ushort)(v & 0xffff));
    sb += bf2f((ushort)(v >> 16));
  }
  if (wid == 0){
    row[lane]       = (uint)f2bf(sa) | ((uint)f2bf(sb) << 16);
    row[128 + lane] = xp32[(size_t)p*64 + lane];
  } else {
    part[wid-1][lane][0] = sa;
    part[wid-1][lane][1] = sb;
  }
  __syncthreads();
  if (wid == 1){
    float ca = part[0][lane][0] + part[1][lane][0] + part[2][lane][0];
    float cb = part[0][lane][1] + part[1][lane][1] + part[2][lane][1];
    row[64 + lane] = (uint)f2bf(ca) | ((uint)f2bf(cb) << 16);
  }
}

// ---------------- edge aggregation, 128-wide (layer 0 only) ----------------
__global__ __launch_bounds__(256) void k_agg(
    const int* __restrict__ mentor, const int* __restrict__ rowptr,
    const int* __restrict__ vals,
    const ushort* __restrict__ yp2p, const ushort* __restrict__ yp3p,
    const float* __restrict__ btp, ushort* __restrict__ aggp){
  int t = blockIdx.x*8 + (threadIdx.x >> 5);
  if (t >= NT) return;
  int i = threadIdx.x & 31;
  float4 s = *(const float4*)(btp + i*4);
  int m = mentor[t];
  ushort4 y = *(const ushort4*)(yp2p + (size_t)m*CDIM + i*4);
  s.x += bf2f(y.x); s.y += bf2f(y.y); s.z += bf2f(y.z); s.w += bf2f(y.w);
  int qb = rowptr[t], qe = rowptr[t+1];
  for (int q = qb; q < qe; ++q){
    ushort4 z = *(const ushort4*)(yp3p + (size_t)vals[q]*CDIM + i*4);
    s.x += bf2f(z.x); s.y += bf2f(z.y); s.z += bf2f(z.z); s.w += bf2f(z.w);
  }
  ushort4 o;
  o.x = f2bf(s.x); o.y = f2bf(s.y); o.z = f2bf(s.z); o.w = f2bf(s.w);
  *(ushort4*)(aggp + (size_t)t*CDIM + i*4) = o;
}

// ---------------- thesis MFMA GEMM ----------------
// EPI: add aggp (agg'd neighbor terms + bias, from k_agg) in epilogue.
// ZT:  ALSO write result tile to LDS (stride 136) and emit zt0 = tile @ W1a
//      (in addition to the normal Outp store).
template<int K, bool AF32, bool EPI, bool RELU, bool ZT>
__global__ __launch_bounds__(256) void k_mm(
    const void* __restrict__ Ain, int M,
    const ushort* __restrict__ Wfrag, const float* __restrict__ bias,
    ushort* __restrict__ Outp, const ushort* __restrict__ aggp,
    const ushort* __restrict__ W1a, ushort* __restrict__ ztout){
  constexpr int SMSZ = ZT ? 2176 : 1024;      // uint4 units (ZT: 34816 B tile overlay)
  __shared__ uint4 smem[SMSZ];
  uint4* As = smem;
  uint4* Bs = smem + 512;
  ushort* tile = (ushort*)smem;               // 128 x 136, used after K-loop only
  const int tid  = threadIdx.x;
  const int lane = tid & 63;
  const int wave = tid >> 6;
  const int wr   = wave >> 1, wc = wave & 1;
  const int m0   = blockIdx.x * 128;
  const float* Af = (const float*)Ain;
  const ushort* Ab = (const ushort*)Ain;

  f32x4 acc[4][4];
  #pragma unroll
  for (int i = 0; i < 4; ++i)
    #pragma unroll
    for (int j = 0; j < 4; ++j) acc[i][j] = (f32x4)(0.f);

  for (int kc = 0; kc < K/32; ++kc){
    if (AF32){
      const int rs = tid >> 2, qs = tid & 3;
      #pragma unroll
      for (int h = 0; h < 2; ++h){
        int rr = rs + 64*h;
        int grow = m0 + rr;
        uint4 payload = make_uint4(0,0,0,0);
        if (grow < M){
          const float* ap = Af + (size_t)grow*K + kc*32 + qs*8;
          float4 fa = *(const float4*)ap;
          float4 fb = *(const float4*)(ap + 4);
          payload.x = (uint)f2bf(fa.x) | ((uint)f2bf(fa.y) << 16);
          payload.y = (uint)f2bf(fa.z) | ((uint)f2bf(fa.w) << 16);
          payload.z = (uint)f2bf(fb.x) | ((uint)f2bf(fb.y) << 16);
          payload.w = (uint)f2bf(fb.z) | ((uint)f2bf(fb.w) << 16);
        }
        As[(rr >> 4)*64 + qs*16 + (rr & 15)] = payload;
      }
    } else {
      #pragma unroll
      for (int h = 0; h < 2; ++h){
        int e = tid + 256*h;
        int rr = e >> 2, q = e & 3;
        int grow = m0 + rr;
        uint4 payload = make_uint4(0,0,0,0);
        if (grow < M)
          payload = *(const uint4*)(Ab + (size_t)grow*K + (4*kc + q)*8);
        As[(rr >> 4)*64 + q*16 + (rr & 15)] = payload;
      }
    }
    const uint4* wsrc = (const uint4*)Wfrag + (size_t)kc*512;
    Bs[tid]       = wsrc[tid];
    Bs[tid + 256] = wsrc[tid + 256];
    __syncthreads();

    bf16x8 a[4], b[4];
    #pragma unroll
    for (int i = 0; i < 4; ++i){ FragU u; u.u = As[(wr*4 + i)*64 + lane]; a[i] = u.b; }
    #pragma unroll
    for (int j = 0; j < 4; ++j){ FragU u; u.u = Bs[(wc*4 + j)*64 + lane]; b[j] = u.b; }
    #pragma unroll
    for (int i = 0; i < 4; ++i)
      #pragma unroll
      for (int j = 0; j < 4; ++j)
        acc[i][j] = __builtin_amdgcn_mfma_f32_16x16x32_bf16(a[i], b[j], acc[i][j], 0, 0, 0);
    __syncthreads();
  }

  // --- epilogue ---
  const int nl = lane & 15;
  float bv[4];
  #pragma unroll
  for (int j = 0; j < 4; ++j) bv[j] = bias ? bias[wc*64 + j*16 + nl] : 0.f;
  const int s0 = nl*8 + wc*4;

  #pragma unroll
  for (int i = 0; i < 4; ++i){
    int rb = wr*64 + i*16 + (lane >> 4)*4;
    #pragma unroll
    for (int reg = 0; reg < 4; ++reg){
      int rr = rb + reg;
      int row = m0 + rr;
      if (row >= M) continue;
      float v0 = acc[i][0][reg] + bv[0];
      float v1 = acc[i][1][reg] + bv[1];
      float v2 = acc[i][2][reg] + bv[2];
      float v3 = acc[i][3][reg] + bv[3];
      if (EPI){
        ushort4 av = *(const ushort4*)(aggp + (size_t)row*CDIM + s0);
        v0 += bf2f(av.x); v1 += bf2f(av.y); v2 += bf2f(av.z); v3 += bf2f(av.w);
      }
      if (RELU){
        v0 = v0 > 0.f ? v0 : 0.f; v1 = v1 > 0.f ? v1 : 0.f;
        v2 = v2 > 0.f ? v2 : 0.f; v3 = v3 > 0.f ? v3 : 0.f;
      }
      ushort4 o;
      o.x = f2bf(v0); o.y = f2bf(v1); o.z = f2bf(v2); o.w = f2bf(v3);
      if (ZT) *(ushort4*)&tile[(size_t)rr*136 + s0] = o;
      *(ushort4*)(Outp + (size_t)row*CDIM + s0) = o;
    }
  }

  if (ZT){
    __syncthreads();
    const uint4* wf = (const uint4*)W1a;
    const int q = lane >> 4, mm = lane & 15;
    f32x4 acc2[2][2];
    #pragma unroll
    for (int a2 = 0; a2 < 2; ++a2)
      #pragma unroll
      for (int b2 = 0; b2 < 2; ++b2) acc2[a2][b2] = (f32x4)(0.f);
    #pragma unroll
    for (int kc = 0; kc < 4; ++kc){
      bf16x8 af[2];
      #pragma unroll
      for (int i2 = 0; i2 < 2; ++i2){
        FragU u;
        u.u = *(const uint4*)&tile[(size_t)(wave*32 + i2*16 + mm)*136 + (4*kc + q)*8];
        af[i2] = u.b;
      }
      #pragma unroll
      for (int nt = 0; nt < 2; ++nt){
        FragU u; u.u = wf[(kc*2 + nt)*64 + lane];
        #pragma unroll
        for (int i2 = 0; i2 < 2; ++i2)
          acc2[i2][nt] = __builtin_amdgcn_mfma_f32_16x16x32_bf16(af[i2], u.b, acc2[i2][nt], 0, 0, 0);
      }
    }
    #pragma unroll
    for (int i2 = 0; i2 < 2; ++i2){
      #pragma unroll
      for (int reg = 0; reg < 4; ++reg){
        int row = m0 + wave*32 + i2*16 + q*4 + reg;
        if (row >= M) continue;
        ztout[(size_t)row*32 + mm]      = f2bf(acc2[i2][0][reg]);
        ztout[(size_t)row*32 + 16 + mm] = f2bf(acc2[i2][1][reg]);
      }
    }
  }
}

// ---------------- layer-0 prof MFMA GEMM: y = {xp1(K=384,relu), yp2, yp3} ----------------
__global__ __launch_bounds__(256) void k_mmp(
    const ushort* __restrict__ apcat, const ushort* __restrict__ xpold,
    const ushort* __restrict__ WpFrag, const ushort* __restrict__ Wl2Frag,
    const ushort* __restrict__ Wl3Frag, const float* __restrict__ bp,
    ushort* __restrict__ xpnew, ushort* __restrict__ yp2p, ushort* __restrict__ yp3p){
  const int y = blockIdx.y;
  const ushort* A; const ushort* Wf; const float* bias; ushort* Out;
  int nkc, rowlen; bool relu;
  if (y == 0){ A = apcat; rowlen = 384; nkc = 12; Wf = WpFrag; bias = bp;
               Out = xpnew; relu = true; }
  else if (y == 1){ A = xpold; rowlen = 128; nkc = 4; Wf = Wl2Frag; bias = nullptr;
               Out = yp2p; relu = false; }
  else       { A = xpold; rowlen = 128; nkc = 4; Wf = Wl3Frag; bias = nullptr;
               Out = yp3p; relu = false; }

  __shared__ uint4 As[512];
  __shared__ uint4 Bs[512];
  const int tid  = threadIdx.x;
  const int lane = tid & 63;
  const int wave = tid >> 6;
  const int wr   = wave >> 1, wc = wave & 1;
  const int m0   = blockIdx.x * 128;

  f32x4 acc[4][4];
  #pragma unroll
  for (int i = 0; i < 4; ++i)
    #pragma unroll
    for (int j = 0; j < 4; ++j) acc[i][j] = (f32x4)(0.f);

  for (int kc = 0; kc < nkc; ++kc){
    #pragma unroll
    for (int h = 0; h < 2; ++h){
      int e = tid + 256*h;
      int rr = e >> 2, q = e & 3;
      int grow = m0 + rr;
      uint4 payload = make_uint4(0,0,0,0);
      if (grow < NP)
        payload = *(const uint4*)(A + (size_t)grow*rowlen + (4*kc + q)*8);
      As[(rr >> 4)*64 + q*16 + (rr & 15)] = payload;
    }
    const uint4* wsrc = (const uint4*)Wf + (size_t)kc*512;
    Bs[tid]       = wsrc[tid];
    Bs[tid + 256] = wsrc[tid + 256];
    __syncthreads();

    bf16x8 a[4], b[4];
    #pragma unroll
    for (int i = 0; i < 4; ++i){ FragU u; u.u = As[(wr*4 + i)*64 + lane]; a[i] = u.b; }
    #pragma unroll
    for (int j = 0; j < 4; ++j){ FragU u; u.u = Bs[(wc*4 + j)*64 + lane]; b[j] = u.b; }
    #pragma unroll
    for (int i = 0; i < 4; ++i)
      #pragma unroll
      for (int j = 0; j < 4; ++j)
        acc[i][j] = __builtin_amdgcn_mfma_f32_16x16x32_bf16(a[i], b[j], acc[i][j], 0, 0, 0);
    __syncthreads();
  }

  const int nl = lane & 15;
  float bv[4];
  #pragma unroll
  for (int j = 0; j < 4; ++j) bv[j] = bias ? bias[wc*64 + j*16 + nl] : 0.f;
  const int s0 = nl*8 + wc*4;

  #pragma unroll
  for (int i = 0; i < 4; ++i){
    int r0 = m0 + wr*64 + i*16 + (lane >> 4)*4;
    #pragma unroll
    for (int reg = 0; reg < 4; ++reg){
      int row = r0 + reg;
      if (row >= NP) continue;
      float v0 = acc[i][0][reg] + bv[0];
      float v1 = acc[i][1][reg] + bv[1];
      float v2 = acc[i][2][reg] + bv[2];
      float v3 = acc[i][3][reg] + bv[3];
      if (relu){
        v0 = v0 > 0.f ? v0 : 0.f; v1 = v1 > 0.f ? v1 : 0.f;
        v2 = v2 > 0.f ? v2 : 0.f; v3 = v3 > 0.f ? v3 : 0.f;
      }
      ushort4 o;
      o.x = f2bf(v0); o.y = f2bf(v1); o.z = f2bf(v2); o.w = f2bf(v3);
      *(ushort4*)(Out + (size_t)row*CDIM + s0) = o;
    }
  }
}

// ---------------- shared N=32 GEMM pass: A sigma-bf16 (per-128 block), W invs-row-perm fp32 ----
__device__ __forceinline__ void g32_pass(const ushort* __restrict__ A, int M, int m0,
                                         int K, int stride,
                                         const float* __restrict__ W,
                                         float* As, float* Ws, float4 acc[4]){
  const int tid  = threadIdx.x;
  const int c4   = (tid & 7)*4;
  const int rowg = tid >> 3;
  for (int k0 = 0; k0 < K; k0 += 32){
    #pragma unroll
    for (int l = 0; l < 4; ++l){
      int q = tid + 256*l;
      int r = q >> 3, kf = q & 7;
      int row = m0 + r;
      float4 v = make_float4(0.f,0.f,0.f,0.f);
      if (row < M){
        ushort4 u = *(const ushort4*)(A + (size_t)row*stride + k0 + kf*4);
        v = make_float4(bf2f(u.x), bf2f(u.y), bf2f(u.z), bf2f(u.w));
      }
      *(float4*)&As[r*36 + kf*4] = v;
    }
    {
      int kk = tid >> 3, cf = tid & 7;
      *(float4*)&Ws[kk*32 + cf*4] = *(const float4*)(W + (size_t)(k0+kk)*32 + cf*4);
    }
    __syncthreads();
    #pragma unroll
    for (int k4 = 0; k4 < 8; ++k4){
      float4 w0 = *(const float4*)&Ws[(k4*4+0)*32 + c4];
      float4 w1 = *(const float4*)&Ws[(k4*4+1)*32 + c4];
      float4 w2 = *(const float4*)&Ws[(k4*4+2)*32 + c4];
      float4 w3 = *(const float4*)&Ws[(k4*4+3)*32 + c4];
      #pragma unroll
      for (int j = 0; j < 4; ++j){
        float4 a = *(const float4*)&As[(rowg + 32*j)*36 + k4*4];
        acc[j].x += a.x*w0.x + a.y*w1.x + a.z*w2.x + a.w*w3.x;
        acc[j].y += a.x*w0.y + a.y*w1.y + a.z*w2.y + a.w*w3.y;
        acc[j].z += a.x*w0.z + a.y*w1.z + a.z*w2.z + a.w*w3.z;
        acc[j].w += a.x*w0.w + a.y*w1.w + a.z*w2.w + a.w*w3.w;
      }
    }
    __syncthreads();
  }
}

// ---------------- prof-side N=32 outputs (layer-1 fully folded; no xp2) ----------------
// y=0: zpc2 = apcat1 @ WpzcPerm + bpzc           (= xp2@Wzc + b1)
// y=1: y2z  = xp1 @ W2V + apcat1 @ WpzbPerm + bpzb  (= yp2@V + zpb + bt1@V)
// y=2: y3z  = xp1 @ W3V
__global__ __launch_bounds__(256) void k_g32prof(
    const ushort* __restrict__ apcat, const ushort* __restrict__ xp1,
    const float* __restrict__ WpzcPerm, const float* __restrict__ WpzbPerm,
    const float* __restrict__ W2V, const float* __restrict__ W3V,
    const float* __restrict__ bpzc, const float* __restrict__ bpzb,
    ushort* __restrict__ zpc2, ushort* __restrict__ y2z, ushort* __restrict__ y3z){
  __shared__ float As[128*36];
  __shared__ float Ws[32*32];
  const int y = blockIdx.y;
  const int m0 = blockIdx.x*128;

  float4 acc[4];
  #pragma unroll
  for (int j = 0; j < 4; ++j) acc[j] = make_float4(0.f,0.f,0.f,0.f);

  const float* bias = nullptr; ushort* Out;
  if (y == 0){
    g32_pass(apcat, NP, m0, 384, 384, WpzcPerm, As, Ws, acc);
    bias = bpzc; Out = zpc2;
  } else if (y == 1){
    g32_pass(xp1, NP, m0, 128, 128, W2V, As, Ws, acc);
    g32_pass(apcat, NP, m0, 384, 384, WpzbPerm, As, Ws, acc);
    bias = bpzb; Out = y2z;
  } else {
    g32_pass(xp1, NP, m0, 128, 128, W3V, As, Ws, acc);
    Out = y3z;
  }

  const int c4   = (threadIdx.x & 7)*4;
  const int rowg = threadIdx.x >> 3;
  float4 bb = make_float4(0.f,0.f,0.f,0.f);
  if (bias) bb = *(const float4*)(bias + c4);
  #pragma unroll
  for (int j = 0; j < 4; ++j){
    int row = m0 + rowg + 32*j;
    if (row < NP){
      ushort4 o;
      o.x = f2bf(acc[j].x + bb.x); o.y = f2bf(acc[j].y + bb.y);
      o.z = f2bf(acc[j].z + bb.z); o.w = f2bf(acc[j].w + bb.w);
      *(ushort4*)(Out + (size_t)row*32 + c4) = o;
    }
  }
}

// ---------------- 32-wide edge aggregation: zt = zt0 + y2z[mentor] + sum y3z[com] ------------
__global__ __launch_bounds__(256) void k_aggz(
    const int* __restrict__ mentor, const int* __restrict__ rowptr,
    const int* __restrict__ vals,
    const uint* __restrict__ zt0, const uint* __restrict__ y2z,
    const uint* __restrict__ y3z, uint* __restrict__ ztout){
  int t = blockIdx.x*16 + (threadIdx.x >> 4);
  if (t >= NT) return;
  int i = threadIdx.x & 15;
  uint v = zt0[(size_t)t*16 + i];
  float a = bf2f((ushort)(v & 0xffff));
  float b = bf2f((ushort)(v >> 16));
  int m = mentor[t];
  uint u = y2z[(size_t)m*16 + i];
  a += bf2f((ushort)(u & 0xffff));
  b += bf2f((ushort)(u >> 16));
  int qb = rowptr[t], qe = rowptr[t+1];
  for (int q = qb; q < qe; ++q){
    uint w = y3z[(size_t)vals[q]*16 + i];
    a += bf2f((ushort)(w & 0xffff));
    b += bf2f((ushort)(w >> 16));
  }
  ztout[(size_t)t*16 + i] = (uint)f2bf(a) | ((uint)f2bf(b) << 16);
}

// ---------------- edge classifier: zt has all mentor-side terms; zpc2 has b1 ----------------
__global__ __launch_bounds__(256) void k_edge(
    const int* __restrict__ el0, const int* __restrict__ el1,
    const ushort* __restrict__ zt2, const ushort* __restrict__ zpc2,
    const float* __restrict__ W2, const float* __restrict__ b2,
    float* __restrict__ out, int n){
  __shared__ float sW[32];
  if (threadIdx.x < 32) sW[threadIdx.x] = W2[threadIdx.x];
  __syncthreads();
  int e = blockIdx.x*256 + threadIdx.x;
  if (e >= n) return;
  int t = el0[e], p = el1[e];
  const uint4* zr = (const uint4*)(zt2  + (size_t)t*32);
  const uint4* cr = (const uint4*)(zpc2 + (size_t)p*32);
  float acc = 0.f;
  #pragma unroll
  for (int i = 0; i < 4; ++i){   // 4 uint4 = 32 bf16 hidden units
    uint4 ua = zr[i], uc = cr[i];
    const uint aw[4] = {ua.x, ua.y, ua.z, ua.w};
    const uint cw[4] = {uc.x, uc.y, uc.z, uc.w};
    #pragma unroll
    for (int k = 0; k < 4; ++k){
      int base = i*8 + k*2;
      float h0 = bf2f((ushort)(aw[k] & 0xffff)) + bf2f((ushort)(cw[k] & 0xffff));
      float h1 = bf2f((ushort)(aw[k] >> 16)) + bf2f((ushort)(cw[k] >> 16));
      h0 = h0 > 0.f ? h0 : 0.f;
      h1 = h1 > 0.f ? h1 : 0.f;
      acc = fmaf(h0, sW[base], acc);
      acc = fmaf(h1, sW[base + 1], acc);
    }
  }
  out[e] = acc + b2[0];
}

// ---------------- launch ----------------
extern "C" void kernel_launch(void* const* d_in, const int* in_sizes, int n_in,
                              void* d_out, int out_size, void* d_ws, size_t ws_size,
                              hipStream_t stream){
  const float* thesis_x = (const float*)d_in[0];
  const float* lin_W    = (const float*)d_in[1];
  const float* lin_b    = (const float*)d_in[2];
  const float* prof_emb = (const float*)d_in[3];
  const float* gWl      = (const float*)d_in[4];
  const float* gbl      = (const float*)d_in[5];
  const float* gWr      = (const float*)d_in[6];
  const float* cW1      = (const float*)d_in[7];
  const float* cb1      = (const float*)d_in[8];
  const float* cW2      = (const float*)d_in[9];
  const float* cb2      = (const float*)d_in[10];
  const int*   pid      = (const int*)d_in[11];
  const int*   sup0     = (const int*)d_in[12];
  const int*   sup1     = sup0 + NT;
  const int*   com0     = (const int*)d_in[13];
  const int*   com1     = com0 + EC;
  const int*   el0      = (const int*)d_in[14];
  const int*   el1      = el0 + EL;
  float* outp = (float*)d_out;

  char* base = (char*)d_ws;
  size_t off = 0;
  auto alloc = [&](size_t bytes)->void*{
    void* p = base + off;
    off += (bytes + 255) & ~(size_t)255;
    return p;
  };
  ushort* xt      = (ushort*)alloc((size_t)NT*CDIM*2);   // sigma-bf16
  ushort* aggp    = (ushort*)alloc((size_t)NT*CDIM*2);   // sigma-bf16 (layer 0)
  ushort* zt      = (ushort*)alloc((size_t)NT*32*2);     // natural bf16 (final)
  ushort* zt0     = (ushort*)alloc((size_t)NT*32*2);     // natural bf16 (xt1 @ Vt, from ZT epi)
  ushort* xp0     = (ushort*)alloc((size_t)NP*CDIM*2);   // sigma-bf16
  ushort* xp1     = (ushort*)alloc((size_t)NP*CDIM*2);
  ushort* apcat   = (ushort*)alloc((size_t)NP*384*2);    // [sig|sig|sig] bf16
  ushort* yp2p    = (ushort*)alloc((size_t)NP*CDIM*2);
  ushort* yp3p    = (ushort*)alloc((size_t)NP*CDIM*2);
  ushort* WmFrag  = (ushort*)alloc((size_t)384*128*2);
  ushort* VtFrag  = (ushort*)alloc((size_t)128*32*2);    // bf16 frag of (Wr12+Wr13)@V
  float*  W2V     = (float*)alloc((size_t)128*32*4);     // invs-perm (Wl12@V)
  float*  W3V     = (float*)alloc((size_t)128*32*4);     // invs-perm (Wl13@V)
  float*  WpzbPerm= (float*)alloc((size_t)384*32*4);     // apcat-block invs (Wp1@Wzb)
  float*  WpzcPerm= (float*)alloc((size_t)384*32*4);     // apcat-block invs (Wp1@Wzc)
  float*  bpzb    = (float*)alloc(256);
  float*  bpzc    = (float*)alloc(256);
  ushort* WpFrag  = (ushort*)alloc((size_t)384*128*2);   // layer 0 only
  ushort* Wl2Frag = (ushort*)alloc((size_t)128*128*2);
  ushort* Wl3Frag = (ushort*)alloc((size_t)128*128*2);
  ushort* WtFrag  = (ushort*)alloc((size_t)128*128*2);
  float*  bp      = (float*)alloc(512);
  float*  btp     = (float*)alloc(512);
  ushort* zpc     = (ushort*)alloc((size_t)NP*32*2);     // zpc2 = zpc incl b1
  ushort* y2z     = (ushort*)alloc((size_t)NP*32*2);
  ushort* y3z     = (ushort*)alloc((size_t)NP*32*2);
  int* rp_all  = (int*)alloc((size_t)(NKEYS+1)*4);
  int* vals    = (int*)alloc((size_t)NEDGE*4);
  int* counts  = (int*)alloc((size_t)NKEYS*4);
  int* cursor  = (int*)alloc((size_t)NKEYS*4);
  int* partials= (int*)alloc(8192);

  auto cdiv = [](int a, int b){ return (a + b - 1)/b; };

  // ---- fused prep (zeroes counts; layer-0 frags; all layer-1 algebraic folds) ----
  const int nEblocks = cdiv(PE_TOTAL, 256);
  k_prepall<<<nEblocks + NFOLD, 256, 0, stream>>>(
      prof_emb, pid, xp0, lin_W, WmFrag, cW1, cb1,
      gWl, gbl, gWr, WpFrag, Wl2Frag, Wl3Frag, WtFrag, bp, btp,
      VtFrag, W2V, W3V, WpzbPerm, WpzcPerm, bpzb, bpzc,
      counts, nEblocks);

  // ---- CSR build ----
  k_hist3<<<cdiv(NEDGE,256),256,0,stream>>>(com0, com1, sup1, counts);
  int nPb = cdiv(NKEYS,256);
  k_scanA<<<nPb,256,0,stream>>>(counts, NKEYS, rp_all, partials);
  k_scanB<<<1,1024,0,stream>>>(partials, nPb, rp_all + NKEYS);
  k_scanC<<<nPb,256,0,stream>>>(rp_all, partials, NKEYS, cursor);
  k_fill3<<<cdiv(NEDGE,256),256,0,stream>>>(com0, com1, sup0, sup1, cursor, vals);
  const int* rp_t = rp_all;               // com by thesis (vals = prof)
  const int* crp  = rp_all + NT;          // com by prof (vals = thesis)
  const int* mrp  = rp_all + NT + NP;     // sup by prof (vals = thesis)

  // xt = sigma-bf16(thesis_x @ lin_W + lin_b)
  k_mm<384,true,false,false,false><<<cdiv(NT,128),256,0,stream>>>(
      thesis_x, NT, WmFrag, lin_b, xt, nullptr, nullptr, nullptr);

  // ---- layer 0 ----
  k_segsum<<<NP,256,0,stream>>>((const uint*)xt, (const uint*)xp0,
                                mrp, crp, vals, (uint*)apcat);
  k_mmp<<<dim3(cdiv(NP,128),3),256,0,stream>>>(
      apcat, xp0, WpFrag, Wl2Frag, Wl3Frag, bp, xp1, yp2p, yp3p);
  k_agg<<<cdiv(NT,8),256,0,stream>>>(sup1, rp_t, vals, yp2p, yp3p, btp, aggp);
  // xt1 (in-place, ReLU) + zt0 = xt1 @ Vt via fused ZT epilogue
  k_mm<128,false,true,true,true><<<cdiv(NT,128),256,0,stream>>>(
      xt, NT, WtFrag, nullptr, xt, aggp, VtFrag, zt0);

  // ---- layer 1 (prof side fully folded; no k_mmp) ----
  k_segsum<<<NP,256,0,stream>>>((const uint*)xt, (const uint*)xp1,
                                mrp, crp, vals, (uint*)apcat);
  k_g32prof<<<dim3(cdiv(NP,128),3),256,0,stream>>>(
      apcat, xp1, WpzcPerm, WpzbPerm, W2V, W3V, bpzc, bpzb, zpc, y2z, y3z);
  k_aggz<<<cdiv(NT,16),256,0,stream>>>(sup1, rp_t, vals,
                                       (const uint*)zt0, (const uint*)y2z,
                                       (const uint*)y3z, (uint*)zt);

  k_edge<<<cdiv(EL,256),256,0,stream>>>(el0, el1, zt, zpc,
                                        cW2, cb2, outp, EL);
}